// Round 1
// baseline (500.032 us; speedup 1.0000x reference)
//
#include <hip/hip_runtime.h>
#include <math.h>

// Problem constants
#define DIMC   512
#define HEADS  8
#define SLOTS  112
#define HD     64          // DIMC/HEADS
#define NROWS  16384       // B*S = 32*512
#define RADIUSF 16.0f

typedef short short8 __attribute__((ext_vector_type(8)));
typedef float f32x4  __attribute__((ext_vector_type(4)));

__device__ __forceinline__ unsigned short f2bf(float f)
{
    unsigned u = __float_as_uint(f);
    unsigned r = (u + 0x7FFFu + ((u >> 16) & 1u)) >> 16;   // RNE
    return (unsigned short)r;
}

// Fused wave-wide (64-lane) reductions with ILP; results broadcast to all lanes.
__device__ __forceinline__ void wred2(float& a, float& b)
{
    #pragma unroll
    for (int off = 32; off; off >>= 1) {
        a += __shfl_down(a, off, 64);
        b += __shfl_down(b, off, 64);
    }
    a = __shfl(a, 0, 64);
    b = __shfl(b, 0, 64);
}

__device__ __forceinline__ void wred4(float& a, float& b, float& c, float& d)
{
    #pragma unroll
    for (int off = 32; off; off >>= 1) {
        a += __shfl_down(a, off, 64);
        b += __shfl_down(b, off, 64);
        c += __shfl_down(c, off, 64);
        d += __shfl_down(d, off, 64);
    }
    a = __shfl(a, 0, 64);
    b = __shfl(b, 0, 64);
    c = __shfl(c, 0, 64);
    d = __shfl(d, 0, 64);
}

// ---------------------------------------------------------------------------
// bf16 MFMA GEMM: C(MxN fp32) = A(MxK bf16) @ B(NxK bf16)^T (+ bias[col])
// 128x128 tile, BK=32, 256 threads = 4 waves, each wave a 64x64 quadrant.
// ---------------------------------------------------------------------------
__global__ __launch_bounds__(256)
void gemm_bf16(const short* __restrict__ A, int lda,
               const short* __restrict__ B, int ldb,
               float* __restrict__ C, int ldc,
               int K, const float* __restrict__ bias)
{
    __shared__ short As[128 * 32];
    __shared__ short Bs[128 * 32];
    const int tid  = threadIdx.x;
    const int wave = tid >> 6;
    const int lane = tid & 63;
    const int m0 = blockIdx.y * 128;
    const int n0 = blockIdx.x * 128;
    const int wm = (wave >> 1) * 64;
    const int wn = (wave & 1) * 64;

    const int srow = tid >> 2;
    const int schk = (tid & 3) * 8;

    const int fr = lane & 15;
    const int fq = (lane >> 4) * 8;

    f32x4 acc[4][4] = {};

    const short* Ag = A + (size_t)(m0 + srow) * lda + schk;
    const short* Bg = B + (size_t)(n0 + srow) * ldb + schk;

    for (int k0 = 0; k0 < K; k0 += 32) {
        *(short8*)&As[srow * 32 + schk]        = *(const short8*)(Ag);
        *(short8*)&As[(srow + 64) * 32 + schk] = *(const short8*)(Ag + (size_t)64 * lda);
        *(short8*)&Bs[srow * 32 + schk]        = *(const short8*)(Bg);
        *(short8*)&Bs[(srow + 64) * 32 + schk] = *(const short8*)(Bg + (size_t)64 * ldb);
        Ag += 32; Bg += 32;
        __syncthreads();
        short8 af[4], bf[4];
        #pragma unroll
        for (int i = 0; i < 4; ++i)
            af[i] = *(const short8*)&As[(wm + i * 16 + fr) * 32 + fq];
        #pragma unroll
        for (int j = 0; j < 4; ++j)
            bf[j] = *(const short8*)&Bs[(wn + j * 16 + fr) * 32 + fq];
        #pragma unroll
        for (int i = 0; i < 4; ++i)
            #pragma unroll
            for (int j = 0; j < 4; ++j)
                acc[i][j] = __builtin_amdgcn_mfma_f32_16x16x32_bf16(
                    af[i], bf[j], acc[i][j], 0, 0, 0);
        __syncthreads();
    }

    const int cr = (lane >> 4) * 4;
    const int cc = lane & 15;
    #pragma unroll
    for (int i = 0; i < 4; ++i) {
        const int grow = m0 + wm + i * 16 + cr;
        #pragma unroll
        for (int j = 0; j < 4; ++j) {
            const int gcol = n0 + wn + j * 16 + cc;
            const float bb = bias ? bias[gcol] : 0.f;
            float* cp = C + (size_t)grow * ldc + gcol;
            #pragma unroll
            for (int r = 0; r < 4; ++r)
                cp[(size_t)r * ldc] = acc[i][j][r] + bb;
        }
    }
}

// ---------------------------------------------------------------------------
// Generic tiled fp32 GEMM: C(MxN) = A(MxK) @ B(NxK)^T (+ bias[col])
// ---------------------------------------------------------------------------
__global__ __launch_bounds__(256)
void gemm_abt(const float* __restrict__ A, int lda,
              const float* __restrict__ B, int ldb,
              float* __restrict__ C, int ldc,
              int M, int N, int K,
              const float* __restrict__ bias,
              int aZ, int bZ, int cZ)
{
    __shared__ float As[16][68];
    __shared__ float Bs[16][68];
    A += (size_t)blockIdx.z * aZ;
    B += (size_t)blockIdx.z * bZ;
    C += (size_t)blockIdx.z * cZ;
    const int m0 = blockIdx.y * 64;
    const int n0 = blockIdx.x * 64;
    const int tid = threadIdx.x;
    const int tm = tid >> 4;
    const int tn = tid & 15;
    const int lr = tid >> 2;
    const int lc = (tid & 3) << 2;

    float acc[4][4] = {};

    for (int k0 = 0; k0 < K; k0 += 16) {
        float4 av = make_float4(0.f, 0.f, 0.f, 0.f);
        float4 bv = make_float4(0.f, 0.f, 0.f, 0.f);
        const int am = m0 + lr;
        if (am < M) av = *(const float4*)(A + (size_t)am * lda + k0 + lc);
        const int bn = n0 + lr;
        if (bn < N) bv = *(const float4*)(B + (size_t)bn * ldb + k0 + lc);
        As[lc + 0][lr] = av.x; As[lc + 1][lr] = av.y;
        As[lc + 2][lr] = av.z; As[lc + 3][lr] = av.w;
        Bs[lc + 0][lr] = bv.x; Bs[lc + 1][lr] = bv.y;
        Bs[lc + 2][lr] = bv.z; Bs[lc + 3][lr] = bv.w;
        __syncthreads();
        #pragma unroll
        for (int k = 0; k < 16; ++k) {
            float a[4], b[4];
            #pragma unroll
            for (int i = 0; i < 4; ++i) a[i] = As[k][tm * 4 + i];
            #pragma unroll
            for (int j = 0; j < 4; ++j) b[j] = Bs[k][tn * 4 + j];
            #pragma unroll
            for (int i = 0; i < 4; ++i)
                #pragma unroll
                for (int j = 0; j < 4; ++j)
                    acc[i][j] += a[i] * b[j];
        }
        __syncthreads();
    }

    #pragma unroll
    for (int i = 0; i < 4; ++i) {
        const int row = m0 + tm * 4 + i;
        if (row >= M) continue;
        #pragma unroll
        for (int j = 0; j < 4; ++j) {
            const int col = n0 + tn * 4 + j;
            if (col < N) {
                float v = acc[i][j];
                if (bias) v += bias[col];
                C[(size_t)row * ldc + col] = v;
            }
        }
    }
}

// ---------------------------------------------------------------------------
// Small helpers
// ---------------------------------------------------------------------------
__device__ __forceinline__ float block_sum_256(float v, float* red)
{
    #pragma unroll
    for (int off = 32; off; off >>= 1) v += __shfl_down(v, off, 64);
    const int lane = threadIdx.x & 63, wid = threadIdx.x >> 6;
    __syncthreads();
    if (lane == 0) red[wid] = v;
    __syncthreads();
    return red[0] + red[1] + red[2] + red[3];
}

__global__ void zero_small(float* p, int n)
{
    int i = blockIdx.x * blockDim.x + threadIdx.x;
    if (i < n) p[i] = 0.f;
}

// fp32 -> bf16 (RNE), n multiple of 4
__global__ void f32_to_bf16(const float* __restrict__ src,
                            unsigned short* __restrict__ dst, int n)
{
    int i = (blockIdx.x * blockDim.x + threadIdx.x) * 4;
    if (i >= n) return;
    float4 v = *(const float4*)(src + i);
    ushort4 o;
    o.x = f2bf(v.x); o.y = f2bf(v.y); o.z = f2bf(v.z); o.w = f2bf(v.w);
    *(ushort4*)(dst + i) = o;
}

__global__ void prep_key_norm(const float* __restrict__ km, float* __restrict__ kn)
{
    const int row = blockIdx.x;
    const int lane = threadIdx.x;      // 64 threads
    float v = km[(size_t)row * HD + lane];
    float s = v * v;
    #pragma unroll
    for (int off = 32; off; off >>= 1) s += __shfl_down(s, off, 64);
    s = __shfl(s, 0, 64);
    const float inv = 1.f / fmaxf(sqrtf(s), 1e-12f);
    kn[(size_t)row * HD + lane] = v * inv;
}

__global__ void prep_value_norm(const float* __restrict__ vm,
                                float* __restrict__ vn, float* __restrict__ vmT)
{
    const int row = blockIdx.x;        // 0..111
    const int tid = threadIdx.x;       // 256
    __shared__ float red[4];
    const float v0 = vm[(size_t)row * DIMC + tid];
    const float v1 = vm[(size_t)row * DIMC + 256 + tid];
    const float tot = block_sum_256(v0 * v0 + v1 * v1, red);
    const float inv = 1.f / fmaxf(sqrtf(tot), 1e-12f);
    vn[(size_t)row * DIMC + tid]        = v0 * inv;
    vn[(size_t)row * DIMC + 256 + tid]  = v1 * inv;
    vmT[(size_t)tid * SLOTS + row]         = v0;
    vmT[(size_t)(256 + tid) * SLOTS + row] = v1;
}

__global__ void contrastive_kernel(const float* __restrict__ vn, float* __restrict__ outc)
{
    __shared__ float vni[DIMC];
    __shared__ float red[2];
    const int i = blockIdx.x, tid = threadIdx.x;   // 128 threads
    for (int d = tid; d < DIMC; d += 128) vni[d] = vn[(size_t)i * DIMC + d];
    __syncthreads();
    float t = 0.f;
    if (tid < SLOTS) {
        const float* r = vn + (size_t)tid * DIMC;
        float dot = 0.f;
        for (int d = 0; d < DIMC; ++d) dot += vni[d] * r[d];
        const float delta = (tid == i) ? 1.f : 0.f;
        t = fabsf(delta - dot);
    }
    #pragma unroll
    for (int off = 32; off; off >>= 1) t += __shfl_down(t, off, 64);
    if ((tid & 63) == 0) red[tid >> 6] = t;
    __syncthreads();
    if (tid == 0) atomicAdd(outc, 0.5f * (red[0] + red[1]));
}

// Per-(row,head) inverse l2 norm of eq
__global__ __launch_bounds__(256)
void eq_head_norms(const float* __restrict__ eq, float* __restrict__ hinv)
{
    const int wid  = threadIdx.x >> 6;
    const int lane = threadIdx.x & 63;
    const int r = blockIdx.x * 4 + wid;
    const float4 v0 = *(const float4*)(eq + (size_t)r * DIMC + lane * 8);
    const float4 v1 = *(const float4*)(eq + (size_t)r * DIMC + lane * 8 + 4);
    float s = v0.x * v0.x + v0.y * v0.y + v0.z * v0.z + v0.w * v0.w
            + v1.x * v1.x + v1.y * v1.y + v1.z * v1.z + v1.w * v1.w;
    s += __shfl_down(s, 4, 8);
    s += __shfl_down(s, 2, 8);
    s += __shfl_down(s, 1, 8);
    if ((lane & 7) == 0)
        hinv[(size_t)r * HEADS + (lane >> 3)] = 1.f / fmaxf(sqrtf(s), 1e-12f);
}

// Per-row inverse l2 norm over 512 floats (one wave per row)
__global__ __launch_bounds__(256)
void row_rnorm(const float* __restrict__ x, float* __restrict__ rinv)
{
    const int wave = threadIdx.x >> 6, lane = threadIdx.x & 63;
    const int r = blockIdx.x * 4 + wave;
    const float* p = x + (size_t)r * DIMC + lane * 8;
    const float4 a = *(const float4*)p;
    const float4 b = *(const float4*)(p + 4);
    float s = a.x * a.x + a.y * a.y + a.z * a.z + a.w * a.w
            + b.x * b.x + b.y * b.y + b.z * b.z + b.w * b.w;
    #pragma unroll
    for (int off = 32; off; off >>= 1) s += __shfl_down(s, off, 64);
    if (lane == 0) rinv[r] = 1.f / fmaxf(sqrtf(s), 1e-12f);
}

// Per-head softmax over 112 slots of sim row (scaled by RADIUS*hinv),
// bf16 output in place over the same row slot (see round-4 notes).
__global__ __launch_bounds__(256)
void key_softmax(const float* __restrict__ sim, unsigned short* __restrict__ kadd,
                 const float* __restrict__ hinv)
{
    const int r = blockIdx.x, tid = threadIdx.x;
    const int g = tid >> 5, li = tid & 31;
    const float scale = RADIUSF * hinv[(size_t)r * HEADS + g];
    const float* row = sim + (size_t)r * (HEADS * SLOTS) + g * SLOTS;
    unsigned short* orow = kadd + (size_t)r * (2 * HEADS * SLOTS) + g * SLOTS;

    float v[4];
    #pragma unroll
    for (int u = 0; u < 4; ++u) {
        const int s = li + u * 32;
        v[u] = (s < SLOTS) ? row[s] * scale : -1e30f;
    }
    __syncthreads();   // all reads of this row done before any bf16 write
    float mx = fmaxf(fmaxf(v[0], v[1]), fmaxf(v[2], v[3]));
    #pragma unroll
    for (int off = 16; off; off >>= 1) mx = fmaxf(mx, __shfl_down(mx, off, 32));
    mx = __shfl(mx, 0, 32);
    float e[4]; float sum = 0.f;
    #pragma unroll
    for (int u = 0; u < 4; ++u) {
        const int s = li + u * 32;
        e[u] = (s < SLOTS) ? __expf(v[u] - mx) : 0.f;
        sum += e[u];
    }
    #pragma unroll
    for (int off = 16; off; off >>= 1) sum += __shfl_down(sum, off, 32);
    sum = __shfl(sum, 0, 32);
    const float invs = 1.f / sum;
    #pragma unroll
    for (int u = 0; u < 4; ++u) {
        const int s = li + u * 32;
        if (s < SLOTS) orow[s] = f2bf(e[u] * invs);
    }
}

// Wave-per-row: vir_pre -> LN(g2,b2) -> +query -> LN(g1,b1) -> out_te
// Round-5 fix: regalloc had chosen a 32-VGPR schedule that re-loaded the
// row operands after each cross-lane reduction chain (remat-via-reload is
// legal under __restrict__), serializing loads behind ~1-2K-cycle shuffle
// chains (observed on twin kernel aud_epilogue_w: 20% HBM BW, 10% VALUBusy).
// Pin x/q with an opaque "+v" asm identity so all loads issue up front and
// stay resident; launch_bounds(256,4) gives the allocator a 128-VGPR budget.
__global__ __launch_bounds__(256, 4)
void vir_te_w(const float* __restrict__ vir_pre, const float* __restrict__ query,
              const float* __restrict__ g1, const float* __restrict__ b1,
              const float* __restrict__ g2, const float* __restrict__ b2,
              float* __restrict__ out_te)
{
    const int wave = threadIdx.x >> 6, lane = threadIdx.x & 63;
    const int r = blockIdx.x * 4 + wave;
    const size_t base = (size_t)r * DIMC + lane * 8;
    const f32x4 xa = *(const f32x4*)(vir_pre + base);
    const f32x4 xb = *(const f32x4*)(vir_pre + base + 4);
    const f32x4 qa = *(const f32x4*)(query + base);
    const f32x4 qb = *(const f32x4*)(query + base + 4);
    float x[8] = {xa[0], xa[1], xa[2], xa[3], xb[0], xb[1], xb[2], xb[3]};
    float q[8] = {qa[0], qa[1], qa[2], qa[3], qb[0], qb[1], qb[2], qb[3]};
    #pragma unroll
    for (int i = 0; i < 8; ++i)
        asm volatile("" : "+v"(x[i]), "+v"(q[i]));   // pin in VGPRs (no remat)

    float s1 = 0.f, s2 = 0.f;
    #pragma unroll
    for (int i = 0; i < 8; ++i) { s1 += x[i]; s2 += x[i] * x[i]; }
    wred2(s1, s2);
    float mu = s1 * (1.f / DIMC);
    float var = s2 * (1.f / DIMC) - mu * mu;
    float rstd = rsqrtf(var + 1e-5f);

    float y[8]; float t1 = 0.f, t2 = 0.f;
    #pragma unroll
    for (int i = 0; i < 8; ++i) {
        const int c = lane * 8 + i;
        const float v = (x[i] - mu) * rstd * g2[c] + b2[c];
        y[i] = q[i] + v;
        t1 += y[i]; t2 += y[i] * y[i];
    }
    wred2(t1, t2);
    mu = t1 * (1.f / DIMC);
    var = t2 * (1.f / DIMC) - mu * mu;
    rstd = rsqrtf(var + 1e-5f);

    float o[8];
    #pragma unroll
    for (int i = 0; i < 8; ++i) {
        const int c = lane * 8 + i;
        o[i] = (y[i] - mu) * rstd * g1[c] + b1[c];
    }
    *(float4*)(out_te + base)     = make_float4(o[0], o[1], o[2], o[3]);
    *(float4*)(out_te + base + 4) = make_float4(o[4], o[5], o[6], o[7]);
}

// Wave-per-row softmax(RADIUS * rinv[r] * sim) over 112 slots, in place.
__global__ __launch_bounds__(256)
void value_softmax_w(float* __restrict__ vs, const float* __restrict__ rinv)
{
    const int wave = threadIdx.x >> 6, lane = threadIdx.x & 63;
    const int r = blockIdx.x * 4 + wave;
    const float scale = RADIUSF * rinv[r];
    float* row = vs + (size_t)r * SLOTS;
    const float v0 = row[lane] * scale;
    const float v1 = (lane < 48) ? row[64 + lane] * scale : -1e30f;
    float m = fmaxf(v0, v1);
    #pragma unroll
    for (int off = 32; off; off >>= 1) m = fmaxf(m, __shfl_down(m, off, 64));
    m = __shfl(m, 0, 64);
    const float e0 = __expf(v0 - m);
    const float e1 = (lane < 48) ? __expf(v1 - m) : 0.f;
    float s = e0 + e1;
    #pragma unroll
    for (int off = 32; off; off >>= 1) s += __shfl_down(s, off, 64);
    s = __shfl(s, 0, 64);
    const float inv = 1.f / s;
    row[lane] = e0 * inv;
    if (lane < 48) row[64 + lane] = e1 * inv;
}

// Wave-per-row: cos/recon, LN(g3,b3), +query, LN(g1,b1) -> out_tr.
// One recon atomic per block (4 rows share the same batch index).
// Round-5 fix (measured: 52.7 µs @ 1.6 TB/s, VALUBusy 10%, VGPR_Count=32):
// the 24-float working set a/v/q cannot live in 32 VGPRs, so the compiler
// re-loaded operands after each reduction chain instead of keeping them
// resident — serializing global loads behind the wred4/wred2 shuffle chains.
// Pin a/v/q via "+v" asm identity; launch_bounds(256,4) = 128-VGPR budget.
__global__ __launch_bounds__(256, 4)
void aud_epilogue_w(const float* __restrict__ aud, const float* __restrict__ value,
                    const float* __restrict__ query,
                    const float* __restrict__ g1, const float* __restrict__ b1,
                    const float* __restrict__ g3, const float* __restrict__ b3,
                    float* __restrict__ out_tr, float* __restrict__ recon)
{
    __shared__ float red[4];
    const int wave = threadIdx.x >> 6, lane = threadIdx.x & 63;
    const int r = blockIdx.x * 4 + wave;
    const size_t base = (size_t)r * DIMC + lane * 8;
    const f32x4 aa = *(const f32x4*)(aud + base);
    const f32x4 ab = *(const f32x4*)(aud + base + 4);
    const f32x4 va = *(const f32x4*)(value + base);
    const f32x4 vb = *(const f32x4*)(value + base + 4);
    const f32x4 qa = *(const f32x4*)(query + base);
    const f32x4 qb = *(const f32x4*)(query + base + 4);
    float a[8] = {aa[0], aa[1], aa[2], aa[3], ab[0], ab[1], ab[2], ab[3]};
    float v[8] = {va[0], va[1], va[2], va[3], vb[0], vb[1], vb[2], vb[3]};
    float q[8] = {qa[0], qa[1], qa[2], qa[3], qb[0], qb[1], qb[2], qb[3]};
    #pragma unroll
    for (int i = 0; i < 8; ++i)
        asm volatile("" : "+v"(a[i]), "+v"(v[i]), "+v"(q[i]));   // pin (no remat)

    float dot = 0.f, na = 0.f, nv = 0.f, s1 = 0.f;
    #pragma unroll
    for (int i = 0; i < 8; ++i) {
        dot += a[i] * v[i];
        na  += a[i] * a[i];
        nv  += v[i] * v[i];
        s1  += a[i];
    }
    wred4(dot, na, nv, s1);                    // na == sum(a^2)
    const float cosv = dot / fmaxf(sqrtf(na) * sqrtf(nv), 1e-8f);
    if (lane == 0) red[wave] = fabsf(1.f - cosv);

    float mu = s1 * (1.f / DIMC);
    float var = na * (1.f / DIMC) - mu * mu;
    float rstd = rsqrtf(var + 1e-5f);

    float y[8]; float t1 = 0.f, t2 = 0.f;
    #pragma unroll
    for (int i = 0; i < 8; ++i) {
        const int c = lane * 8 + i;
        const float w = (a[i] - mu) * rstd * g3[c] + b3[c];
        y[i] = q[i] + w;
        t1 += y[i]; t2 += y[i] * y[i];
    }
    wred2(t1, t2);
    mu = t1 * (1.f / DIMC);
    var = t2 * (1.f / DIMC) - mu * mu;
    rstd = rsqrtf(var + 1e-5f);

    float o[8];
    #pragma unroll
    for (int i = 0; i < 8; ++i) {
        const int c = lane * 8 + i;
        o[i] = (y[i] - mu) * rstd * g1[c] + b1[c];
    }
    *(float4*)(out_tr + base)     = make_float4(o[0], o[1], o[2], o[3]);
    *(float4*)(out_tr + base + 4) = make_float4(o[4], o[5], o[6], o[7]);

    __syncthreads();
    if (threadIdx.x == 0)
        atomicAdd(&recon[r >> 9], red[0] + red[1] + red[2] + red[3]);
}

// ---------------------------------------------------------------------------
// Launch
// ---------------------------------------------------------------------------
extern "C" void kernel_launch(void* const* d_in, const int* in_sizes, int n_in,
                              void* d_out, int out_size, void* d_ws, size_t ws_size,
                              hipStream_t stream)
{
    const float* query = (const float*)d_in[0];
    const float* value = (const float*)d_in[1];
    const float* keym  = (const float*)d_in[2];
    const float* vmem  = (const float*)d_in[3];
    const float* Wq    = (const float*)d_in[4];
    const float* bq    = (const float*)d_in[5];
    const float* Wv    = (const float*)d_in[6];
    const float* bv    = (const float*)d_in[7];
    const float* Wl    = (const float*)d_in[8];
    const float* bl    = (const float*)d_in[9];
    const float* g1    = (const float*)d_in[10];
    const float* b1    = (const float*)d_in[11];
    const float* g2    = (const float*)d_in[12];
    const float* b2    = (const float*)d_in[13];
    const float* g3    = (const float*)d_in[14];
    const float* b3    = (const float*)d_in[15];

    float* out    = (float*)d_out;
    float* out_te = out;
    float* out_tr = out + 8388608;
    float* out_rc = out + 16777216;    // 32 recon + 1 contrastive

    // Workspace layout (float offsets). Total 34,054,144 floats = 136.2 MB.
    float* ws = (float*)d_ws;
    float* w_kn   = ws + 0;         //   896*64
    float* w_vn   = ws + 57344;     //   112*512
    float* w_vmT  = ws + 114688;    //   512*112
    float* w_W2T  = ws + 172032;    //   512*896 fp32
    float* w_hinv = ws + 630784;    // 16384*8
    float* w_eq   = ws + 761856;    // 16384*512 fp32 (eq -> vir_pre)
    float* w_sims = ws + 9150464;   // 16384*896 fp32 [9150464, 23830528)
    float* w_ev   = ws + 23830528;  // 16384*512 fp32 [23830528, 32219136) (ev -> aud)
    float* w_vs   = ws + 32219136;  // 16384*112 fp32

    // bf16 staging aliases (lifetimes verified against stream order, round 4):
    unsigned short* w_qbf   = (unsigned short*)(ws + 23830528); // in w_ev region
    unsigned short* w_wqbf  = (unsigned short*)(ws + 28024832);
    unsigned short* w_w2tbf = (unsigned short*)(ws + 28155904);
    unsigned short* w_kadd  = (unsigned short*)(ws + 9150464);  // in place over sims
    unsigned short* w_vbf   = (unsigned short*)(ws + 9150464);  // sims region, dead post-vir
    unsigned short* w_wvbf  = (unsigned short*)(ws + 13344768);
    float*          w_rinv  = ws + 13475840;                    // 16384 fp32, sims region

    // 0) zero recon+contrastive
    zero_small<<<1, 64, 0, stream>>>(out_rc, 33);

    // 1) input-only precomputes
    prep_key_norm<<<896, 64, 0, stream>>>(keym, w_kn);
    prep_value_norm<<<112, 256, 0, stream>>>(vmem, w_vn, w_vmT);
    contrastive_kernel<<<112, 128, 0, stream>>>(w_vn, out_rc + 32);
    gemm_abt<<<dim3(2, 8, 8), 256, 0, stream>>>(              // W2T fp32
        Wl, 4096, vmem, DIMC, w_W2T, HEADS * SLOTS,
        DIMC, SLOTS, DIMC, nullptr, DIMC, 0, SLOTS);
    f32_to_bf16<<<448, 256, 0, stream>>>(w_W2T, w_w2tbf, DIMC * HEADS * SLOTS);

    // 2) key addressing path
    f32_to_bf16<<<8192, 256, 0, stream>>>(query, w_qbf, NROWS * DIMC);
    f32_to_bf16<<<256, 256, 0, stream>>>(Wq, w_wqbf, DIMC * DIMC);
    gemm_bf16<<<dim3(4, 128), 256, 0, stream>>>(              // eq = q@Wq^T + bq
        (const short*)w_qbf, DIMC, (const short*)w_wqbf, DIMC,
        w_eq, DIMC, DIMC, bq);
    eq_head_norms<<<NROWS / 4, 256, 0, stream>>>(w_eq, w_hinv);
    gemm_abt<<<dim3(2, 256, 8), 256, 0, stream>>>(            // sims (fp32)
        w_eq, DIMC, w_kn, HD, w_sims, HEADS * SLOTS,
        NROWS, SLOTS, HD, nullptr, HD, SLOTS * HD, SLOTS);
    key_softmax<<<NROWS, 256, 0, stream>>>(w_sims, w_kadd, w_hinv);
    gemm_bf16<<<dim3(4, 128), 256, 0, stream>>>(              // vir_pre = kadd@W2T^T + bl
        (const short*)w_kadd, 2 * HEADS * SLOTS, (const short*)w_w2tbf, HEADS * SLOTS,
        w_eq, DIMC, HEADS * SLOTS, bl);
    vir_te_w<<<NROWS / 4, 256, 0, stream>>>(w_eq, query, g1, b1, g2, b2, out_te);

    // 3) value addressing path (vbf/wvbf/rinv live in dead sims region)
    f32_to_bf16<<<8192, 256, 0, stream>>>(value, w_vbf, NROWS * DIMC);
    f32_to_bf16<<<256, 256, 0, stream>>>(Wv, w_wvbf, DIMC * DIMC);
    gemm_bf16<<<dim3(4, 128), 256, 0, stream>>>(              // ev = v@Wv^T + bv
        (const short*)w_vbf, DIMC, (const short*)w_wvbf, DIMC,
        w_ev, DIMC, DIMC, bv);
    row_rnorm<<<NROWS / 4, 256, 0, stream>>>(w_ev, w_rinv);   // replaces l2norm round-trip
    gemm_abt<<<dim3(2, 256, 1), 256, 0, stream>>>(            // value_sim on RAW ev (fp32)
        w_ev, DIMC, w_vn, DIMC, w_vs, SLOTS,
        NROWS, SLOTS, DIMC, nullptr, 0, 0, 0);
    value_softmax_w<<<NROWS / 4, 256, 0, stream>>>(w_vs, w_rinv);
    gemm_abt<<<dim3(8, 256, 1), 256, 0, stream>>>(            // aud (fp32)
        w_vs, SLOTS, w_vmT, SLOTS, w_ev, DIMC,
        NROWS, DIMC, SLOTS, nullptr, 0, 0, 0);
    aud_epilogue_w<<<NROWS / 4, 256, 0, stream>>>(
        w_ev, value, query, g1, b1, g3, b3, out_tr, out_rc);
}

// Round 2
// 494.266 us; speedup vs baseline: 1.0117x; 1.0117x over previous
//
#include <hip/hip_runtime.h>
#include <math.h>

// Problem constants
#define DIMC   512
#define HEADS  8
#define SLOTS  112
#define HD     64          // DIMC/HEADS
#define NROWS  16384       // B*S = 32*512
#define RADIUSF 16.0f

typedef short short8 __attribute__((ext_vector_type(8)));
typedef float f32x4  __attribute__((ext_vector_type(4)));

__device__ __forceinline__ unsigned short f2bf(float f)
{
    unsigned u = __float_as_uint(f);
    unsigned r = (u + 0x7FFFu + ((u >> 16) & 1u)) >> 16;   // RNE
    return (unsigned short)r;
}

// ---------------------------------------------------------------------------
// DPP-based wave reductions (round-6).
// Round-5 post-mortem: __shfl-based wred chains left aud_epilogue_w at 52 µs,
// 20% HBM BW, VALUBusy 10% — waves stalled in ~21-deep ds_bpermute dependency
// chains on the contended LDS pipe. DPP row_shr/row_bcast runs on the VALU
// (~4-8 cy/step, no LDS traffic): 6 ops per 64-lane reduction, result read
// back uniformly via v_readlane(63).
// ---------------------------------------------------------------------------
#define DPP_ADD(x, ctrl, rmask)                                               \
    (x) += __int_as_float(__builtin_amdgcn_update_dpp(                        \
               0, __float_as_int(x), (ctrl), (rmask), 0xf, true))
#define DPP_MAX(x, ctrl, rmask)                                               \
    (x) = fmaxf((x), __int_as_float(__builtin_amdgcn_update_dpp(              \
               __float_as_int(x), __float_as_int(x), (ctrl), (rmask), 0xf,    \
               false)))

// Full-wave (64-lane) sum, result broadcast (uniform) to all lanes.
__device__ __forceinline__ float wsum64(float x)
{
    DPP_ADD(x, 0x111, 0xf);   // row_shr:1
    DPP_ADD(x, 0x112, 0xf);   // row_shr:2
    DPP_ADD(x, 0x114, 0xf);   // row_shr:4
    DPP_ADD(x, 0x118, 0xf);   // row_shr:8  -> lane15 of each row = row sum
    DPP_ADD(x, 0x142, 0xa);   // row_bcast:15 -> lane31 = sum(0..31), lane63 = sum(32..63)
    DPP_ADD(x, 0x143, 0xc);   // row_bcast:31 -> lane63 = total
    return __int_as_float(__builtin_amdgcn_readlane(__float_as_int(x), 63));
}

__device__ __forceinline__ float wmax64(float x)
{
    DPP_MAX(x, 0x111, 0xf);
    DPP_MAX(x, 0x112, 0xf);
    DPP_MAX(x, 0x114, 0xf);
    DPP_MAX(x, 0x118, 0xf);
    DPP_MAX(x, 0x142, 0xa);
    DPP_MAX(x, 0x143, 0xc);
    return __int_as_float(__builtin_amdgcn_readlane(__float_as_int(x), 63));
}

// Two/four interleaved 64-lane sums (independent chains -> ILP), broadcast.
__device__ __forceinline__ void wsum64_2(float& a, float& b)
{
    DPP_ADD(a, 0x111, 0xf); DPP_ADD(b, 0x111, 0xf);
    DPP_ADD(a, 0x112, 0xf); DPP_ADD(b, 0x112, 0xf);
    DPP_ADD(a, 0x114, 0xf); DPP_ADD(b, 0x114, 0xf);
    DPP_ADD(a, 0x118, 0xf); DPP_ADD(b, 0x118, 0xf);
    DPP_ADD(a, 0x142, 0xa); DPP_ADD(b, 0x142, 0xa);
    DPP_ADD(a, 0x143, 0xc); DPP_ADD(b, 0x143, 0xc);
    a = __int_as_float(__builtin_amdgcn_readlane(__float_as_int(a), 63));
    b = __int_as_float(__builtin_amdgcn_readlane(__float_as_int(b), 63));
}

__device__ __forceinline__ void wsum64_4(float& a, float& b, float& c, float& d)
{
    DPP_ADD(a, 0x111, 0xf); DPP_ADD(b, 0x111, 0xf); DPP_ADD(c, 0x111, 0xf); DPP_ADD(d, 0x111, 0xf);
    DPP_ADD(a, 0x112, 0xf); DPP_ADD(b, 0x112, 0xf); DPP_ADD(c, 0x112, 0xf); DPP_ADD(d, 0x112, 0xf);
    DPP_ADD(a, 0x114, 0xf); DPP_ADD(b, 0x114, 0xf); DPP_ADD(c, 0x114, 0xf); DPP_ADD(d, 0x114, 0xf);
    DPP_ADD(a, 0x118, 0xf); DPP_ADD(b, 0x118, 0xf); DPP_ADD(c, 0x118, 0xf); DPP_ADD(d, 0x118, 0xf);
    DPP_ADD(a, 0x142, 0xa); DPP_ADD(b, 0x142, 0xa); DPP_ADD(c, 0x142, 0xa); DPP_ADD(d, 0x142, 0xa);
    DPP_ADD(a, 0x143, 0xc); DPP_ADD(b, 0x143, 0xc); DPP_ADD(c, 0x143, 0xc); DPP_ADD(d, 0x143, 0xc);
    a = __int_as_float(__builtin_amdgcn_readlane(__float_as_int(a), 63));
    b = __int_as_float(__builtin_amdgcn_readlane(__float_as_int(b), 63));
    c = __int_as_float(__builtin_amdgcn_readlane(__float_as_int(c), 63));
    d = __int_as_float(__builtin_amdgcn_readlane(__float_as_int(d), 63));
}

// Per-32-lane-group sum/max: 5 DPP steps put group sums on lanes 31/63,
// one bpermute (__shfl) broadcasts within each 32-group.
__device__ __forceinline__ float gsum32(float x)
{
    DPP_ADD(x, 0x111, 0xf);
    DPP_ADD(x, 0x112, 0xf);
    DPP_ADD(x, 0x114, 0xf);
    DPP_ADD(x, 0x118, 0xf);
    DPP_ADD(x, 0x142, 0xa);   // lane31 = sum(0..31), lane63 = sum(32..63)
    return __shfl(x, 31, 32);
}

__device__ __forceinline__ float gmax32(float x)
{
    DPP_MAX(x, 0x111, 0xf);
    DPP_MAX(x, 0x112, 0xf);
    DPP_MAX(x, 0x114, 0xf);
    DPP_MAX(x, 0x118, 0xf);
    DPP_MAX(x, 0x142, 0xa);
    return __shfl(x, 31, 32);
}

// ---------------------------------------------------------------------------
// bf16 MFMA GEMM: C(MxN fp32) = A(MxK bf16) @ B(NxK bf16)^T (+ bias[col])
// 128x128 tile, BK=32, 256 threads = 4 waves, each wave a 64x64 quadrant.
// ---------------------------------------------------------------------------
__global__ __launch_bounds__(256)
void gemm_bf16(const short* __restrict__ A, int lda,
               const short* __restrict__ B, int ldb,
               float* __restrict__ C, int ldc,
               int K, const float* __restrict__ bias)
{
    __shared__ short As[128 * 32];
    __shared__ short Bs[128 * 32];
    const int tid  = threadIdx.x;
    const int wave = tid >> 6;
    const int lane = tid & 63;
    const int m0 = blockIdx.y * 128;
    const int n0 = blockIdx.x * 128;
    const int wm = (wave >> 1) * 64;
    const int wn = (wave & 1) * 64;

    const int srow = tid >> 2;
    const int schk = (tid & 3) * 8;

    const int fr = lane & 15;
    const int fq = (lane >> 4) * 8;

    f32x4 acc[4][4] = {};

    const short* Ag = A + (size_t)(m0 + srow) * lda + schk;
    const short* Bg = B + (size_t)(n0 + srow) * ldb + schk;

    for (int k0 = 0; k0 < K; k0 += 32) {
        *(short8*)&As[srow * 32 + schk]        = *(const short8*)(Ag);
        *(short8*)&As[(srow + 64) * 32 + schk] = *(const short8*)(Ag + (size_t)64 * lda);
        *(short8*)&Bs[srow * 32 + schk]        = *(const short8*)(Bg);
        *(short8*)&Bs[(srow + 64) * 32 + schk] = *(const short8*)(Bg + (size_t)64 * ldb);
        Ag += 32; Bg += 32;
        __syncthreads();
        short8 af[4], bf[4];
        #pragma unroll
        for (int i = 0; i < 4; ++i)
            af[i] = *(const short8*)&As[(wm + i * 16 + fr) * 32 + fq];
        #pragma unroll
        for (int j = 0; j < 4; ++j)
            bf[j] = *(const short8*)&Bs[(wn + j * 16 + fr) * 32 + fq];
        #pragma unroll
        for (int i = 0; i < 4; ++i)
            #pragma unroll
            for (int j = 0; j < 4; ++j)
                acc[i][j] = __builtin_amdgcn_mfma_f32_16x16x32_bf16(
                    af[i], bf[j], acc[i][j], 0, 0, 0);
        __syncthreads();
    }

    const int cr = (lane >> 4) * 4;
    const int cc = lane & 15;
    #pragma unroll
    for (int i = 0; i < 4; ++i) {
        const int grow = m0 + wm + i * 16 + cr;
        #pragma unroll
        for (int j = 0; j < 4; ++j) {
            const int gcol = n0 + wn + j * 16 + cc;
            const float bb = bias ? bias[gcol] : 0.f;
            float* cp = C + (size_t)grow * ldc + gcol;
            #pragma unroll
            for (int r = 0; r < 4; ++r)
                cp[(size_t)r * ldc] = acc[i][j][r] + bb;
        }
    }
}

// ---------------------------------------------------------------------------
// Generic tiled fp32 GEMM: C(MxN) = A(MxK) @ B(NxK)^T (+ bias[col])
// ---------------------------------------------------------------------------
__global__ __launch_bounds__(256)
void gemm_abt(const float* __restrict__ A, int lda,
              const float* __restrict__ B, int ldb,
              float* __restrict__ C, int ldc,
              int M, int N, int K,
              const float* __restrict__ bias,
              int aZ, int bZ, int cZ)
{
    __shared__ float As[16][68];
    __shared__ float Bs[16][68];
    A += (size_t)blockIdx.z * aZ;
    B += (size_t)blockIdx.z * bZ;
    C += (size_t)blockIdx.z * cZ;
    const int m0 = blockIdx.y * 64;
    const int n0 = blockIdx.x * 64;
    const int tid = threadIdx.x;
    const int tm = tid >> 4;
    const int tn = tid & 15;
    const int lr = tid >> 2;
    const int lc = (tid & 3) << 2;

    float acc[4][4] = {};

    for (int k0 = 0; k0 < K; k0 += 16) {
        float4 av = make_float4(0.f, 0.f, 0.f, 0.f);
        float4 bv = make_float4(0.f, 0.f, 0.f, 0.f);
        const int am = m0 + lr;
        if (am < M) av = *(const float4*)(A + (size_t)am * lda + k0 + lc);
        const int bn = n0 + lr;
        if (bn < N) bv = *(const float4*)(B + (size_t)bn * ldb + k0 + lc);
        As[lc + 0][lr] = av.x; As[lc + 1][lr] = av.y;
        As[lc + 2][lr] = av.z; As[lc + 3][lr] = av.w;
        Bs[lc + 0][lr] = bv.x; Bs[lc + 1][lr] = bv.y;
        Bs[lc + 2][lr] = bv.z; Bs[lc + 3][lr] = bv.w;
        __syncthreads();
        #pragma unroll
        for (int k = 0; k < 16; ++k) {
            float a[4], b[4];
            #pragma unroll
            for (int i = 0; i < 4; ++i) a[i] = As[k][tm * 4 + i];
            #pragma unroll
            for (int j = 0; j < 4; ++j) b[j] = Bs[k][tn * 4 + j];
            #pragma unroll
            for (int i = 0; i < 4; ++i)
                #pragma unroll
                for (int j = 0; j < 4; ++j)
                    acc[i][j] += a[i] * b[j];
        }
        __syncthreads();
    }

    #pragma unroll
    for (int i = 0; i < 4; ++i) {
        const int row = m0 + tm * 4 + i;
        if (row >= M) continue;
        #pragma unroll
        for (int j = 0; j < 4; ++j) {
            const int col = n0 + tn * 4 + j;
            if (col < N) {
                float v = acc[i][j];
                if (bias) v += bias[col];
                C[(size_t)row * ldc + col] = v;
            }
        }
    }
}

// ---------------------------------------------------------------------------
// Small helpers
// ---------------------------------------------------------------------------
__device__ __forceinline__ float block_sum_256(float v, float* red)
{
    #pragma unroll
    for (int off = 32; off; off >>= 1) v += __shfl_down(v, off, 64);
    const int lane = threadIdx.x & 63, wid = threadIdx.x >> 6;
    __syncthreads();
    if (lane == 0) red[wid] = v;
    __syncthreads();
    return red[0] + red[1] + red[2] + red[3];
}

__global__ void zero_small(float* p, int n)
{
    int i = blockIdx.x * blockDim.x + threadIdx.x;
    if (i < n) p[i] = 0.f;
}

// fp32 -> bf16 (RNE), n multiple of 4
__global__ void f32_to_bf16(const float* __restrict__ src,
                            unsigned short* __restrict__ dst, int n)
{
    int i = (blockIdx.x * blockDim.x + threadIdx.x) * 4;
    if (i >= n) return;
    float4 v = *(const float4*)(src + i);
    ushort4 o;
    o.x = f2bf(v.x); o.y = f2bf(v.y); o.z = f2bf(v.z); o.w = f2bf(v.w);
    *(ushort4*)(dst + i) = o;
}

__global__ void prep_key_norm(const float* __restrict__ km, float* __restrict__ kn)
{
    const int row = blockIdx.x;
    const int lane = threadIdx.x;      // 64 threads
    float v = km[(size_t)row * HD + lane];
    const float s = wsum64(v * v);
    const float inv = 1.f / fmaxf(sqrtf(s), 1e-12f);
    kn[(size_t)row * HD + lane] = v * inv;
}

__global__ void prep_value_norm(const float* __restrict__ vm,
                                float* __restrict__ vn, float* __restrict__ vmT)
{
    const int row = blockIdx.x;        // 0..111
    const int tid = threadIdx.x;       // 256
    __shared__ float red[4];
    const float v0 = vm[(size_t)row * DIMC + tid];
    const float v1 = vm[(size_t)row * DIMC + 256 + tid];
    const float tot = block_sum_256(v0 * v0 + v1 * v1, red);
    const float inv = 1.f / fmaxf(sqrtf(tot), 1e-12f);
    vn[(size_t)row * DIMC + tid]        = v0 * inv;
    vn[(size_t)row * DIMC + 256 + tid]  = v1 * inv;
    vmT[(size_t)tid * SLOTS + row]         = v0;
    vmT[(size_t)(256 + tid) * SLOTS + row] = v1;
}

__global__ void contrastive_kernel(const float* __restrict__ vn, float* __restrict__ outc)
{
    __shared__ float vni[DIMC];
    __shared__ float red[2];
    const int i = blockIdx.x, tid = threadIdx.x;   // 128 threads
    for (int d = tid; d < DIMC; d += 128) vni[d] = vn[(size_t)i * DIMC + d];
    __syncthreads();
    float t = 0.f;
    if (tid < SLOTS) {
        const float* r = vn + (size_t)tid * DIMC;
        float dot = 0.f;
        for (int d = 0; d < DIMC; ++d) dot += vni[d] * r[d];
        const float delta = (tid == i) ? 1.f : 0.f;
        t = fabsf(delta - dot);
    }
    #pragma unroll
    for (int off = 32; off; off >>= 1) t += __shfl_down(t, off, 64);
    if ((tid & 63) == 0) red[tid >> 6] = t;
    __syncthreads();
    if (tid == 0) atomicAdd(outc, 0.5f * (red[0] + red[1]));
}

// Per-(row,head) inverse l2 norm of eq.
// DPP row_shr:1/2/4 keeps each 8-lane group's sum on its top lane (7 mod 8).
__global__ __launch_bounds__(256)
void eq_head_norms(const float* __restrict__ eq, float* __restrict__ hinv)
{
    const int wid  = threadIdx.x >> 6;
    const int lane = threadIdx.x & 63;
    const int r = blockIdx.x * 4 + wid;
    const float4 v0 = *(const float4*)(eq + (size_t)r * DIMC + lane * 8);
    const float4 v1 = *(const float4*)(eq + (size_t)r * DIMC + lane * 8 + 4);
    float s = v0.x * v0.x + v0.y * v0.y + v0.z * v0.z + v0.w * v0.w
            + v1.x * v1.x + v1.y * v1.y + v1.z * v1.z + v1.w * v1.w;
    DPP_ADD(s, 0x111, 0xf);   // row_shr:1
    DPP_ADD(s, 0x112, 0xf);   // row_shr:2
    DPP_ADD(s, 0x114, 0xf);   // row_shr:4 -> lane 7 mod 8 = 8-group sum
    if ((lane & 7) == 7)
        hinv[(size_t)r * HEADS + (lane >> 3)] = 1.f / fmaxf(sqrtf(s), 1e-12f);
}

// Per-row inverse l2 norm over 512 floats (one wave per row)
__global__ __launch_bounds__(256)
void row_rnorm(const float* __restrict__ x, float* __restrict__ rinv)
{
    const int wave = threadIdx.x >> 6, lane = threadIdx.x & 63;
    const int r = blockIdx.x * 4 + wave;
    const float* p = x + (size_t)r * DIMC + lane * 8;
    const float4 a = *(const float4*)p;
    const float4 b = *(const float4*)(p + 4);
    float s = a.x * a.x + a.y * a.y + a.z * a.z + a.w * a.w
            + b.x * b.x + b.y * b.y + b.z * b.z + b.w * b.w;
    s = wsum64(s);
    if (lane == 0) rinv[r] = 1.f / fmaxf(sqrtf(s), 1e-12f);
}

// Per-head softmax over 112 slots of sim row (scaled by RADIUS*hinv),
// bf16 output in place over the same row slot (see round-4 notes).
__global__ __launch_bounds__(256)
void key_softmax(const float* __restrict__ sim, unsigned short* __restrict__ kadd,
                 const float* __restrict__ hinv)
{
    const int r = blockIdx.x, tid = threadIdx.x;
    const int g = tid >> 5, li = tid & 31;
    const float scale = RADIUSF * hinv[(size_t)r * HEADS + g];
    const float* row = sim + (size_t)r * (HEADS * SLOTS) + g * SLOTS;
    unsigned short* orow = kadd + (size_t)r * (2 * HEADS * SLOTS) + g * SLOTS;

    float v[4];
    #pragma unroll
    for (int u = 0; u < 4; ++u) {
        const int s = li + u * 32;
        v[u] = (s < SLOTS) ? row[s] * scale : -1e30f;
    }
    __syncthreads();   // all reads of this row done before any bf16 write
    float mx = gmax32(fmaxf(fmaxf(v[0], v[1]), fmaxf(v[2], v[3])));
    float e[4]; float sum = 0.f;
    #pragma unroll
    for (int u = 0; u < 4; ++u) {
        const int s = li + u * 32;
        e[u] = (s < SLOTS) ? __expf(v[u] - mx) : 0.f;
        sum += e[u];
    }
    sum = gsum32(sum);
    const float invs = 1.f / sum;
    #pragma unroll
    for (int u = 0; u < 4; ++u) {
        const int s = li + u * 32;
        if (s < SLOTS) orow[s] = f2bf(e[u] * invs);
    }
}

// Wave-per-2-rows: vir_pre -> LN(g2,b2) -> +query -> LN(g1,b1) -> out_te
// Round-6: DPP reductions (VALU, no LDS pipe) + 2 independent rows per wave
// for chain-level ILP and doubled memory-level parallelism.
__global__ __launch_bounds__(256, 4)
void vir_te_w(const float* __restrict__ vir_pre, const float* __restrict__ query,
              const float* __restrict__ g1, const float* __restrict__ b1,
              const float* __restrict__ g2, const float* __restrict__ b2,
              float* __restrict__ out_te)
{
    const int wave = threadIdx.x >> 6, lane = threadIdx.x & 63;
    const int r0 = blockIdx.x * 8 + wave * 2;
    const int c0 = lane * 8;

    float x[2][8], q[2][8];
    #pragma unroll
    for (int p = 0; p < 2; ++p) {
        const size_t base = (size_t)(r0 + p) * DIMC + c0;
        *(f32x4*)&x[p][0] = *(const f32x4*)(vir_pre + base);
        *(f32x4*)&x[p][4] = *(const f32x4*)(vir_pre + base + 4);
        *(f32x4*)&q[p][0] = *(const f32x4*)(query + base);
        *(f32x4*)&q[p][4] = *(const f32x4*)(query + base + 4);
    }
    float gg2[8], bb2[8], gg1[8], bb1[8];
    *(f32x4*)&gg2[0] = *(const f32x4*)(g2 + c0);
    *(f32x4*)&gg2[4] = *(const f32x4*)(g2 + c0 + 4);
    *(f32x4*)&bb2[0] = *(const f32x4*)(b2 + c0);
    *(f32x4*)&bb2[4] = *(const f32x4*)(b2 + c0 + 4);
    *(f32x4*)&gg1[0] = *(const f32x4*)(g1 + c0);
    *(f32x4*)&gg1[4] = *(const f32x4*)(g1 + c0 + 4);
    *(f32x4*)&bb1[0] = *(const f32x4*)(b1 + c0);
    *(f32x4*)&bb1[4] = *(const f32x4*)(b1 + c0 + 4);

    // Pass 1 partials for both rows, reduced as 4 interleaved DPP chains.
    float s1[2] = {0.f, 0.f}, s2[2] = {0.f, 0.f};
    #pragma unroll
    for (int p = 0; p < 2; ++p)
        #pragma unroll
        for (int i = 0; i < 8; ++i) {
            s1[p] += x[p][i];
            s2[p] += x[p][i] * x[p][i];
        }
    wsum64_4(s1[0], s2[0], s1[1], s2[1]);

    float y[2][8];
    float t1[2] = {0.f, 0.f}, t2[2] = {0.f, 0.f};
    #pragma unroll
    for (int p = 0; p < 2; ++p) {
        const float mu = s1[p] * (1.f / DIMC);
        const float var = s2[p] * (1.f / DIMC) - mu * mu;
        const float rstd = rsqrtf(var + 1e-5f);
        #pragma unroll
        for (int i = 0; i < 8; ++i) {
            const float v = (x[p][i] - mu) * rstd * gg2[i] + bb2[i];
            y[p][i] = q[p][i] + v;
            t1[p] += y[p][i];
            t2[p] += y[p][i] * y[p][i];
        }
    }
    wsum64_4(t1[0], t2[0], t1[1], t2[1]);

    #pragma unroll
    for (int p = 0; p < 2; ++p) {
        const float mu = t1[p] * (1.f / DIMC);
        const float var = t2[p] * (1.f / DIMC) - mu * mu;
        const float rstd = rsqrtf(var + 1e-5f);
        float o[8];
        #pragma unroll
        for (int i = 0; i < 8; ++i)
            o[i] = (y[p][i] - mu) * rstd * gg1[i] + bb1[i];
        const size_t base = (size_t)(r0 + p) * DIMC + c0;
        *(float4*)(out_te + base)     = make_float4(o[0], o[1], o[2], o[3]);
        *(float4*)(out_te + base + 4) = make_float4(o[4], o[5], o[6], o[7]);
    }
}

// Wave-per-row softmax(RADIUS * rinv[r] * sim) over 112 slots, in place.
__global__ __launch_bounds__(256)
void value_softmax_w(float* __restrict__ vs, const float* __restrict__ rinv)
{
    const int wave = threadIdx.x >> 6, lane = threadIdx.x & 63;
    const int r = blockIdx.x * 4 + wave;
    const float scale = RADIUSF * rinv[r];
    float* row = vs + (size_t)r * SLOTS;
    const float v0 = row[lane] * scale;
    const float v1 = (lane < 48) ? row[64 + lane] * scale : -1e30f;
    const float m = wmax64(fmaxf(v0, v1));
    const float e0 = __expf(v0 - m);
    const float e1 = (lane < 48) ? __expf(v1 - m) : 0.f;
    const float s = wsum64(e0 + e1);
    const float inv = 1.f / s;
    row[lane] = e0 * inv;
    if (lane < 48) row[64 + lane] = e1 * inv;
}

// Wave-per-2-rows: cos/recon, LN(g3,b3), +query, LN(g1,b1) -> out_tr.
// Round-6: DPP reductions + 2 rows/wave (see vir_te_w comment). One recon
// atomic per block (8 rows share the same batch index: 8 | 512).
__global__ __launch_bounds__(256, 4)
void aud_epilogue_w(const float* __restrict__ aud, const float* __restrict__ value,
                    const float* __restrict__ query,
                    const float* __restrict__ g1, const float* __restrict__ b1,
                    const float* __restrict__ g3, const float* __restrict__ b3,
                    float* __restrict__ out_tr, float* __restrict__ recon)
{
    __shared__ float red[4];
    const int wave = threadIdx.x >> 6, lane = threadIdx.x & 63;
    const int r0 = blockIdx.x * 8 + wave * 2;
    const int c0 = lane * 8;

    float a[2][8], v[2][8], q[2][8];
    #pragma unroll
    for (int p = 0; p < 2; ++p) {
        const size_t base = (size_t)(r0 + p) * DIMC + c0;
        *(f32x4*)&a[p][0] = *(const f32x4*)(aud + base);
        *(f32x4*)&a[p][4] = *(const f32x4*)(aud + base + 4);
        *(f32x4*)&v[p][0] = *(const f32x4*)(value + base);
        *(f32x4*)&v[p][4] = *(const f32x4*)(value + base + 4);
        *(f32x4*)&q[p][0] = *(const f32x4*)(query + base);
        *(f32x4*)&q[p][4] = *(const f32x4*)(query + base + 4);
    }
    float gg3[8], bb3[8], gg1[8], bb1[8];
    *(f32x4*)&gg3[0] = *(const f32x4*)(g3 + c0);
    *(f32x4*)&gg3[4] = *(const f32x4*)(g3 + c0 + 4);
    *(f32x4*)&bb3[0] = *(const f32x4*)(b3 + c0);
    *(f32x4*)&bb3[4] = *(const f32x4*)(b3 + c0 + 4);
    *(f32x4*)&gg1[0] = *(const f32x4*)(g1 + c0);
    *(f32x4*)&gg1[4] = *(const f32x4*)(g1 + c0 + 4);
    *(f32x4*)&bb1[0] = *(const f32x4*)(b1 + c0);
    *(f32x4*)&bb1[4] = *(const f32x4*)(b1 + c0 + 4);

    float dot[2] = {0.f, 0.f}, na[2] = {0.f, 0.f};
    float nv[2] = {0.f, 0.f}, s1[2] = {0.f, 0.f};
    #pragma unroll
    for (int p = 0; p < 2; ++p)
        #pragma unroll
        for (int i = 0; i < 8; ++i) {
            dot[p] += a[p][i] * v[p][i];
            na[p]  += a[p][i] * a[p][i];
            nv[p]  += v[p][i] * v[p][i];
            s1[p]  += a[p][i];
        }
    wsum64_4(dot[0], na[0], nv[0], s1[0]);
    wsum64_4(dot[1], na[1], nv[1], s1[1]);

    float rloc = 0.f;
    #pragma unroll
    for (int p = 0; p < 2; ++p) {
        const float cosv = dot[p] / fmaxf(sqrtf(na[p]) * sqrtf(nv[p]), 1e-8f);
        rloc += fabsf(1.f - cosv);
    }
    if (lane == 0) red[wave] = rloc;

    float y[2][8];
    float t1[2] = {0.f, 0.f}, t2[2] = {0.f, 0.f};
    #pragma unroll
    for (int p = 0; p < 2; ++p) {
        const float mu = s1[p] * (1.f / DIMC);
        const float var = na[p] * (1.f / DIMC) - mu * mu;   // na == sum(a^2)
        const float rstd = rsqrtf(var + 1e-5f);
        #pragma unroll
        for (int i = 0; i < 8; ++i) {
            const float w = (a[p][i] - mu) * rstd * gg3[i] + bb3[i];
            y[p][i] = q[p][i] + w;
            t1[p] += y[p][i];
            t2[p] += y[p][i] * y[p][i];
        }
    }
    wsum64_4(t1[0], t2[0], t1[1], t2[1]);

    #pragma unroll
    for (int p = 0; p < 2; ++p) {
        const float mu = t1[p] * (1.f / DIMC);
        const float var = t2[p] * (1.f / DIMC) - mu * mu;
        const float rstd = rsqrtf(var + 1e-5f);
        float o[8];
        #pragma unroll
        for (int i = 0; i < 8; ++i)
            o[i] = (y[p][i] - mu) * rstd * gg1[i] + bb1[i];
        const size_t base = (size_t)(r0 + p) * DIMC + c0;
        *(float4*)(out_tr + base)     = make_float4(o[0], o[1], o[2], o[3]);
        *(float4*)(out_tr + base + 4) = make_float4(o[4], o[5], o[6], o[7]);
    }

    __syncthreads();
    if (threadIdx.x == 0)
        atomicAdd(&recon[r0 >> 9], red[0] + red[1] + red[2] + red[3]);
}

// ---------------------------------------------------------------------------
// Launch
// ---------------------------------------------------------------------------
extern "C" void kernel_launch(void* const* d_in, const int* in_sizes, int n_in,
                              void* d_out, int out_size, void* d_ws, size_t ws_size,
                              hipStream_t stream)
{
    const float* query = (const float*)d_in[0];
    const float* value = (const float*)d_in[1];
    const float* keym  = (const float*)d_in[2];
    const float* vmem  = (const float*)d_in[3];
    const float* Wq    = (const float*)d_in[4];
    const float* bq    = (const float*)d_in[5];
    const float* Wv    = (const float*)d_in[6];
    const float* bv    = (const float*)d_in[7];
    const float* Wl    = (const float*)d_in[8];
    const float* bl    = (const float*)d_in[9];
    const float* g1    = (const float*)d_in[10];
    const float* b1    = (const float*)d_in[11];
    const float* g2    = (const float*)d_in[12];
    const float* b2    = (const float*)d_in[13];
    const float* g3    = (const float*)d_in[14];
    const float* b3    = (const float*)d_in[15];

    float* out    = (float*)d_out;
    float* out_te = out;
    float* out_tr = out + 8388608;
    float* out_rc = out + 16777216;    // 32 recon + 1 contrastive

    // Workspace layout (float offsets). Total 34,054,144 floats = 136.2 MB.
    float* ws = (float*)d_ws;
    float* w_kn   = ws + 0;         //   896*64
    float* w_vn   = ws + 57344;     //   112*512
    float* w_vmT  = ws + 114688;    //   512*112
    float* w_W2T  = ws + 172032;    //   512*896 fp32
    float* w_hinv = ws + 630784;    // 16384*8
    float* w_eq   = ws + 761856;    // 16384*512 fp32 (eq -> vir_pre)
    float* w_sims = ws + 9150464;   // 16384*896 fp32 [9150464, 23830528)
    float* w_ev   = ws + 23830528;  // 16384*512 fp32 [23830528, 32219136) (ev -> aud)
    float* w_vs   = ws + 32219136;  // 16384*112 fp32

    // bf16 staging aliases (lifetimes verified against stream order, round 4):
    unsigned short* w_qbf   = (unsigned short*)(ws + 23830528); // in w_ev region
    unsigned short* w_wqbf  = (unsigned short*)(ws + 28024832);
    unsigned short* w_w2tbf = (unsigned short*)(ws + 28155904);
    unsigned short* w_kadd  = (unsigned short*)(ws + 9150464);  // in place over sims
    unsigned short* w_vbf   = (unsigned short*)(ws + 9150464);  // sims region, dead post-vir
    unsigned short* w_wvbf  = (unsigned short*)(ws + 13344768);
    float*          w_rinv  = ws + 13475840;                    // 16384 fp32, sims region

    // 0) zero recon+contrastive
    zero_small<<<1, 64, 0, stream>>>(out_rc, 33);

    // 1) input-only precomputes
    prep_key_norm<<<896, 64, 0, stream>>>(keym, w_kn);
    prep_value_norm<<<112, 256, 0, stream>>>(vmem, w_vn, w_vmT);
    contrastive_kernel<<<112, 128, 0, stream>>>(w_vn, out_rc + 32);
    gemm_abt<<<dim3(2, 8, 8), 256, 0, stream>>>(              // W2T fp32
        Wl, 4096, vmem, DIMC, w_W2T, HEADS * SLOTS,
        DIMC, SLOTS, DIMC, nullptr, DIMC, 0, SLOTS);
    f32_to_bf16<<<448, 256, 0, stream>>>(w_W2T, w_w2tbf, DIMC * HEADS * SLOTS);

    // 2) key addressing path
    f32_to_bf16<<<8192, 256, 0, stream>>>(query, w_qbf, NROWS * DIMC);
    f32_to_bf16<<<256, 256, 0, stream>>>(Wq, w_wqbf, DIMC * DIMC);
    gemm_bf16<<<dim3(4, 128), 256, 0, stream>>>(              // eq = q@Wq^T + bq
        (const short*)w_qbf, DIMC, (const short*)w_wqbf, DIMC,
        w_eq, DIMC, DIMC, bq);
    eq_head_norms<<<NROWS / 4, 256, 0, stream>>>(w_eq, w_hinv);
    gemm_abt<<<dim3(2, 256, 8), 256, 0, stream>>>(            // sims (fp32)
        w_eq, DIMC, w_kn, HD, w_sims, HEADS * SLOTS,
        NROWS, SLOTS, HD, nullptr, HD, SLOTS * HD, SLOTS);
    key_softmax<<<NROWS, 256, 0, stream>>>(w_sims, w_kadd, w_hinv);
    gemm_bf16<<<dim3(4, 128), 256, 0, stream>>>(              // vir_pre = kadd@W2T^T + bl
        (const short*)w_kadd, 2 * HEADS * SLOTS, (const short*)w_w2tbf, HEADS * SLOTS,
        w_eq, DIMC, HEADS * SLOTS, bl);
    vir_te_w<<<NROWS / 8, 256, 0, stream>>>(w_eq, query, g1, b1, g2, b2, out_te);

    // 3) value addressing path (vbf/wvbf/rinv live in dead sims region)
    f32_to_bf16<<<8192, 256, 0, stream>>>(value, w_vbf, NROWS * DIMC);
    f32_to_bf16<<<256, 256, 0, stream>>>(Wv, w_wvbf, DIMC * DIMC);
    gemm_bf16<<<dim3(4, 128), 256, 0, stream>>>(              // ev = v@Wv^T + bv
        (const short*)w_vbf, DIMC, (const short*)w_wvbf, DIMC,
        w_ev, DIMC, DIMC, bv);
    row_rnorm<<<NROWS / 4, 256, 0, stream>>>(w_ev, w_rinv);   // replaces l2norm round-trip
    gemm_abt<<<dim3(2, 256, 1), 256, 0, stream>>>(            // value_sim on RAW ev (fp32)
        w_ev, DIMC, w_vn, DIMC, w_vs, SLOTS,
        NROWS, SLOTS, DIMC, nullptr, 0, 0, 0);
    value_softmax_w<<<NROWS / 4, 256, 0, stream>>>(w_vs, w_rinv);
    gemm_abt<<<dim3(8, 256, 1), 256, 0, stream>>>(            // aud (fp32)
        w_vs, SLOTS, w_vmT, SLOTS, w_ev, DIMC,
        NROWS, DIMC, SLOTS, nullptr, 0, 0, 0);
    aud_epilogue_w<<<NROWS / 8, 256, 0, stream>>>(
        w_ev, value, query, g1, b1, g3, b3, out_tr, out_rc);
}

// Round 3
// 402.416 us; speedup vs baseline: 1.2426x; 1.2282x over previous
//
#include <hip/hip_runtime.h>
#include <math.h>

// Problem constants
#define DIMC   512
#define HEADS  8
#define SLOTS  112
#define HD     64          // DIMC/HEADS
#define NROWS  16384       // B*S = 32*512
#define RADIUSF 16.0f

typedef short short8 __attribute__((ext_vector_type(8)));
typedef unsigned short ushort8 __attribute__((ext_vector_type(8)));
typedef float f32x4  __attribute__((ext_vector_type(4)));

__device__ __forceinline__ unsigned short f2bf(float f)
{
    unsigned u = __float_as_uint(f);
    unsigned r = (u + 0x7FFFu + ((u >> 16) & 1u)) >> 16;   // RNE
    return (unsigned short)r;
}
__device__ __forceinline__ float bf2f(unsigned short h)
{
    return __uint_as_float((unsigned)h << 16);
}

// ---------------------------------------------------------------------------
// DPP-based wave reductions (round-6; validated round 2 — epilogues left the
// top-5). VALU-only, no LDS pipe.
// ---------------------------------------------------------------------------
#define DPP_ADD(x, ctrl, rmask)                                               \
    (x) += __int_as_float(__builtin_amdgcn_update_dpp(                        \
               0, __float_as_int(x), (ctrl), (rmask), 0xf, true))
#define DPP_MAX(x, ctrl, rmask)                                               \
    (x) = fmaxf((x), __int_as_float(__builtin_amdgcn_update_dpp(              \
               __float_as_int(x), __float_as_int(x), (ctrl), (rmask), 0xf,    \
               false)))

__device__ __forceinline__ float wsum64(float x)
{
    DPP_ADD(x, 0x111, 0xf);
    DPP_ADD(x, 0x112, 0xf);
    DPP_ADD(x, 0x114, 0xf);
    DPP_ADD(x, 0x118, 0xf);
    DPP_ADD(x, 0x142, 0xa);
    DPP_ADD(x, 0x143, 0xc);
    return __int_as_float(__builtin_amdgcn_readlane(__float_as_int(x), 63));
}

__device__ __forceinline__ float wmax64(float x)
{
    DPP_MAX(x, 0x111, 0xf);
    DPP_MAX(x, 0x112, 0xf);
    DPP_MAX(x, 0x114, 0xf);
    DPP_MAX(x, 0x118, 0xf);
    DPP_MAX(x, 0x142, 0xa);
    DPP_MAX(x, 0x143, 0xc);
    return __int_as_float(__builtin_amdgcn_readlane(__float_as_int(x), 63));
}

__device__ __forceinline__ void wsum64_4(float& a, float& b, float& c, float& d)
{
    DPP_ADD(a, 0x111, 0xf); DPP_ADD(b, 0x111, 0xf); DPP_ADD(c, 0x111, 0xf); DPP_ADD(d, 0x111, 0xf);
    DPP_ADD(a, 0x112, 0xf); DPP_ADD(b, 0x112, 0xf); DPP_ADD(c, 0x112, 0xf); DPP_ADD(d, 0x112, 0xf);
    DPP_ADD(a, 0x114, 0xf); DPP_ADD(b, 0x114, 0xf); DPP_ADD(c, 0x114, 0xf); DPP_ADD(d, 0x114, 0xf);
    DPP_ADD(a, 0x118, 0xf); DPP_ADD(b, 0x118, 0xf); DPP_ADD(c, 0x118, 0xf); DPP_ADD(d, 0x118, 0xf);
    DPP_ADD(a, 0x142, 0xa); DPP_ADD(b, 0x142, 0xa); DPP_ADD(c, 0x142, 0xa); DPP_ADD(d, 0x142, 0xa);
    DPP_ADD(a, 0x143, 0xc); DPP_ADD(b, 0x143, 0xc); DPP_ADD(c, 0x143, 0xc); DPP_ADD(d, 0x143, 0xc);
    a = __int_as_float(__builtin_amdgcn_readlane(__float_as_int(a), 63));
    b = __int_as_float(__builtin_amdgcn_readlane(__float_as_int(b), 63));
    c = __int_as_float(__builtin_amdgcn_readlane(__float_as_int(c), 63));
    d = __int_as_float(__builtin_amdgcn_readlane(__float_as_int(d), 63));
}

__device__ __forceinline__ float gsum32(float x)
{
    DPP_ADD(x, 0x111, 0xf);
    DPP_ADD(x, 0x112, 0xf);
    DPP_ADD(x, 0x114, 0xf);
    DPP_ADD(x, 0x118, 0xf);
    DPP_ADD(x, 0x142, 0xa);
    return __shfl(x, 31, 32);
}

__device__ __forceinline__ float gmax32(float x)
{
    DPP_MAX(x, 0x111, 0xf);
    DPP_MAX(x, 0x112, 0xf);
    DPP_MAX(x, 0x114, 0xf);
    DPP_MAX(x, 0x118, 0xf);
    DPP_MAX(x, 0x142, 0xa);
    return __shfl(x, 31, 32);
}

// ---------------------------------------------------------------------------
// bf16 MFMA GEMM: C(MxN fp32) / Cb(MxN bf16) = A(MxK bf16) @ B(NxK bf16)^T
// (+ bias[col]). 128x128 tile, BK=32, 256 threads = 4 waves.
// Round-7: replaced ALL fp32 gemm_abt uses (value_sim was 46 µs at 16.5%
// occupancy / VALUBusy 35% / MfmaUtil 0 — latency-bound VALU GEMM at 2
// blocks/CU). Additions: Nvalid store-mask for N=112 (B padded to 128 rows),
// optional fp32 (C) and/or bf16 (Cb) outputs (skip dead fp32 stores),
// z-batch element offsets aZ/bZ/cZ for per-head batching.
// ---------------------------------------------------------------------------
__global__ __launch_bounds__(256)
void gemm_bf16(const short* __restrict__ A, int lda,
               const short* __restrict__ B, int ldb,
               float* __restrict__ C, unsigned short* __restrict__ Cb,
               int ldc, int K, const float* __restrict__ bias, int Nvalid,
               int aZ, int bZ, int cZ)
{
    __shared__ short As[128 * 32];
    __shared__ short Bs[128 * 32];
    A += (size_t)blockIdx.z * aZ;
    B += (size_t)blockIdx.z * bZ;
    const size_t czoff = (size_t)blockIdx.z * cZ;
    const int tid  = threadIdx.x;
    const int wave = tid >> 6;
    const int lane = tid & 63;
    const int m0 = blockIdx.y * 128;
    const int n0 = blockIdx.x * 128;
    const int wm = (wave >> 1) * 64;
    const int wn = (wave & 1) * 64;

    const int srow = tid >> 2;
    const int schk = (tid & 3) * 8;

    const int fr = lane & 15;
    const int fq = (lane >> 4) * 8;

    f32x4 acc[4][4] = {};

    const short* Ag = A + (size_t)(m0 + srow) * lda + schk;
    const short* Bg = B + (size_t)(n0 + srow) * ldb + schk;

    for (int k0 = 0; k0 < K; k0 += 32) {
        *(short8*)&As[srow * 32 + schk]        = *(const short8*)(Ag);
        *(short8*)&As[(srow + 64) * 32 + schk] = *(const short8*)(Ag + (size_t)64 * lda);
        *(short8*)&Bs[srow * 32 + schk]        = *(const short8*)(Bg);
        *(short8*)&Bs[(srow + 64) * 32 + schk] = *(const short8*)(Bg + (size_t)64 * ldb);
        Ag += 32; Bg += 32;
        __syncthreads();
        short8 af[4], bf[4];
        #pragma unroll
        for (int i = 0; i < 4; ++i)
            af[i] = *(const short8*)&As[(wm + i * 16 + fr) * 32 + fq];
        #pragma unroll
        for (int j = 0; j < 4; ++j)
            bf[j] = *(const short8*)&Bs[(wn + j * 16 + fr) * 32 + fq];
        #pragma unroll
        for (int i = 0; i < 4; ++i)
            #pragma unroll
            for (int j = 0; j < 4; ++j)
                acc[i][j] = __builtin_amdgcn_mfma_f32_16x16x32_bf16(
                    af[i], bf[j], acc[i][j], 0, 0, 0);
        __syncthreads();
    }

    const int cr = (lane >> 4) * 4;
    const int cc = lane & 15;
    #pragma unroll
    for (int i = 0; i < 4; ++i) {
        const int grow = m0 + wm + i * 16 + cr;
        #pragma unroll
        for (int j = 0; j < 4; ++j) {
            const int gcol = n0 + wn + j * 16 + cc;
            if (gcol < Nvalid) {
                const float bb = bias ? bias[gcol] : 0.f;
                const size_t base = czoff + (size_t)grow * ldc + gcol;
                #pragma unroll
                for (int r = 0; r < 4; ++r) {
                    const float val = acc[i][j][r] + bb;
                    if (C)  C[base + (size_t)r * ldc]  = val;
                    if (Cb) Cb[base + (size_t)r * ldc] = f2bf(val);
                }
            }
        }
    }
}

// ---------------------------------------------------------------------------
// Small helpers
// ---------------------------------------------------------------------------
__device__ __forceinline__ float block_sum_256(float v, float* red)
{
    #pragma unroll
    for (int off = 32; off; off >>= 1) v += __shfl_down(v, off, 64);
    const int lane = threadIdx.x & 63, wid = threadIdx.x >> 6;
    __syncthreads();
    if (lane == 0) red[wid] = v;
    __syncthreads();
    return red[0] + red[1] + red[2] + red[3];
}

__global__ void zero_small(float* p, int n)
{
    int i = blockIdx.x * blockDim.x + threadIdx.x;
    if (i < n) p[i] = 0.f;
}

// fp32 -> bf16 (RNE), n multiple of 4
__global__ void f32_to_bf16(const float* __restrict__ src,
                            unsigned short* __restrict__ dst, int n)
{
    int i = (blockIdx.x * blockDim.x + threadIdx.x) * 4;
    if (i >= n) return;
    float4 v = *(const float4*)(src + i);
    ushort4 o;
    o.x = f2bf(v.x); o.y = f2bf(v.y); o.z = f2bf(v.z); o.w = f2bf(v.w);
    *(ushort4*)(dst + i) = o;
}

// key_mem row-normalize -> bf16, padded to 128 slots/head ([8][128][64] bf16).
// grid 1024 = 8 heads x 128 slots; pad slots write zeros.
__global__ void prep_key_norm(const float* __restrict__ km,
                              unsigned short* __restrict__ knb)
{
    const int row = blockIdx.x;         // h*128+s
    const int h = row >> 7, s = row & 127;
    const int lane = threadIdx.x;       // 64 threads
    const float v = (s < SLOTS) ? km[(size_t)(h * SLOTS + s) * HD + lane] : 0.f;
    const float ssum = wsum64(v * v);
    const float inv = 1.f / fmaxf(sqrtf(ssum), 1e-12f);
    knb[(size_t)row * HD + lane] = f2bf(v * inv);
}

// value_mem: vn fp32 (for contrastive), vn bf16 padded [128][512],
// vmem^T bf16 padded [512][128].
__global__ void prep_value_norm(const float* __restrict__ vm,
                                float* __restrict__ vn,
                                unsigned short* __restrict__ vnb,
                                unsigned short* __restrict__ vmTb)
{
    const int row = blockIdx.x;        // 0..111
    const int tid = threadIdx.x;       // 256
    __shared__ float red[4];
    const float v0 = vm[(size_t)row * DIMC + tid];
    const float v1 = vm[(size_t)row * DIMC + 256 + tid];
    const float tot = block_sum_256(v0 * v0 + v1 * v1, red);
    const float inv = 1.f / fmaxf(sqrtf(tot), 1e-12f);
    vn[(size_t)row * DIMC + tid]        = v0 * inv;
    vn[(size_t)row * DIMC + 256 + tid]  = v1 * inv;
    vnb[(size_t)row * DIMC + tid]       = f2bf(v0 * inv);
    vnb[(size_t)row * DIMC + 256 + tid] = f2bf(v1 * inv);
    vmTb[(size_t)tid * 128 + row]         = f2bf(v0);
    vmTb[(size_t)(256 + tid) * 128 + row] = f2bf(v1);
}

__global__ void contrastive_kernel(const float* __restrict__ vn, float* __restrict__ outc)
{
    __shared__ float vni[DIMC];
    __shared__ float red[2];
    const int i = blockIdx.x, tid = threadIdx.x;   // 128 threads
    for (int d = tid; d < DIMC; d += 128) vni[d] = vn[(size_t)i * DIMC + d];
    __syncthreads();
    float t = 0.f;
    if (tid < SLOTS) {
        const float* r = vn + (size_t)tid * DIMC;
        float dot = 0.f;
        for (int d = 0; d < DIMC; ++d) dot += vni[d] * r[d];
        const float delta = (tid == i) ? 1.f : 0.f;
        t = fabsf(delta - dot);
    }
    #pragma unroll
    for (int off = 32; off; off >>= 1) t += __shfl_down(t, off, 64);
    if ((tid & 63) == 0) red[tid >> 6] = t;
    __syncthreads();
    if (tid == 0) atomicAdd(outc, 0.5f * (red[0] + red[1]));
}

// Per-(row,head) inverse l2 norm of eq (bf16 input — consistent with the
// bf16 values the sims MFMA consumes).
__global__ __launch_bounds__(256)
void eq_head_norms(const unsigned short* __restrict__ eq, float* __restrict__ hinv)
{
    const int wid  = threadIdx.x >> 6;
    const int lane = threadIdx.x & 63;
    const int r = blockIdx.x * 4 + wid;
    const ushort8 u = *(const ushort8*)(eq + (size_t)r * DIMC + lane * 8);
    float s = 0.f;
    #pragma unroll
    for (int i = 0; i < 8; ++i) {
        const float f = bf2f(u[i]);
        s += f * f;
    }
    DPP_ADD(s, 0x111, 0xf);
    DPP_ADD(s, 0x112, 0xf);
    DPP_ADD(s, 0x114, 0xf);   // lane 7 mod 8 = 8-lane-group (64-elem) sum
    if ((lane & 7) == 7)
        hinv[(size_t)r * HEADS + (lane >> 3)] = 1.f / fmaxf(sqrtf(s), 1e-12f);
}

// Per-row inverse l2 norm over 512 bf16 (one wave per row)
__global__ __launch_bounds__(256)
void row_rnorm(const unsigned short* __restrict__ x, float* __restrict__ rinv)
{
    const int wave = threadIdx.x >> 6, lane = threadIdx.x & 63;
    const int r = blockIdx.x * 4 + wave;
    const ushort8 u = *(const ushort8*)(x + (size_t)r * DIMC + lane * 8);
    float s = 0.f;
    #pragma unroll
    for (int i = 0; i < 8; ++i) {
        const float f = bf2f(u[i]);
        s += f * f;
    }
    s = wsum64(s);
    if (lane == 0) rinv[r] = 1.f / fmaxf(sqrtf(s), 1e-12f);
}

// Per-head softmax over 112 slots of sim row (scaled by RADIUS*hinv),
// bf16 output in place over the same row slot (round-4 in-place trick).
__global__ __launch_bounds__(256)
void key_softmax(const float* __restrict__ sim, unsigned short* __restrict__ kadd,
                 const float* __restrict__ hinv)
{
    const int r = blockIdx.x, tid = threadIdx.x;
    const int g = tid >> 5, li = tid & 31;
    const float scale = RADIUSF * hinv[(size_t)r * HEADS + g];
    const float* row = sim + (size_t)r * (HEADS * SLOTS) + g * SLOTS;
    unsigned short* orow = kadd + (size_t)r * (2 * HEADS * SLOTS) + g * SLOTS;

    float v[4];
    #pragma unroll
    for (int u = 0; u < 4; ++u) {
        const int s = li + u * 32;
        v[u] = (s < SLOTS) ? row[s] * scale : -1e30f;
    }
    __syncthreads();   // all reads of this row done before any bf16 write
    float mx = gmax32(fmaxf(fmaxf(v[0], v[1]), fmaxf(v[2], v[3])));
    float e[4]; float sum = 0.f;
    #pragma unroll
    for (int u = 0; u < 4; ++u) {
        const int s = li + u * 32;
        e[u] = (s < SLOTS) ? __expf(v[u] - mx) : 0.f;
        sum += e[u];
    }
    sum = gsum32(sum);
    const float invs = 1.f / sum;
    #pragma unroll
    for (int u = 0; u < 4; ++u) {
        const int s = li + u * 32;
        if (s < SLOTS) orow[s] = f2bf(e[u] * invs);
    }
}

// Wave-per-2-rows: vir_pre -> LN(g2,b2) -> +query -> LN(g1,b1) -> out_te
__global__ __launch_bounds__(256, 4)
void vir_te_w(const float* __restrict__ vir_pre, const float* __restrict__ query,
              const float* __restrict__ g1, const float* __restrict__ b1,
              const float* __restrict__ g2, const float* __restrict__ b2,
              float* __restrict__ out_te)
{
    const int wave = threadIdx.x >> 6, lane = threadIdx.x & 63;
    const int r0 = blockIdx.x * 8 + wave * 2;
    const int c0 = lane * 8;

    float x[2][8], q[2][8];
    #pragma unroll
    for (int p = 0; p < 2; ++p) {
        const size_t base = (size_t)(r0 + p) * DIMC + c0;
        *(f32x4*)&x[p][0] = *(const f32x4*)(vir_pre + base);
        *(f32x4*)&x[p][4] = *(const f32x4*)(vir_pre + base + 4);
        *(f32x4*)&q[p][0] = *(const f32x4*)(query + base);
        *(f32x4*)&q[p][4] = *(const f32x4*)(query + base + 4);
    }
    float gg2[8], bb2[8], gg1[8], bb1[8];
    *(f32x4*)&gg2[0] = *(const f32x4*)(g2 + c0);
    *(f32x4*)&gg2[4] = *(const f32x4*)(g2 + c0 + 4);
    *(f32x4*)&bb2[0] = *(const f32x4*)(b2 + c0);
    *(f32x4*)&bb2[4] = *(const f32x4*)(b2 + c0 + 4);
    *(f32x4*)&gg1[0] = *(const f32x4*)(g1 + c0);
    *(f32x4*)&gg1[4] = *(const f32x4*)(g1 + c0 + 4);
    *(f32x4*)&bb1[0] = *(const f32x4*)(b1 + c0);
    *(f32x4*)&bb1[4] = *(const f32x4*)(b1 + c0 + 4);

    float s1[2] = {0.f, 0.f}, s2[2] = {0.f, 0.f};
    #pragma unroll
    for (int p = 0; p < 2; ++p)
        #pragma unroll
        for (int i = 0; i < 8; ++i) {
            s1[p] += x[p][i];
            s2[p] += x[p][i] * x[p][i];
        }
    wsum64_4(s1[0], s2[0], s1[1], s2[1]);

    float y[2][8];
    float t1[2] = {0.f, 0.f}, t2[2] = {0.f, 0.f};
    #pragma unroll
    for (int p = 0; p < 2; ++p) {
        const float mu = s1[p] * (1.f / DIMC);
        const float var = s2[p] * (1.f / DIMC) - mu * mu;
        const float rstd = rsqrtf(var + 1e-5f);
        #pragma unroll
        for (int i = 0; i < 8; ++i) {
            const float v = (x[p][i] - mu) * rstd * gg2[i] + bb2[i];
            y[p][i] = q[p][i] + v;
            t1[p] += y[p][i];
            t2[p] += y[p][i] * y[p][i];
        }
    }
    wsum64_4(t1[0], t2[0], t1[1], t2[1]);

    #pragma unroll
    for (int p = 0; p < 2; ++p) {
        const float mu = t1[p] * (1.f / DIMC);
        const float var = t2[p] * (1.f / DIMC) - mu * mu;
        const float rstd = rsqrtf(var + 1e-5f);
        float o[8];
        #pragma unroll
        for (int i = 0; i < 8; ++i)
            o[i] = (y[p][i] - mu) * rstd * gg1[i] + bb1[i];
        const size_t base = (size_t)(r0 + p) * DIMC + c0;
        *(float4*)(out_te + base)     = make_float4(o[0], o[1], o[2], o[3]);
        *(float4*)(out_te + base + 4) = make_float4(o[4], o[5], o[6], o[7]);
    }
}

// Wave-per-row softmax(RADIUS * rinv[r] * vs) over 112 slots (fp32 in,
// stride 112) -> bf16 out padded to 128 cols (zeros in 112..127) for the
// MFMA aud GEMM.
__global__ __launch_bounds__(256)
void value_softmax_w(const float* __restrict__ vs, unsigned short* __restrict__ vsb,
                     const float* __restrict__ rinv)
{
    const int wave = threadIdx.x >> 6, lane = threadIdx.x & 63;
    const int r = blockIdx.x * 4 + wave;
    const float scale = RADIUSF * rinv[r];
    const float* row = vs + (size_t)r * SLOTS;
    const float v0 = row[lane] * scale;
    const float v1 = (lane < 48) ? row[64 + lane] * scale : -1e30f;
    const float m = wmax64(fmaxf(v0, v1));
    const float e0 = __expf(v0 - m);
    const float e1 = (lane < 48) ? __expf(v1 - m) : 0.f;
    const float s = wsum64(e0 + e1);
    const float inv = 1.f / s;
    unsigned short* ob = vsb + (size_t)r * 128;
    ob[lane] = f2bf(e0 * inv);
    ob[64 + lane] = (lane < 48) ? f2bf(e1 * inv) : (unsigned short)0;
}

// Wave-per-2-rows: cos/recon, LN(g3,b3), +query, LN(g1,b1) -> out_tr.
__global__ __launch_bounds__(256, 4)
void aud_epilogue_w(const float* __restrict__ aud, const float* __restrict__ value,
                    const float* __restrict__ query,
                    const float* __restrict__ g1, const float* __restrict__ b1,
                    const float* __restrict__ g3, const float* __restrict__ b3,
                    float* __restrict__ out_tr, float* __restrict__ recon)
{
    __shared__ float red[4];
    const int wave = threadIdx.x >> 6, lane = threadIdx.x & 63;
    const int r0 = blockIdx.x * 8 + wave * 2;
    const int c0 = lane * 8;

    float a[2][8], v[2][8], q[2][8];
    #pragma unroll
    for (int p = 0; p < 2; ++p) {
        const size_t base = (size_t)(r0 + p) * DIMC + c0;
        *(f32x4*)&a[p][0] = *(const f32x4*)(aud + base);
        *(f32x4*)&a[p][4] = *(const f32x4*)(aud + base + 4);
        *(f32x4*)&v[p][0] = *(const f32x4*)(value + base);
        *(f32x4*)&v[p][4] = *(const f32x4*)(value + base + 4);
        *(f32x4*)&q[p][0] = *(const f32x4*)(query + base);
        *(f32x4*)&q[p][4] = *(const f32x4*)(query + base + 4);
    }
    float gg3[8], bb3[8], gg1[8], bb1[8];
    *(f32x4*)&gg3[0] = *(const f32x4*)(g3 + c0);
    *(f32x4*)&gg3[4] = *(const f32x4*)(g3 + c0 + 4);
    *(f32x4*)&bb3[0] = *(const f32x4*)(b3 + c0);
    *(f32x4*)&bb3[4] = *(const f32x4*)(b3 + c0 + 4);
    *(f32x4*)&gg1[0] = *(const f32x4*)(g1 + c0);
    *(f32x4*)&gg1[4] = *(const f32x4*)(g1 + c0 + 4);
    *(f32x4*)&bb1[0] = *(const f32x4*)(b1 + c0);
    *(f32x4*)&bb1[4] = *(const f32x4*)(b1 + c0 + 4);

    float dot[2] = {0.f, 0.f}, na[2] = {0.f, 0.f};
    float nv[2] = {0.f, 0.f}, s1[2] = {0.f, 0.f};
    #pragma unroll
    for (int p = 0; p < 2; ++p)
        #pragma unroll
        for (int i = 0; i < 8; ++i) {
            dot[p] += a[p][i] * v[p][i];
            na[p]  += a[p][i] * a[p][i];
            nv[p]  += v[p][i] * v[p][i];
            s1[p]  += a[p][i];
        }
    wsum64_4(dot[0], na[0], nv[0], s1[0]);
    wsum64_4(dot[1], na[1], nv[1], s1[1]);

    float rloc = 0.f;
    #pragma unroll
    for (int p = 0; p < 2; ++p) {
        const float cosv = dot[p] / fmaxf(sqrtf(na[p]) * sqrtf(nv[p]), 1e-8f);
        rloc += fabsf(1.f - cosv);
    }
    if (lane == 0) red[wave] = rloc;

    float y[2][8];
    float t1[2] = {0.f, 0.f}, t2[2] = {0.f, 0.f};
    #pragma unroll
    for (int p = 0; p < 2; ++p) {
        const float mu = s1[p] * (1.f / DIMC);
        const float var = na[p] * (1.f / DIMC) - mu * mu;   // na == sum(a^2)
        const float rstd = rsqrtf(var + 1e-5f);
        #pragma unroll
        for (int i = 0; i < 8; ++i) {
            const float w = (a[p][i] - mu) * rstd * gg3[i] + bb3[i];
            y[p][i] = q[p][i] + w;
            t1[p] += y[p][i];
            t2[p] += y[p][i] * y[p][i];
        }
    }
    wsum64_4(t1[0], t2[0], t1[1], t2[1]);

    #pragma unroll
    for (int p = 0; p < 2; ++p) {
        const float mu = t1[p] * (1.f / DIMC);
        const float var = t2[p] * (1.f / DIMC) - mu * mu;
        const float rstd = rsqrtf(var + 1e-5f);
        float o[8];
        #pragma unroll
        for (int i = 0; i < 8; ++i)
            o[i] = (y[p][i] - mu) * rstd * gg1[i] + bb1[i];
        const size_t base = (size_t)(r0 + p) * DIMC + c0;
        *(float4*)(out_tr + base)     = make_float4(o[0], o[1], o[2], o[3]);
        *(float4*)(out_tr + base + 4) = make_float4(o[4], o[5], o[6], o[7]);
    }

    __syncthreads();
    if (threadIdx.x == 0)
        atomicAdd(&recon[r0 >> 9], red[0] + red[1] + red[2] + red[3]);
}

// ---------------------------------------------------------------------------
// Launch
// ---------------------------------------------------------------------------
extern "C" void kernel_launch(void* const* d_in, const int* in_sizes, int n_in,
                              void* d_out, int out_size, void* d_ws, size_t ws_size,
                              hipStream_t stream)
{
    const float* query = (const float*)d_in[0];
    const float* value = (const float*)d_in[1];
    const float* keym  = (const float*)d_in[2];
    const float* vmem  = (const float*)d_in[3];
    const float* Wq    = (const float*)d_in[4];
    const float* bq    = (const float*)d_in[5];
    const float* Wv    = (const float*)d_in[6];
    const float* bv    = (const float*)d_in[7];
    const float* Wl    = (const float*)d_in[8];
    const float* bl    = (const float*)d_in[9];
    const float* g1    = (const float*)d_in[10];
    const float* b1    = (const float*)d_in[11];
    const float* g2    = (const float*)d_in[12];
    const float* b2    = (const float*)d_in[13];
    const float* g3    = (const float*)d_in[14];
    const float* b3    = (const float*)d_in[15];

    float* out    = (float*)d_out;
    float* out_te = out;
    float* out_tr = out + 8388608;
    float* out_rc = out + 16777216;    // 32 recon + 1 contrastive

    // Workspace layout (float offsets), round-7. Budget 34,054,144 floats.
    // phase-1 statics:
    //   0        knb    [8][128][64] bf16   32768 fl
    //   32768    vmTb   [512][128]  bf16    32768 fl (raw vmem^T, K-padded)
    //   65536    vnb    [128][512]  bf16    32768 fl (l2norm rows, N-padded)
    //   98304    vn     [112][512]  fp32    57344 fl (contrastive only)
    //   155648   w2tbf  [512][896]  bf16    229376 fl
    //   385024   hinv   [16384][8]  fp32    131072 fl
    //   516096   vmbf   [128][512]  bf16    32768 fl (raw vmem, phase-1 only)
    //   548864   wlbf   [512][4096] bf16    1048576 fl (phase-1 only)
    // big regions (lifetime-multiplexed, stream-ordered):
    //   1597440  BIG1: vir_pre fp32 (key) -> aud fp32 (value)     8388608 fl
    //   9986048  BIG2: eqbf (key) -> evbf (value)                 4194304 fl
    //   14180352 BIG3: sims fp32/kadd overlay (key) ->
    //                  vs fp32 @+0 (1835008), vsb bf16 @+1835008  14680064 fl
    //   28860416 qbf (key) -> vbf (value)                         4194304 fl
    //   33054720 wqbf -> wvbf                                     131072 fl
    //   33185792 rinv                                             16384 fl
    // total 33202176 < 34054144.
    float* ws = (float*)d_ws;
    unsigned short* w_knb  = (unsigned short*)(ws + 0);
    unsigned short* w_vmTb = (unsigned short*)(ws + 32768);
    unsigned short* w_vnb  = (unsigned short*)(ws + 65536);
    float*          w_vn   = ws + 98304;
    unsigned short* w_w2tbf= (unsigned short*)(ws + 155648);
    float*          w_hinv = ws + 385024;
    unsigned short* w_vmbf = (unsigned short*)(ws + 516096);
    unsigned short* w_wlbf = (unsigned short*)(ws + 548864);
    float*          w_big1 = ws + 1597440;   // vir_pre then aud
    unsigned short* w_xbf  = (unsigned short*)(ws + 9986048);   // eqbf then evbf
    float*          w_sims = ws + 14180352;
    unsigned short* w_kadd = (unsigned short*)(ws + 14180352);
    float*          w_vs   = ws + 14180352;                     // after kadd dead
    unsigned short* w_vsb  = (unsigned short*)(ws + 16015360);
    unsigned short* w_qbf  = (unsigned short*)(ws + 28860416);  // then vbf
    unsigned short* w_wqbf = (unsigned short*)(ws + 33054720);  // then wvbf
    float*          w_rinv = ws + 33185792;

    // 0) zero recon+contrastive and bf16 pad regions (vmTb, vnb contiguous)
    zero_small<<<1, 64, 0, stream>>>(out_rc, 33);
    zero_small<<<256, 256, 0, stream>>>(ws + 32768, 65536);   // vmTb + vnb
    zero_small<<<128, 256, 0, stream>>>(ws + 516096, 32768);  // vmbf

    // 1) input-only precomputes
    prep_key_norm<<<1024, 64, 0, stream>>>(keym, w_knb);
    prep_value_norm<<<112, 256, 0, stream>>>(vmem, w_vn, w_vnb, w_vmTb);
    contrastive_kernel<<<112, 128, 0, stream>>>(w_vn, out_rc + 32);
    f32_to_bf16<<<2048, 256, 0, stream>>>(Wl, w_wlbf, DIMC * DIMC * HEADS);
    f32_to_bf16<<<56, 256, 0, stream>>>(vmem, w_vmbf, SLOTS * DIMC);
    // W2T[d][h*112+s] = sum_c Wl[d][h*512+c]*vmem[s][c] -> bf16 direct
    gemm_bf16<<<dim3(1, 4, 8), 256, 0, stream>>>(
        (const short*)w_wlbf, HEADS * DIMC, (const short*)w_vmbf, DIMC,
        nullptr, w_w2tbf, HEADS * SLOTS, DIMC, nullptr, SLOTS,
        DIMC, 0, SLOTS);

    // 2) key addressing path
    f32_to_bf16<<<8192, 256, 0, stream>>>(query, w_qbf, NROWS * DIMC);
    f32_to_bf16<<<256, 256, 0, stream>>>(Wq, w_wqbf, DIMC * DIMC);
    gemm_bf16<<<dim3(4, 128), 256, 0, stream>>>(              // eqbf = q@Wq^T+bq
        (const short*)w_qbf, DIMC, (const short*)w_wqbf, DIMC,
        nullptr, w_xbf, DIMC, DIMC, bq, DIMC, 0, 0, 0);
    eq_head_norms<<<NROWS / 4, 256, 0, stream>>>(w_xbf, w_hinv);
    gemm_bf16<<<dim3(1, 128, 8), 256, 0, stream>>>(           // sims fp32, z=head
        (const short*)w_xbf, DIMC, (const short*)w_knb, HD,
        w_sims, nullptr, HEADS * SLOTS, HD, nullptr, SLOTS,
        HD, 128 * HD, SLOTS);
    key_softmax<<<NROWS, 256, 0, stream>>>(w_sims, w_kadd, w_hinv);
    gemm_bf16<<<dim3(4, 128), 256, 0, stream>>>(              // vir_pre = kadd@W2T^T+bl
        (const short*)w_kadd, 2 * HEADS * SLOTS, (const short*)w_w2tbf, HEADS * SLOTS,
        w_big1, nullptr, DIMC, HEADS * SLOTS, bl, DIMC, 0, 0, 0);
    vir_te_w<<<NROWS / 8, 256, 0, stream>>>(w_big1, query, g1, b1, g2, b2, out_te);

    // 3) value addressing path
    f32_to_bf16<<<8192, 256, 0, stream>>>(value, w_qbf, NROWS * DIMC);   // vbf
    f32_to_bf16<<<256, 256, 0, stream>>>(Wv, w_wqbf, DIMC * DIMC);       // wvbf
    gemm_bf16<<<dim3(4, 128), 256, 0, stream>>>(              // evbf = v@Wv^T+bv
        (const short*)w_qbf, DIMC, (const short*)w_wqbf, DIMC,
        nullptr, w_xbf, DIMC, DIMC, bv, DIMC, 0, 0, 0);
    row_rnorm<<<NROWS / 4, 256, 0, stream>>>(w_xbf, w_rinv);
    gemm_bf16<<<dim3(1, 128), 256, 0, stream>>>(              // vs = ev@vn^T (fp32)
        (const short*)w_xbf, DIMC, (const short*)w_vnb, DIMC,
        w_vs, nullptr, SLOTS, DIMC, nullptr, SLOTS, 0, 0, 0);
    value_softmax_w<<<NROWS / 4, 256, 0, stream>>>(w_vs, w_vsb, w_rinv);
    gemm_bf16<<<dim3(4, 128), 256, 0, stream>>>(              // aud = vsb@vmTb^T (fp32)
        (const short*)w_vsb, 128, (const short*)w_vmTb, 128,
        w_big1, nullptr, DIMC, 128, nullptr, DIMC, 0, 0, 0);
    aud_epilogue_w<<<NROWS / 8, 256, 0, stream>>>(
        w_big1, value, query, g1, b1, g3, b3, out_tr, out_rc);
}

// Round 5
// 388.175 us; speedup vs baseline: 1.2882x; 1.0367x over previous
//
#include <hip/hip_runtime.h>
#include <math.h>

// Problem constants
#define DIMC   512
#define HEADS  8
#define SLOTS  112
#define HD     64          // DIMC/HEADS
#define NROWS  16384       // B*S = 32*512
#define RADIUSF 16.0f

typedef short short8 __attribute__((ext_vector_type(8)));
typedef unsigned short ushort8 __attribute__((ext_vector_type(8)));
typedef float f32x4  __attribute__((ext_vector_type(4)));

__device__ __forceinline__ unsigned short f2bf(float f)
{
    unsigned u = __float_as_uint(f);
    unsigned r = (u + 0x7FFFu + ((u >> 16) & 1u)) >> 16;   // RNE
    return (unsigned short)r;
}
__device__ __forceinline__ float bf2f(unsigned short h)
{
    return __uint_as_float((unsigned)h << 16);
}

// Async global->LDS 16B/lane. LDS dest is wave-uniform base + lane*16;
// our staging layout (thread t owns LDS bytes [16t,16t+16)) matches exactly.
__device__ __forceinline__ void gl16(const void* g, void* lds_wave_base)
{
    __builtin_amdgcn_global_load_lds(
        (const __attribute__((address_space(1))) unsigned int*)g,
        (__attribute__((address_space(3))) unsigned int*)lds_wave_base,
        16, 0, 0);
}

// ---------------------------------------------------------------------------
// DPP-based wave reductions (round-6; validated). VALU-only, no LDS pipe.
// ---------------------------------------------------------------------------
#define DPP_ADD(x, ctrl, rmask)                                               \
    (x) += __int_as_float(__builtin_amdgcn_update_dpp(                        \
               0, __float_as_int(x), (ctrl), (rmask), 0xf, true))

__device__ __forceinline__ float wsum64(float x)
{
    DPP_ADD(x, 0x111, 0xf);
    DPP_ADD(x, 0x112, 0xf);
    DPP_ADD(x, 0x114, 0xf);
    DPP_ADD(x, 0x118, 0xf);
    DPP_ADD(x, 0x142, 0xa);
    DPP_ADD(x, 0x143, 0xc);
    return __int_as_float(__builtin_amdgcn_readlane(__float_as_int(x), 63));
}

__device__ __forceinline__ void wsum64_4(float& a, float& b, float& c, float& d)
{
    DPP_ADD(a, 0x111, 0xf); DPP_ADD(b, 0x111, 0xf); DPP_ADD(c, 0x111, 0xf); DPP_ADD(d, 0x111, 0xf);
    DPP_ADD(a, 0x112, 0xf); DPP_ADD(b, 0x112, 0xf); DPP_ADD(c, 0x112, 0xf); DPP_ADD(d, 0x112, 0xf);
    DPP_ADD(a, 0x114, 0xf); DPP_ADD(b, 0x114, 0xf); DPP_ADD(c, 0x114, 0xf); DPP_ADD(d, 0x114, 0xf);
    DPP_ADD(a, 0x118, 0xf); DPP_ADD(b, 0x118, 0xf); DPP_ADD(c, 0x118, 0xf); DPP_ADD(d, 0x118, 0xf);
    DPP_ADD(a, 0x142, 0xa); DPP_ADD(b, 0x142, 0xa); DPP_ADD(c, 0x142, 0xa); DPP_ADD(d, 0x142, 0xa);
    DPP_ADD(a, 0x143, 0xc); DPP_ADD(b, 0x143, 0xc); DPP_ADD(c, 0x143, 0xc); DPP_ADD(d, 0x143, 0xc);
    a = __int_as_float(__builtin_amdgcn_readlane(__float_as_int(a), 63));
    b = __int_as_float(__builtin_amdgcn_readlane(__float_as_int(b), 63));
    c = __int_as_float(__builtin_amdgcn_readlane(__float_as_int(c), 63));
    d = __int_as_float(__builtin_amdgcn_readlane(__float_as_int(d), 63));
}

// ---------------------------------------------------------------------------
// bf16 MFMA GEMM: C(MxN fp32) / Cb(MxN bf16) = A(MxK bf16) @ B(NxK bf16)^T
// (+ bias[col]). 128x128 tile, BK=32, 256 threads = 4 waves.
// Round-8: staging via global_load_lds (async DMA, no VGPR round-trip) —
// round-3 counters showed MfmaUtil 14% / occupancy 16% with reg staging.
// ---------------------------------------------------------------------------
__global__ __launch_bounds__(256)
void gemm_bf16(const short* __restrict__ A, int lda,
               const short* __restrict__ B, int ldb,
               float* __restrict__ C, unsigned short* __restrict__ Cb,
               int ldc, int K, const float* __restrict__ bias, int Nvalid,
               int aZ, int bZ, int cZ)
{
    __shared__ short As[128 * 32];
    __shared__ short Bs[128 * 32];
    A += (size_t)blockIdx.z * aZ;
    B += (size_t)blockIdx.z * bZ;
    const size_t czoff = (size_t)blockIdx.z * cZ;
    const int tid  = threadIdx.x;
    const int wave = tid >> 6;
    const int lane = tid & 63;
    const int m0 = blockIdx.y * 128;
    const int n0 = blockIdx.x * 128;
    const int wm = (wave >> 1) * 64;
    const int wn = (wave & 1) * 64;

    const int srow = tid >> 2;
    const int schk = (tid & 3) * 8;

    const int fr = lane & 15;
    const int fq = (lane >> 4) * 8;

    f32x4 acc[4][4] = {};

    const short* Ag = A + (size_t)(m0 + srow) * lda + schk;
    const short* Bg = B + (size_t)(n0 + srow) * ldb + schk;

    // wave-uniform LDS bases: wave w stages rows [w*16, w*16+16) (lower) and
    // [64+w*16, ...) (upper) of each 128x32 tile; lane i -> base + i*16B.
    short* asL = As + wave * 512;
    short* asU = As + 2048 + wave * 512;
    short* bsL = Bs + wave * 512;
    short* bsU = Bs + 2048 + wave * 512;

    for (int k0 = 0; k0 < K; k0 += 32) {
        gl16(Ag, asL);
        gl16(Ag + (size_t)64 * lda, asU);
        gl16(Bg, bsL);
        gl16(Bg + (size_t)64 * ldb, bsU);
        Ag += 32; Bg += 32;
        __syncthreads();
        short8 af[4], bf[4];
        #pragma unroll
        for (int i = 0; i < 4; ++i)
            af[i] = *(const short8*)&As[(wm + i * 16 + fr) * 32 + fq];
        #pragma unroll
        for (int j = 0; j < 4; ++j)
            bf[j] = *(const short8*)&Bs[(wn + j * 16 + fr) * 32 + fq];
        #pragma unroll
        for (int i = 0; i < 4; ++i)
            #pragma unroll
            for (int j = 0; j < 4; ++j)
                acc[i][j] = __builtin_amdgcn_mfma_f32_16x16x32_bf16(
                    af[i], bf[j], acc[i][j], 0, 0, 0);
        __syncthreads();
    }

    const int cr = (lane >> 4) * 4;
    const int cc = lane & 15;
    #pragma unroll
    for (int i = 0; i < 4; ++i) {
        const int grow = m0 + wm + i * 16 + cr;
        #pragma unroll
        for (int j = 0; j < 4; ++j) {
            const int gcol = n0 + wn + j * 16 + cc;
            if (gcol < Nvalid) {
                const float bb = bias ? bias[gcol] : 0.f;
                const size_t base = czoff + (size_t)grow * ldc + gcol;
                #pragma unroll
                for (int r = 0; r < 4; ++r) {
                    const float val = acc[i][j][r] + bb;
                    if (C)  C[base + (size_t)r * ldc]  = val;
                    if (Cb) Cb[base + (size_t)r * ldc] = f2bf(val);
                }
            }
        }
    }
}

// ---------------------------------------------------------------------------
// Fused GEMM + row-softmax (round-8): S = A@B^T (M x 112, one N-tile),
// P = softmax(RADIUS * sc[row] * S) per row, bf16 out (+ zero pad cols).
// Works because grid.x==1 and N=112 <= 128: each block owns entire rows.
// Replaces {sims GEMM -> 58MB fp32 -> key_softmax} and
//          {value_sim GEMM -> vs fp32 -> value_softmax_w}.
// ---------------------------------------------------------------------------
__global__ __launch_bounds__(256)
void gemm_softmax(const short* __restrict__ A, int lda, int aZ,
                  const short* __restrict__ B, int ldb, int bZ,
                  int K,
                  const float* __restrict__ sc, int scStride,
                  unsigned short* __restrict__ Ob, int ldo, int oPerZ, int padN)
{
    __shared__ short As[128 * 32];
    __shared__ short Bs[128 * 32];
    __shared__ float P[128][113];
    A += (size_t)blockIdx.z * aZ;
    B += (size_t)blockIdx.z * bZ;
    const int tid  = threadIdx.x;
    const int wave = tid >> 6;
    const int lane = tid & 63;
    const int m0 = blockIdx.y * 128;
    const int wm = (wave >> 1) * 64;
    const int wn = (wave & 1) * 64;
    const int srow = tid >> 2;
    const int schk = (tid & 3) * 8;
    const int fr = lane & 15;
    const int fq = (lane >> 4) * 8;

    f32x4 acc[4][4] = {};

    const short* Ag = A + (size_t)(m0 + srow) * lda + schk;
    const short* Bg = B + (size_t)srow * ldb + schk;

    short* asL = As + wave * 512;
    short* asU = As + 2048 + wave * 512;
    short* bsL = Bs + wave * 512;
    short* bsU = Bs + 2048 + wave * 512;

    for (int k0 = 0; k0 < K; k0 += 32) {
        gl16(Ag, asL);
        gl16(Ag + (size_t)64 * lda, asU);
        gl16(Bg, bsL);
        gl16(Bg + (size_t)64 * ldb, bsU);
        Ag += 32; Bg += 32;
        __syncthreads();
        short8 af[4], bf[4];
        #pragma unroll
        for (int i = 0; i < 4; ++i)
            af[i] = *(const short8*)&As[(wm + i * 16 + fr) * 32 + fq];
        #pragma unroll
        for (int j = 0; j < 4; ++j)
            bf[j] = *(const short8*)&Bs[(wn + j * 16 + fr) * 32 + fq];
        #pragma unroll
        for (int i = 0; i < 4; ++i)
            #pragma unroll
            for (int j = 0; j < 4; ++j)
                acc[i][j] = __builtin_amdgcn_mfma_f32_16x16x32_bf16(
                    af[i], bf[j], acc[i][j], 0, 0, 0);
        __syncthreads();
    }

    // scatter acc -> P (cols < SLOTS only)
    const int cr = (lane >> 4) * 4;
    const int cc = lane & 15;
    #pragma unroll
    for (int i = 0; i < 4; ++i) {
        const int prow = wm + i * 16 + cr;
        #pragma unroll
        for (int j = 0; j < 4; ++j) {
            const int pcol = wn + j * 16 + cc;
            if (pcol < SLOTS) {
                #pragma unroll
                for (int r = 0; r < 4; ++r)
                    P[prow + r][pcol] = acc[i][j][r];
            }
        }
    }
    __syncthreads();

    // 2 threads per row: halves of 56 cols; pair-combine via shfl_xor(1).
    const int rowt = tid >> 1;
    const int half = tid & 1;
    const int k0 = half * 56;
    const int rr = m0 + rowt;
    const float s = RADIUSF * sc[(size_t)rr * scStride + blockIdx.z];
    float mx = -1e30f;
    for (int k = k0; k < k0 + 56; ++k) mx = fmaxf(mx, P[rowt][k]);
    mx = fmaxf(mx, __shfl_xor(mx, 1, 64));
    float sum = 0.f;
    for (int k = k0; k < k0 + 56; ++k) {
        const float e = __expf(s * (P[rowt][k] - mx));
        P[rowt][k] = e;
        sum += e;
    }
    sum += __shfl_xor(sum, 1, 64);
    const float inv = 1.f / sum;
    unsigned short* orow = Ob + (size_t)rr * ldo + (size_t)blockIdx.z * oPerZ;
    for (int k = k0; k < k0 + 56; ++k) orow[k] = f2bf(P[rowt][k] * inv);
    if (half == 1)
        for (int k = SLOTS; k < padN; ++k) orow[k] = 0;
}

// ---------------------------------------------------------------------------
// Small helpers
// ---------------------------------------------------------------------------
__device__ __forceinline__ float block_sum_256(float v, float* red)
{
    #pragma unroll
    for (int off = 32; off; off >>= 1) v += __shfl_down(v, off, 64);
    const int lane = threadIdx.x & 63, wid = threadIdx.x >> 6;
    __syncthreads();
    if (lane == 0) red[wid] = v;
    __syncthreads();
    return red[0] + red[1] + red[2] + red[3];
}

__global__ void zero_small(float* p, int n)
{
    int i = blockIdx.x * blockDim.x + threadIdx.x;
    if (i < n) p[i] = 0.f;
}

// fp32 -> bf16 (RNE), n multiple of 4
__global__ void f32_to_bf16(const float* __restrict__ src,
                            unsigned short* __restrict__ dst, int n)
{
    int i = (blockIdx.x * blockDim.x + threadIdx.x) * 4;
    if (i >= n) return;
    float4 v = *(const float4*)(src + i);
    ushort4 o;
    o.x = f2bf(v.x); o.y = f2bf(v.y); o.z = f2bf(v.z); o.w = f2bf(v.w);
    *(ushort4*)(dst + i) = o;
}

// key_mem row-normalize -> bf16, padded to 128 slots/head ([8][128][64] bf16).
__global__ void prep_key_norm(const float* __restrict__ km,
                              unsigned short* __restrict__ knb)
{
    const int row = blockIdx.x;         // h*128+s
    const int h = row >> 7, s = row & 127;
    const int lane = threadIdx.x;       // 64 threads
    const float v = (s < SLOTS) ? km[(size_t)(h * SLOTS + s) * HD + lane] : 0.f;
    const float ssum = wsum64(v * v);
    const float inv = 1.f / fmaxf(sqrtf(ssum), 1e-12f);
    knb[(size_t)row * HD + lane] = f2bf(v * inv);
}

// value_mem: vn fp32 (for contrastive), vn bf16 padded [128][512],
// vmem^T bf16 padded [512][128].
__global__ void prep_value_norm(const float* __restrict__ vm,
                                float* __restrict__ vn,
                                unsigned short* __restrict__ vnb,
                                unsigned short* __restrict__ vmTb)
{
    const int row = blockIdx.x;        // 0..111
    const int tid = threadIdx.x;       // 256
    __shared__ float red[4];
    const float v0 = vm[(size_t)row * DIMC + tid];
    const float v1 = vm[(size_t)row * DIMC + 256 + tid];
    const float tot = block_sum_256(v0 * v0 + v1 * v1, red);
    const float inv = 1.f / fmaxf(sqrtf(tot), 1e-12f);
    vn[(size_t)row * DIMC + tid]        = v0 * inv;
    vn[(size_t)row * DIMC + 256 + tid]  = v1 * inv;
    vnb[(size_t)row * DIMC + tid]       = f2bf(v0 * inv);
    vnb[(size_t)row * DIMC + 256 + tid] = f2bf(v1 * inv);
    vmTb[(size_t)tid * 128 + row]         = f2bf(v0);
    vmTb[(size_t)(256 + tid) * 128 + row] = f2bf(v1);
}

__global__ void contrastive_kernel(const float* __restrict__ vn, float* __restrict__ outc)
{
    __shared__ float vni[DIMC];
    __shared__ float red[2];
    const int i = blockIdx.x, tid = threadIdx.x;   // 128 threads
    for (int d = tid; d < DIMC; d += 128) vni[d] = vn[(size_t)i * DIMC + d];
    __syncthreads();
    float t = 0.f;
    if (tid < SLOTS) {
        const float* r = vn + (size_t)tid * DIMC;
        float dot = 0.f;
        for (int d = 0; d < DIMC; ++d) dot += vni[d] * r[d];
        const float delta = (tid == i) ? 1.f : 0.f;
        t = fabsf(delta - dot);
    }
    #pragma unroll
    for (int off = 32; off; off >>= 1) t += __shfl_down(t, off, 64);
    if ((tid & 63) == 0) red[tid >> 6] = t;
    __syncthreads();
    if (tid == 0) atomicAdd(outc, 0.5f * (red[0] + red[1]));
}

// Per-(row,head) inverse l2 norm of eq (bf16 input).
__global__ __launch_bounds__(256)
void eq_head_norms(const unsigned short* __restrict__ eq, float* __restrict__ hinv)
{
    const int wid  = threadIdx.x >> 6;
    const int lane = threadIdx.x & 63;
    const int r = blockIdx.x * 4 + wid;
    const ushort8 u = *(const ushort8*)(eq + (size_t)r * DIMC + lane * 8);
    float s = 0.f;
    #pragma unroll
    for (int i = 0; i < 8; ++i) {
        const float f = bf2f(u[i]);
        s += f * f;
    }
    DPP_ADD(s, 0x111, 0xf);
    DPP_ADD(s, 0x112, 0xf);
    DPP_ADD(s, 0x114, 0xf);   // lane 7 mod 8 = 8-lane-group (64-elem) sum
    if ((lane & 7) == 7)
        hinv[(size_t)r * HEADS + (lane >> 3)] = 1.f / fmaxf(sqrtf(s), 1e-12f);
}

// Per-row inverse l2 norm over 512 bf16 (one wave per row)
__global__ __launch_bounds__(256)
void row_rnorm(const unsigned short* __restrict__ x, float* __restrict__ rinv)
{
    const int wave = threadIdx.x >> 6, lane = threadIdx.x & 63;
    const int r = blockIdx.x * 4 + wave;
    const ushort8 u = *(const ushort8*)(x + (size_t)r * DIMC + lane * 8);
    float s = 0.f;
    #pragma unroll
    for (int i = 0; i < 8; ++i) {
        const float f = bf2f(u[i]);
        s += f * f;
    }
    s = wsum64(s);
    if (lane == 0) rinv[r] = 1.f / fmaxf(sqrtf(s), 1e-12f);
}

// Wave-per-2-rows: vir_pre -> LN(g2,b2) -> +query -> LN(g1,b1) -> out_te
__global__ __launch_bounds__(256, 4)
void vir_te_w(const float* __restrict__ vir_pre, const float* __restrict__ query,
              const float* __restrict__ g1, const float* __restrict__ b1,
              const float* __restrict__ g2, const float* __restrict__ b2,
              float* __restrict__ out_te)
{
    const int wave = threadIdx.x >> 6, lane = threadIdx.x & 63;
    const int r0 = blockIdx.x * 8 + wave * 2;
    const int c0 = lane * 8;

    float x[2][8], q[2][8];
    #pragma unroll
    for (int p = 0; p < 2; ++p) {
        const size_t base = (size_t)(r0 + p) * DIMC + c0;
        *(f32x4*)&x[p][0] = *(const f32x4*)(vir_pre + base);
        *(f32x4*)&x[p][4] = *(const f32x4*)(vir_pre + base + 4);
        *(f32x4*)&q[p][0] = *(const f32x4*)(query + base);
        *(f32x4*)&q[p][4] = *(const f32x4*)(query + base + 4);
    }
    float gg2[8], bb2[8], gg1[8], bb1[8];
    *(f32x4*)&gg2[0] = *(const f32x4*)(g2 + c0);
    *(f32x4*)&gg2[4] = *(const f32x4*)(g2 + c0 + 4);
    *(f32x4*)&bb2[0] = *(const f32x4*)(b2 + c0);
    *(f32x4*)&bb2[4] = *(const f32x4*)(b2 + c0 + 4);
    *(f32x4*)&gg1[0] = *(const f32x4*)(g1 + c0);
    *(f32x4*)&gg1[4] = *(const f32x4*)(g1 + c0 + 4);
    *(f32x4*)&bb1[0] = *(const f32x4*)(b1 + c0);
    *(f32x4*)&bb1[4] = *(const f32x4*)(b1 + c0 + 4);

    float s1[2] = {0.f, 0.f}, s2[2] = {0.f, 0.f};
    #pragma unroll
    for (int p = 0; p < 2; ++p)
        #pragma unroll
        for (int i = 0; i < 8; ++i) {
            s1[p] += x[p][i];
            s2[p] += x[p][i] * x[p][i];
        }
    wsum64_4(s1[0], s2[0], s1[1], s2[1]);

    float y[2][8];
    float t1[2] = {0.f, 0.f}, t2[2] = {0.f, 0.f};
    #pragma unroll
    for (int p = 0; p < 2; ++p) {
        const float mu = s1[p] * (1.f / DIMC);
        const float var = s2[p] * (1.f / DIMC) - mu * mu;
        const float rstd = rsqrtf(var + 1e-5f);
        #pragma unroll
        for (int i = 0; i < 8; ++i) {
            const float v = (x[p][i] - mu) * rstd * gg2[i] + bb2[i];
            y[p][i] = q[p][i] + v;
            t1[p] += y[p][i];
            t2[p] += y[p][i] * y[p][i];
        }
    }
    wsum64_4(t1[0], t2[0], t1[1], t2[1]);

    #pragma unroll
    for (int p = 0; p < 2; ++p) {
        const float mu = t1[p] * (1.f / DIMC);
        const float var = t2[p] * (1.f / DIMC) - mu * mu;
        const float rstd = rsqrtf(var + 1e-5f);
        float o[8];
        #pragma unroll
        for (int i = 0; i < 8; ++i)
            o[i] = (y[p][i] - mu) * rstd * gg1[i] + bb1[i];
        const size_t base = (size_t)(r0 + p) * DIMC + c0;
        *(float4*)(out_te + base)     = make_float4(o[0], o[1], o[2], o[3]);
        *(float4*)(out_te + base + 4) = make_float4(o[4], o[5], o[6], o[7]);
    }
}

// Wave-per-2-rows: cos/recon, LN(g3,b3), +query, LN(g1,b1) -> out_tr.
__global__ __launch_bounds__(256, 4)
void aud_epilogue_w(const float* __restrict__ aud, const float* __restrict__ value,
                    const float* __restrict__ query,
                    const float* __restrict__ g1, const float* __restrict__ b1,
                    const float* __restrict__ g3, const float* __restrict__ b3,
                    float* __restrict__ out_tr, float* __restrict__ recon)
{
    __shared__ float red[4];
    const int wave = threadIdx.x >> 6, lane = threadIdx.x & 63;
    const int r0 = blockIdx.x * 8 + wave * 2;
    const int c0 = lane * 8;

    float a[2][8], v[2][8], q[2][8];
    #pragma unroll
    for (int p = 0; p < 2; ++p) {
        const size_t base = (size_t)(r0 + p) * DIMC + c0;
        *(f32x4*)&a[p][0] = *(const f32x4*)(aud + base);
        *(f32x4*)&a[p][4] = *(const f32x4*)(aud + base + 4);
        *(f32x4*)&v[p][0] = *(const f32x4*)(value + base);
        *(f32x4*)&v[p][4] = *(const f32x4*)(value + base + 4);
        *(f32x4*)&q[p][0] = *(const f32x4*)(query + base);
        *(f32x4*)&q[p][4] = *(const f32x4*)(query + base + 4);
    }
    float gg3[8], bb3[8], gg1[8], bb1[8];
    *(f32x4*)&gg3[0] = *(const f32x4*)(g3 + c0);
    *(f32x4*)&gg3[4] = *(const f32x4*)(g3 + c0 + 4);
    *(f32x4*)&bb3[0] = *(const f32x4*)(b3 + c0);
    *(f32x4*)&bb3[4] = *(const f32x4*)(b3 + c0 + 4);
    *(f32x4*)&gg1[0] = *(const f32x4*)(g1 + c0);
    *(f32x4*)&gg1[4] = *(const f32x4*)(g1 + c0 + 4);
    *(f32x4*)&bb1[0] = *(const f32x4*)(b1 + c0);
    *(f32x4*)&bb1[4] = *(const f32x4*)(b1 + c0 + 4);

    float dot[2] = {0.f, 0.f}, na[2] = {0.f, 0.f};
    float nv[2] = {0.f, 0.f}, s1[2] = {0.f, 0.f};
    #pragma unroll
    for (int p = 0; p < 2; ++p)
        #pragma unroll
        for (int i = 0; i < 8; ++i) {
            dot[p] += a[p][i] * v[p][i];
            na[p]  += a[p][i] * a[p][i];
            nv[p]  += v[p][i] * v[p][i];
            s1[p]  += a[p][i];
        }
    wsum64_4(dot[0], na[0], nv[0], s1[0]);
    wsum64_4(dot[1], na[1], nv[1], s1[1]);

    float rloc = 0.f;
    #pragma unroll
    for (int p = 0; p < 2; ++p) {
        const float cosv = dot[p] / fmaxf(sqrtf(na[p]) * sqrtf(nv[p]), 1e-8f);
        rloc += fabsf(1.f - cosv);
    }
    if (lane == 0) red[wave] = rloc;

    float y[2][8];
    float t1[2] = {0.f, 0.f}, t2[2] = {0.f, 0.f};
    #pragma unroll
    for (int p = 0; p < 2; ++p) {
        const float mu = s1[p] * (1.f / DIMC);
        const float var = na[p] * (1.f / DIMC) - mu * mu;   // na == sum(a^2)
        const float rstd = rsqrtf(var + 1e-5f);
        #pragma unroll
        for (int i = 0; i < 8; ++i) {
            const float w = (a[p][i] - mu) * rstd * gg3[i] + bb3[i];
            y[p][i] = q[p][i] + w;
            t1[p] += y[p][i];
            t2[p] += y[p][i] * y[p][i];
        }
    }
    wsum64_4(t1[0], t2[0], t1[1], t2[1]);

    #pragma unroll
    for (int p = 0; p < 2; ++p) {
        const float mu = t1[p] * (1.f / DIMC);
        const float var = t2[p] * (1.f / DIMC) - mu * mu;
        const float rstd = rsqrtf(var + 1e-5f);
        float o[8];
        #pragma unroll
        for (int i = 0; i < 8; ++i)
            o[i] = (y[p][i] - mu) * rstd * gg1[i] + bb1[i];
        const size_t base = (size_t)(r0 + p) * DIMC + c0;
        *(float4*)(out_tr + base)     = make_float4(o[0], o[1], o[2], o[3]);
        *(float4*)(out_tr + base + 4) = make_float4(o[4], o[5], o[6], o[7]);
    }

    __syncthreads();
    if (threadIdx.x == 0)
        atomicAdd(&recon[r0 >> 9], red[0] + red[1] + red[2] + red[3]);
}

// ---------------------------------------------------------------------------
// Launch
// ---------------------------------------------------------------------------
extern "C" void kernel_launch(void* const* d_in, const int* in_sizes, int n_in,
                              void* d_out, int out_size, void* d_ws, size_t ws_size,
                              hipStream_t stream)
{
    const float* query = (const float*)d_in[0];
    const float* value = (const float*)d_in[1];
    const float* keym  = (const float*)d_in[2];
    const float* vmem  = (const float*)d_in[3];
    const float* Wq    = (const float*)d_in[4];
    const float* bq    = (const float*)d_in[5];
    const float* Wv    = (const float*)d_in[6];
    const float* bv    = (const float*)d_in[7];
    const float* Wl    = (const float*)d_in[8];
    const float* bl    = (const float*)d_in[9];
    const float* g1    = (const float*)d_in[10];
    const float* b1    = (const float*)d_in[11];
    const float* g2    = (const float*)d_in[12];
    const float* b2    = (const float*)d_in[13];
    const float* g3    = (const float*)d_in[14];
    const float* b3    = (const float*)d_in[15];

    float* out    = (float*)d_out;
    float* out_te = out;
    float* out_tr = out + 8388608;
    float* out_rc = out + 16777216;    // 32 recon + 1 contrastive

    // Workspace layout (float offsets), round-8. Budget 34,054,144 floats.
    //   0         knb    [8][128][64] bf16    32768 fl
    //   32768     vmTb   [512][128]  bf16     32768 fl
    //   65536     vnb    [128][512]  bf16     32768 fl
    //   98304     vn     [112][512]  fp32     57344 fl
    //   155648    w2tbf  [512][896]  bf16     229376 fl
    //   385024    hinv   [16384][8]  fp32     131072 fl
    //   516096    vmbf   [128][512]  bf16     32768 fl
    //   548864    wlbf   [512][4096] bf16     1048576 fl
    //   1597440   BIG1: vir_pre (key) -> aud (value) fp32   8388608 fl
    //   9986048   xbf:  eqbf (key) -> evbf (value)          4194304 fl
    //   14180352  kaddc [16384][896] bf16 compact           7340032 fl
    //   21520384  vsb   [16384][128] bf16                   1048576 fl
    //   22568960  qbf (key) -> vbf (value)                  4194304 fl
    //   26763264  wqbf -> wvbf                              131072 fl
    //   26894336  rinv                                      16384 fl
    // total 26910720 < 34054144.
    float* ws = (float*)d_ws;
    unsigned short* w_knb  = (unsigned short*)(ws + 0);
    unsigned short* w_vmTb = (unsigned short*)(ws + 32768);
    unsigned short* w_vnb  = (unsigned short*)(ws + 65536);
    float*          w_vn   = ws + 98304;
    unsigned short* w_w2tbf= (unsigned short*)(ws + 155648);
    float*          w_hinv = ws + 385024;
    unsigned short* w_vmbf = (unsigned short*)(ws + 516096);
    unsigned short* w_wlbf = (unsigned short*)(ws + 548864);
    float*          w_big1 = ws + 1597440;
    unsigned short* w_xbf  = (unsigned short*)(ws + 9986048);
    unsigned short* w_kaddc= (unsigned short*)(ws + 14180352);
    unsigned short* w_vsb  = (unsigned short*)(ws + 21520384);
    unsigned short* w_qbf  = (unsigned short*)(ws + 22568960);
    unsigned short* w_wqbf = (unsigned short*)(ws + 26763264);
    float*          w_rinv = ws + 26894336;

    // 0) zero recon+contrastive and bf16 pad regions
    zero_small<<<1, 64, 0, stream>>>(out_rc, 33);
    zero_small<<<256, 256, 0, stream>>>(ws + 32768, 65536);   // vmTb + vnb
    zero_small<<<128, 256, 0, stream>>>(ws + 516096, 32768);  // vmbf

    // 1) input-only precomputes
    prep_key_norm<<<1024, 64, 0, stream>>>(keym, w_knb);
    prep_value_norm<<<112, 256, 0, stream>>>(vmem, w_vn, w_vnb, w_vmTb);
    contrastive_kernel<<<112, 128, 0, stream>>>(w_vn, out_rc + 32);
    f32_to_bf16<<<2048, 256, 0, stream>>>(Wl, w_wlbf, DIMC * DIMC * HEADS);
    f32_to_bf16<<<56, 256, 0, stream>>>(vmem, w_vmbf, SLOTS * DIMC);
    gemm_bf16<<<dim3(1, 4, 8), 256, 0, stream>>>(             // W2T bf16 direct
        (const short*)w_wlbf, HEADS * DIMC, (const short*)w_vmbf, DIMC,
        nullptr, w_w2tbf, HEADS * SLOTS, DIMC, nullptr, SLOTS,
        DIMC, 0, SLOTS);

    // 2) key addressing path
    f32_to_bf16<<<8192, 256, 0, stream>>>(query, w_qbf, NROWS * DIMC);
    f32_to_bf16<<<256, 256, 0, stream>>>(Wq, w_wqbf, DIMC * DIMC);
    gemm_bf16<<<dim3(4, 128), 256, 0, stream>>>(              // eqbf = q@Wq^T+bq
        (const short*)w_qbf, DIMC, (const short*)w_wqbf, DIMC,
        nullptr, w_xbf, DIMC, DIMC, bq, DIMC, 0, 0, 0);
    eq_head_norms<<<NROWS / 4, 256, 0, stream>>>(w_xbf, w_hinv);
    gemm_softmax<<<dim3(1, 128, 8), 256, 0, stream>>>(        // kaddc = softmax(sims)
        (const short*)w_xbf, DIMC, HD, (const short*)w_knb, HD, 128 * HD,
        HD, w_hinv, HEADS, w_kaddc, HEADS * SLOTS, SLOTS, SLOTS);
    gemm_bf16<<<dim3(4, 128), 256, 0, stream>>>(              // vir_pre = kaddc@W2T^T+bl
        (const short*)w_kaddc, HEADS * SLOTS, (const short*)w_w2tbf, HEADS * SLOTS,
        w_big1, nullptr, DIMC, HEADS * SLOTS, bl, DIMC, 0, 0, 0);
    vir_te_w<<<NROWS / 8, 256, 0, stream>>>(w_big1, query, g1, b1, g2, b2, out_te);

    // 3) value addressing path
    f32_to_bf16<<<8192, 256, 0, stream>>>(value, w_qbf, NROWS * DIMC);   // vbf
    f32_to_bf16<<<256, 256, 0, stream>>>(Wv, w_wqbf, DIMC * DIMC);       // wvbf
    gemm_bf16<<<dim3(4, 128), 256, 0, stream>>>(              // evbf = v@Wv^T+bv
        (const short*)w_qbf, DIMC, (const short*)w_wqbf, DIMC,
        nullptr, w_xbf, DIMC, DIMC, bv, DIMC, 0, 0, 0);
    row_rnorm<<<NROWS / 4, 256, 0, stream>>>(w_xbf, w_rinv);
    gemm_softmax<<<dim3(1, 128, 1), 256, 0, stream>>>(        // vsb = softmax(ev@vn^T)
        (const short*)w_xbf, DIMC, 0, (const short*)w_vnb, DIMC, 0,
        DIMC, w_rinv, 1, w_vsb, 128, 0, 128);
    gemm_bf16<<<dim3(4, 128), 256, 0, stream>>>(              // aud = vsb@vmTb^T (fp32)
        (const short*)w_vsb, 128, (const short*)w_vmTb, 128,
        w_big1, nullptr, DIMC, 128, nullptr, DIMC, 0, 0, 0);
    aud_epilogue_w<<<NROWS / 8, 256, 0, stream>>>(
        w_big1, value, query, g1, b1, g3, b3, out_tr, out_rc);
}

// Round 6
// 359.840 us; speedup vs baseline: 1.3896x; 1.0787x over previous
//
#include <hip/hip_runtime.h>
#include <math.h>

// Problem constants
#define DIMC   512
#define HEADS  8
#define SLOTS  112
#define HD     64          // DIMC/HEADS
#define NROWS  16384       // B*S = 32*512
#define RADIUSF 16.0f

typedef short short8 __attribute__((ext_vector_type(8)));
typedef unsigned short ushort8 __attribute__((ext_vector_type(8)));
typedef float f32x4  __attribute__((ext_vector_type(4)));

__device__ __forceinline__ unsigned short f2bf(float f)
{
    unsigned u = __float_as_uint(f);
    unsigned r = (u + 0x7FFFu + ((u >> 16) & 1u)) >> 16;   // RNE
    return (unsigned short)r;
}
__device__ __forceinline__ float bf2f(unsigned short h)
{
    return __uint_as_float((unsigned)h << 16);
}

// Async global->LDS 16B/lane. LDS dest is wave-uniform base + lane*16;
// our staging layout (thread t owns LDS bytes [16t,16t+16)) matches exactly.
__device__ __forceinline__ void gl16(const void* g, void* lds_wave_base)
{
    __builtin_amdgcn_global_load_lds(
        (const __attribute__((address_space(1))) unsigned int*)g,
        (__attribute__((address_space(3))) unsigned int*)lds_wave_base,
        16, 0, 0);
}

// ---------------------------------------------------------------------------
// DPP-based wave reductions (round-6; validated). VALU-only, no LDS pipe.
// ---------------------------------------------------------------------------
#define DPP_ADD(x, ctrl, rmask)                                               \
    (x) += __int_as_float(__builtin_amdgcn_update_dpp(                        \
               0, __float_as_int(x), (ctrl), (rmask), 0xf, true))

__device__ __forceinline__ float wsum64(float x)
{
    DPP_ADD(x, 0x111, 0xf);
    DPP_ADD(x, 0x112, 0xf);
    DPP_ADD(x, 0x114, 0xf);
    DPP_ADD(x, 0x118, 0xf);
    DPP_ADD(x, 0x142, 0xa);
    DPP_ADD(x, 0x143, 0xc);
    return __int_as_float(__builtin_amdgcn_readlane(__float_as_int(x), 63));
}

__device__ __forceinline__ void wsum64_4(float& a, float& b, float& c, float& d)
{
    DPP_ADD(a, 0x111, 0xf); DPP_ADD(b, 0x111, 0xf); DPP_ADD(c, 0x111, 0xf); DPP_ADD(d, 0x111, 0xf);
    DPP_ADD(a, 0x112, 0xf); DPP_ADD(b, 0x112, 0xf); DPP_ADD(c, 0x112, 0xf); DPP_ADD(d, 0x112, 0xf);
    DPP_ADD(a, 0x114, 0xf); DPP_ADD(b, 0x114, 0xf); DPP_ADD(c, 0x114, 0xf); DPP_ADD(d, 0x114, 0xf);
    DPP_ADD(a, 0x118, 0xf); DPP_ADD(b, 0x118, 0xf); DPP_ADD(c, 0x118, 0xf); DPP_ADD(d, 0x118, 0xf);
    DPP_ADD(a, 0x142, 0xa); DPP_ADD(b, 0x142, 0xa); DPP_ADD(c, 0x142, 0xa); DPP_ADD(d, 0x142, 0xa);
    DPP_ADD(a, 0x143, 0xc); DPP_ADD(b, 0x143, 0xc); DPP_ADD(c, 0x143, 0xc); DPP_ADD(d, 0x143, 0xc);
    a = __int_as_float(__builtin_amdgcn_readlane(__float_as_int(a), 63));
    b = __int_as_float(__builtin_amdgcn_readlane(__float_as_int(b), 63));
    c = __int_as_float(__builtin_amdgcn_readlane(__float_as_int(c), 63));
    d = __int_as_float(__builtin_amdgcn_readlane(__float_as_int(d), 63));
}

// ---------------------------------------------------------------------------
// bf16 MFMA GEMM: C(MxN fp32) / Cb(MxN bf16) = A(MxK bf16) @ B(NxK bf16)^T
// (+ bias[col]). 128x128 tile, BK=32, 256 threads = 4 waves.
// Staging via global_load_lds (round-8; validated round 5).
// ---------------------------------------------------------------------------
__global__ __launch_bounds__(256)
void gemm_bf16(const short* __restrict__ A, int lda,
               const short* __restrict__ B, int ldb,
               float* __restrict__ C, unsigned short* __restrict__ Cb,
               int ldc, int K, const float* __restrict__ bias, int Nvalid,
               int aZ, int bZ, int cZ)
{
    __shared__ short As[128 * 32];
    __shared__ short Bs[128 * 32];
    A += (size_t)blockIdx.z * aZ;
    B += (size_t)blockIdx.z * bZ;
    const size_t czoff = (size_t)blockIdx.z * cZ;
    const int tid  = threadIdx.x;
    const int wave = tid >> 6;
    const int lane = tid & 63;
    const int m0 = blockIdx.y * 128;
    const int n0 = blockIdx.x * 128;
    const int wm = (wave >> 1) * 64;
    const int wn = (wave & 1) * 64;

    const int srow = tid >> 2;
    const int schk = (tid & 3) * 8;

    const int fr = lane & 15;
    const int fq = (lane >> 4) * 8;

    f32x4 acc[4][4] = {};

    const short* Ag = A + (size_t)(m0 + srow) * lda + schk;
    const short* Bg = B + (size_t)(n0 + srow) * ldb + schk;

    short* asL = As + wave * 512;
    short* asU = As + 2048 + wave * 512;
    short* bsL = Bs + wave * 512;
    short* bsU = Bs + 2048 + wave * 512;

    for (int k0 = 0; k0 < K; k0 += 32) {
        gl16(Ag, asL);
        gl16(Ag + (size_t)64 * lda, asU);
        gl16(Bg, bsL);
        gl16(Bg + (size_t)64 * ldb, bsU);
        Ag += 32; Bg += 32;
        __syncthreads();
        short8 af[4], bf[4];
        #pragma unroll
        for (int i = 0; i < 4; ++i)
            af[i] = *(const short8*)&As[(wm + i * 16 + fr) * 32 + fq];
        #pragma unroll
        for (int j = 0; j < 4; ++j)
            bf[j] = *(const short8*)&Bs[(wn + j * 16 + fr) * 32 + fq];
        #pragma unroll
        for (int i = 0; i < 4; ++i)
            #pragma unroll
            for (int j = 0; j < 4; ++j)
                acc[i][j] = __builtin_amdgcn_mfma_f32_16x16x32_bf16(
                    af[i], bf[j], acc[i][j], 0, 0, 0);
        __syncthreads();
    }

    const int cr = (lane >> 4) * 4;
    const int cc = lane & 15;
    #pragma unroll
    for (int i = 0; i < 4; ++i) {
        const int grow = m0 + wm + i * 16 + cr;
        #pragma unroll
        for (int j = 0; j < 4; ++j) {
            const int gcol = n0 + wn + j * 16 + cc;
            if (gcol < Nvalid) {
                const float bb = bias ? bias[gcol] : 0.f;
                const size_t base = czoff + (size_t)grow * ldc + gcol;
                #pragma unroll
                for (int r = 0; r < 4; ++r) {
                    const float val = acc[i][j][r] + bb;
                    if (C)  C[base + (size_t)r * ldc]  = val;
                    if (Cb) Cb[base + (size_t)r * ldc] = f2bf(val);
                }
            }
        }
    }
}

// ---------------------------------------------------------------------------
// Fused GEMM + in-kernel row-l2norm + row-softmax (round-9).
// S = A@B^T (M x 112, one N-tile); scale = RADIUS / ||A_row|| computed from
// the SAME bf16 A-fragments the MFMA consumes (deletes the separate
// eq_head_norms / row_rnorm passes); P = softmax(scale * S) -> bf16 (+pad).
// Valid because grid.x==1, N=112<=128 and A's K-slice IS the normed vector
// (key: per-head 64-col slice via aZ; value: full 512-col row).
// ---------------------------------------------------------------------------
__global__ __launch_bounds__(256)
void gemm_softmax(const short* __restrict__ A, int lda, int aZ,
                  const short* __restrict__ B, int ldb, int bZ,
                  int K,
                  unsigned short* __restrict__ Ob, int ldo, int oPerZ, int padN)
{
    __shared__ short As[128 * 32];
    __shared__ short Bs[128 * 32];
    __shared__ float P[128][113];
    __shared__ float hinvS[128];
    A += (size_t)blockIdx.z * aZ;
    B += (size_t)blockIdx.z * bZ;
    const int tid  = threadIdx.x;
    const int wave = tid >> 6;
    const int lane = tid & 63;
    const int m0 = blockIdx.y * 128;
    const int wm = (wave >> 1) * 64;
    const int wn = (wave & 1) * 64;
    const int srow = tid >> 2;
    const int schk = (tid & 3) * 8;
    const int fr = lane & 15;
    const int fq = (lane >> 4) * 8;

    f32x4 acc[4][4] = {};
    float ss[4] = {0.f, 0.f, 0.f, 0.f};

    const short* Ag = A + (size_t)(m0 + srow) * lda + schk;
    const short* Bg = B + (size_t)srow * ldb + schk;

    short* asL = As + wave * 512;
    short* asU = As + 2048 + wave * 512;
    short* bsL = Bs + wave * 512;
    short* bsU = Bs + 2048 + wave * 512;

    for (int k0 = 0; k0 < K; k0 += 32) {
        gl16(Ag, asL);
        gl16(Ag + (size_t)64 * lda, asU);
        gl16(Bg, bsL);
        gl16(Bg + (size_t)64 * ldb, bsU);
        Ag += 32; Bg += 32;
        __syncthreads();
        short8 af[4], bf[4];
        #pragma unroll
        for (int i = 0; i < 4; ++i)
            af[i] = *(const short8*)&As[(wm + i * 16 + fr) * 32 + fq];
        #pragma unroll
        for (int j = 0; j < 4; ++j)
            bf[j] = *(const short8*)&Bs[(wn + j * 16 + fr) * 32 + fq];
        // A-row sum-of-squares from the fragments (lane covers cols fq..fq+7
        // of rows wm+i*16+fr; the 4 fq-lane-groups cover all 32 cols/chunk).
        #pragma unroll
        for (int i = 0; i < 4; ++i)
            #pragma unroll
            for (int e = 0; e < 8; ++e) {
                const float f = bf2f((unsigned short)af[i][e]);
                ss[i] += f * f;
            }
        #pragma unroll
        for (int i = 0; i < 4; ++i)
            #pragma unroll
            for (int j = 0; j < 4; ++j)
                acc[i][j] = __builtin_amdgcn_mfma_f32_16x16x32_bf16(
                    af[i], bf[j], acc[i][j], 0, 0, 0);
        __syncthreads();
    }

    // combine fq-groups: lanes fr+{0,16,32,48} hold partials of the same row
    #pragma unroll
    for (int i = 0; i < 4; ++i) {
        ss[i] += __shfl_xor(ss[i], 16, 64);
        ss[i] += __shfl_xor(ss[i], 32, 64);
    }
    if (lane < 16) {
        #pragma unroll
        for (int i = 0; i < 4; ++i)
            hinvS[wm + i * 16 + lane] = 1.f / fmaxf(sqrtf(ss[i]), 1e-12f);
    }

    // scatter acc -> P (cols < SLOTS only)
    const int cr = (lane >> 4) * 4;
    const int cc = lane & 15;
    #pragma unroll
    for (int i = 0; i < 4; ++i) {
        const int prow = wm + i * 16 + cr;
        #pragma unroll
        for (int j = 0; j < 4; ++j) {
            const int pcol = wn + j * 16 + cc;
            if (pcol < SLOTS) {
                #pragma unroll
                for (int r = 0; r < 4; ++r)
                    P[prow + r][pcol] = acc[i][j][r];
            }
        }
    }
    __syncthreads();

    // 2 threads per row: halves of 56 cols; pair-combine via shfl_xor(1).
    const int rowt = tid >> 1;
    const int half = tid & 1;
    const int k0 = half * 56;
    const int rr = m0 + rowt;
    const float s = RADIUSF * hinvS[rowt];
    float mx = -1e30f;
    for (int k = k0; k < k0 + 56; ++k) mx = fmaxf(mx, P[rowt][k]);
    mx = fmaxf(mx, __shfl_xor(mx, 1, 64));
    float sum = 0.f;
    for (int k = k0; k < k0 + 56; ++k) {
        const float e = __expf(s * (P[rowt][k] - mx));
        P[rowt][k] = e;
        sum += e;
    }
    sum += __shfl_xor(sum, 1, 64);
    const float inv = 1.f / sum;
    unsigned short* orow = Ob + (size_t)rr * ldo + (size_t)blockIdx.z * oPerZ;
    for (int k = k0; k < k0 + 56; ++k) orow[k] = f2bf(P[rowt][k] * inv);
    if (half == 1)
        for (int k = SLOTS; k < padN; ++k) orow[k] = 0;
}

// ---------------------------------------------------------------------------
// Small helpers
// ---------------------------------------------------------------------------
__device__ __forceinline__ float block_sum_256(float v, float* red)
{
    #pragma unroll
    for (int off = 32; off; off >>= 1) v += __shfl_down(v, off, 64);
    const int lane = threadIdx.x & 63, wid = threadIdx.x >> 6;
    __syncthreads();
    if (lane == 0) red[wid] = v;
    __syncthreads();
    return red[0] + red[1] + red[2] + red[3];
}

// One fused conversion kernel (round-9): all fp32->bf16 input staging in a
// single segmented grid-stride launch (replaces 6 f32_to_bf16 dispatches).
// Segments in float4 units; last segment zeros the vmbf pad rows.
__global__ void conv_all(const float* __restrict__ q, const float* __restrict__ v,
                         const float* __restrict__ Wq, const float* __restrict__ Wv,
                         const float* __restrict__ Wl, const float* __restrict__ vm,
                         unsigned short* __restrict__ qbf, unsigned short* __restrict__ vbf,
                         unsigned short* __restrict__ wqbf, unsigned short* __restrict__ wvbf,
                         unsigned short* __restrict__ wlbf, unsigned short* __restrict__ vmbf)
{
    const int i = blockIdx.x * blockDim.x + threadIdx.x;   // float4-unit index
    const float* src;
    unsigned short* dst;
    int off;
    if (i < 2097152)      { src = q;  dst = qbf;  off = i; }
    else if (i < 4194304) { src = v;  dst = vbf;  off = i - 2097152; }
    else if (i < 4259840) { src = Wq; dst = wqbf; off = i - 4194304; }
    else if (i < 4325376) { src = Wv; dst = wvbf; off = i - 4259840; }
    else if (i < 4849664) { src = Wl; dst = wlbf; off = i - 4325376; }
    else if (i < 4864000) { src = vm; dst = vmbf; off = i - 4849664; }
    else {                 // zero vmbf pad rows 112..127 (8192 bf16)
        const int j = i - 4864000;   // 0..2047
        *(ushort4*)(vmbf + 57344 + (size_t)j * 4) = make_ushort4(0, 0, 0, 0);
        return;
    }
    const float4 x = *(const float4*)(src + (size_t)off * 4);
    ushort4 o;
    o.x = f2bf(x.x); o.y = f2bf(x.y); o.z = f2bf(x.z); o.w = f2bf(x.w);
    *(ushort4*)(dst + (size_t)off * 4) = o;
}

// key_mem row-normalize -> bf16, padded to 128 slots/head ([8][128][64] bf16).
// Block 0 also zeroes the recon+contrastive outputs (runs before any atomics).
__global__ void prep_key_norm(const float* __restrict__ km,
                              unsigned short* __restrict__ knb,
                              float* __restrict__ outrc)
{
    const int row = blockIdx.x;         // h*128+s
    const int h = row >> 7, s = row & 127;
    const int lane = threadIdx.x;       // 64 threads
    if (row == 0 && lane < 33) outrc[lane] = 0.f;
    const float v = (s < SLOTS) ? km[(size_t)(h * SLOTS + s) * HD + lane] : 0.f;
    const float ssum = wsum64(v * v);
    const float inv = 1.f / fmaxf(sqrtf(ssum), 1e-12f);
    knb[(size_t)row * HD + lane] = f2bf(v * inv);
}

// value_mem: vn fp32 (contrastive), vn bf16 padded [128][512], vmem^T bf16
// padded [512][128]. Blocks >= 112 zero the pad slots (vmTb cols 112..127,
// vnb rows 112..127) — replaces the zero_small pre-pass.
__global__ void prep_value_norm(const float* __restrict__ vm,
                                float* __restrict__ vn,
                                unsigned short* __restrict__ vnb,
                                unsigned short* __restrict__ vmTb)
{
    const int row = blockIdx.x;        // 0..175
    const int tid = threadIdx.x;       // 256
    if (row >= 112) {
        const int idx = (row - 112) * 256 + tid;   // 0..16383
        if (idx < 8192) {
            vmTb[(size_t)(idx >> 4) * 128 + 112 + (idx & 15)] = 0;
        } else {
            const int j = idx - 8192;
            vnb[(size_t)(112 + (j >> 9)) * 512 + (j & 511)] = 0;
        }
        return;
    }
    __shared__ float red[4];
    const float v0 = vm[(size_t)row * DIMC + tid];
    const float v1 = vm[(size_t)row * DIMC + 256 + tid];
    const float tot = block_sum_256(v0 * v0 + v1 * v1, red);
    const float inv = 1.f / fmaxf(sqrtf(tot), 1e-12f);
    vn[(size_t)row * DIMC + tid]        = v0 * inv;
    vn[(size_t)row * DIMC + 256 + tid]  = v1 * inv;
    vnb[(size_t)row * DIMC + tid]       = f2bf(v0 * inv);
    vnb[(size_t)row * DIMC + 256 + tid] = f2bf(v1 * inv);
    vmTb[(size_t)tid * 128 + row]         = f2bf(v0);
    vmTb[(size_t)(256 + tid) * 128 + row] = f2bf(v1);
}

__global__ void contrastive_kernel(const float* __restrict__ vn, float* __restrict__ outc)
{
    __shared__ float vni[DIMC];
    __shared__ float red[2];
    const int i = blockIdx.x, tid = threadIdx.x;   // 128 threads
    for (int d = tid; d < DIMC; d += 128) vni[d] = vn[(size_t)i * DIMC + d];
    __syncthreads();
    float t = 0.f;
    if (tid < SLOTS) {
        const float* r = vn + (size_t)tid * DIMC;
        float dot = 0.f;
        for (int d = 0; d < DIMC; ++d) dot += vni[d] * r[d];
        const float delta = (tid == i) ? 1.f : 0.f;
        t = fabsf(delta - dot);
    }
    #pragma unroll
    for (int off = 32; off; off >>= 1) t += __shfl_down(t, off, 64);
    if ((tid & 63) == 0) red[tid >> 6] = t;
    __syncthreads();
    if (tid == 0) atomicAdd(outc, 0.5f * (red[0] + red[1]));
}

// Wave-per-2-rows: vir_pre -> LN(g2,b2) -> +query -> LN(g1,b1) -> out_te
__global__ __launch_bounds__(256, 4)
void vir_te_w(const float* __restrict__ vir_pre, const float* __restrict__ query,
              const float* __restrict__ g1, const float* __restrict__ b1,
              const float* __restrict__ g2, const float* __restrict__ b2,
              float* __restrict__ out_te)
{
    const int wave = threadIdx.x >> 6, lane = threadIdx.x & 63;
    const int r0 = blockIdx.x * 8 + wave * 2;
    const int c0 = lane * 8;

    float x[2][8], q[2][8];
    #pragma unroll
    for (int p = 0; p < 2; ++p) {
        const size_t base = (size_t)(r0 + p) * DIMC + c0;
        *(f32x4*)&x[p][0] = *(const f32x4*)(vir_pre + base);
        *(f32x4*)&x[p][4] = *(const f32x4*)(vir_pre + base + 4);
        *(f32x4*)&q[p][0] = *(const f32x4*)(query + base);
        *(f32x4*)&q[p][4] = *(const f32x4*)(query + base + 4);
    }
    float gg2[8], bb2[8], gg1[8], bb1[8];
    *(f32x4*)&gg2[0] = *(const f32x4*)(g2 + c0);
    *(f32x4*)&gg2[4] = *(const f32x4*)(g2 + c0 + 4);
    *(f32x4*)&bb2[0] = *(const f32x4*)(b2 + c0);
    *(f32x4*)&bb2[4] = *(const f32x4*)(b2 + c0 + 4);
    *(f32x4*)&gg1[0] = *(const f32x4*)(g1 + c0);
    *(f32x4*)&gg1[4] = *(const f32x4*)(g1 + c0 + 4);
    *(f32x4*)&bb1[0] = *(const f32x4*)(b1 + c0);
    *(f32x4*)&bb1[4] = *(const f32x4*)(b1 + c0 + 4);

    float s1[2] = {0.f, 0.f}, s2[2] = {0.f, 0.f};
    #pragma unroll
    for (int p = 0; p < 2; ++p)
        #pragma unroll
        for (int i = 0; i < 8; ++i) {
            s1[p] += x[p][i];
            s2[p] += x[p][i] * x[p][i];
        }
    wsum64_4(s1[0], s2[0], s1[1], s2[1]);

    float y[2][8];
    float t1[2] = {0.f, 0.f}, t2[2] = {0.f, 0.f};
    #pragma unroll
    for (int p = 0; p < 2; ++p) {
        const float mu = s1[p] * (1.f / DIMC);
        const float var = s2[p] * (1.f / DIMC) - mu * mu;
        const float rstd = rsqrtf(var + 1e-5f);
        #pragma unroll
        for (int i = 0; i < 8; ++i) {
            const float v = (x[p][i] - mu) * rstd * gg2[i] + bb2[i];
            y[p][i] = q[p][i] + v;
            t1[p] += y[p][i];
            t2[p] += y[p][i] * y[p][i];
        }
    }
    wsum64_4(t1[0], t2[0], t1[1], t2[1]);

    #pragma unroll
    for (int p = 0; p < 2; ++p) {
        const float mu = t1[p] * (1.f / DIMC);
        const float var = t2[p] * (1.f / DIMC) - mu * mu;
        const float rstd = rsqrtf(var + 1e-5f);
        float o[8];
        #pragma unroll
        for (int i = 0; i < 8; ++i)
            o[i] = (y[p][i] - mu) * rstd * gg1[i] + bb1[i];
        const size_t base = (size_t)(r0 + p) * DIMC + c0;
        *(float4*)(out_te + base)     = make_float4(o[0], o[1], o[2], o[3]);
        *(float4*)(out_te + base + 4) = make_float4(o[4], o[5], o[6], o[7]);
    }
}

// Wave-per-2-rows: cos/recon, LN(g3,b3), +query, LN(g1,b1) -> out_tr.
__global__ __launch_bounds__(256, 4)
void aud_epilogue_w(const float* __restrict__ aud, const float* __restrict__ value,
                    const float* __restrict__ query,
                    const float* __restrict__ g1, const float* __restrict__ b1,
                    const float* __restrict__ g3, const float* __restrict__ b3,
                    float* __restrict__ out_tr, float* __restrict__ recon)
{
    __shared__ float red[4];
    const int wave = threadIdx.x >> 6, lane = threadIdx.x & 63;
    const int r0 = blockIdx.x * 8 + wave * 2;
    const int c0 = lane * 8;

    float a[2][8], v[2][8], q[2][8];
    #pragma unroll
    for (int p = 0; p < 2; ++p) {
        const size_t base = (size_t)(r0 + p) * DIMC + c0;
        *(f32x4*)&a[p][0] = *(const f32x4*)(aud + base);
        *(f32x4*)&a[p][4] = *(const f32x4*)(aud + base + 4);
        *(f32x4*)&v[p][0] = *(const f32x4*)(value + base);
        *(f32x4*)&v[p][4] = *(const f32x4*)(value + base + 4);
        *(f32x4*)&q[p][0] = *(const f32x4*)(query + base);
        *(f32x4*)&q[p][4] = *(const f32x4*)(query + base + 4);
    }
    float gg3[8], bb3[8], gg1[8], bb1[8];
    *(f32x4*)&gg3[0] = *(const f32x4*)(g3 + c0);
    *(f32x4*)&gg3[4] = *(const f32x4*)(g3 + c0 + 4);
    *(f32x4*)&bb3[0] = *(const f32x4*)(b3 + c0);
    *(f32x4*)&bb3[4] = *(const f32x4*)(b3 + c0 + 4);
    *(f32x4*)&gg1[0] = *(const f32x4*)(g1 + c0);
    *(f32x4*)&gg1[4] = *(const f32x4*)(g1 + c0 + 4);
    *(f32x4*)&bb1[0] = *(const f32x4*)(b1 + c0);
    *(f32x4*)&bb1[4] = *(const f32x4*)(b1 + c0 + 4);

    float dot[2] = {0.f, 0.f}, na[2] = {0.f, 0.f};
    float nv[2] = {0.f, 0.f}, s1[2] = {0.f, 0.f};
    #pragma unroll
    for (int p = 0; p < 2; ++p)
        #pragma unroll
        for (int i = 0; i < 8; ++i) {
            dot[p] += a[p][i] * v[p][i];
            na[p]  += a[p][i] * a[p][i];
            nv[p]  += v[p][i] * v[p][i];
            s1[p]  += a[p][i];
        }
    wsum64_4(dot[0], na[0], nv[0], s1[0]);
    wsum64_4(dot[1], na[1], nv[1], s1[1]);

    float rloc = 0.f;
    #pragma unroll
    for (int p = 0; p < 2; ++p) {
        const float cosv = dot[p] / fmaxf(sqrtf(na[p]) * sqrtf(nv[p]), 1e-8f);
        rloc += fabsf(1.f - cosv);
    }
    if (lane == 0) red[wave] = rloc;

    float y[2][8];
    float t1[2] = {0.f, 0.f}, t2[2] = {0.f, 0.f};
    #pragma unroll
    for (int p = 0; p < 2; ++p) {
        const float mu = s1[p] * (1.f / DIMC);
        const float var = na[p] * (1.f / DIMC) - mu * mu;   // na == sum(a^2)
        const float rstd = rsqrtf(var + 1e-5f);
        #pragma unroll
        for (int i = 0; i < 8; ++i) {
            const float w = (a[p][i] - mu) * rstd * gg3[i] + bb3[i];
            y[p][i] = q[p][i] + w;
            t1[p] += y[p][i];
            t2[p] += y[p][i] * y[p][i];
        }
    }
    wsum64_4(t1[0], t2[0], t1[1], t2[1]);

    #pragma unroll
    for (int p = 0; p < 2; ++p) {
        const float mu = t1[p] * (1.f / DIMC);
        const float var = t2[p] * (1.f / DIMC) - mu * mu;
        const float rstd = rsqrtf(var + 1e-5f);
        float o[8];
        #pragma unroll
        for (int i = 0; i < 8; ++i)
            o[i] = (y[p][i] - mu) * rstd * gg1[i] + bb1[i];
        const size_t base = (size_t)(r0 + p) * DIMC + c0;
        *(float4*)(out_tr + base)     = make_float4(o[0], o[1], o[2], o[3]);
        *(float4*)(out_tr + base + 4) = make_float4(o[4], o[5], o[6], o[7]);
    }

    __syncthreads();
    if (threadIdx.x == 0)
        atomicAdd(&recon[r0 >> 9], red[0] + red[1] + red[2] + red[3]);
}

// ---------------------------------------------------------------------------
// Launch
// ---------------------------------------------------------------------------
extern "C" void kernel_launch(void* const* d_in, const int* in_sizes, int n_in,
                              void* d_out, int out_size, void* d_ws, size_t ws_size,
                              hipStream_t stream)
{
    const float* query = (const float*)d_in[0];
    const float* value = (const float*)d_in[1];
    const float* keym  = (const float*)d_in[2];
    const float* vmem  = (const float*)d_in[3];
    const float* Wq    = (const float*)d_in[4];
    const float* bq    = (const float*)d_in[5];
    const float* Wv    = (const float*)d_in[6];
    const float* bv    = (const float*)d_in[7];
    const float* Wl    = (const float*)d_in[8];
    const float* bl    = (const float*)d_in[9];
    const float* g1    = (const float*)d_in[10];
    const float* b1    = (const float*)d_in[11];
    const float* g2    = (const float*)d_in[12];
    const float* b2    = (const float*)d_in[13];
    const float* g3    = (const float*)d_in[14];
    const float* b3    = (const float*)d_in[15];

    float* out    = (float*)d_out;
    float* out_te = out;
    float* out_tr = out + 8388608;
    float* out_rc = out + 16777216;    // 32 recon + 1 contrastive

    // Workspace layout (float offsets), round-9. Budget 34,054,144 floats.
    //   0         knb    [8][128][64] bf16    32768 fl
    //   32768     vmTb   [512][128]  bf16     32768 fl
    //   65536     vnb    [128][512]  bf16     32768 fl
    //   98304     vn     [112][512]  fp32     57344 fl
    //   155648    w2tbf  [512][896]  bf16     229376 fl
    //   516096    vmbf   [128][512]  bf16     32768 fl
    //   548864    wlbf   [512][4096] bf16     1048576 fl
    //   1597440   BIG1: vir_pre (key) -> aud (value) fp32   8388608 fl
    //   9986048   xbf:  eqbf (key) -> evbf (value)          4194304 fl
    //   14180352  kaddc [16384][896] bf16 compact           7340032 fl
    //   21520384  vsb   [16384][128] bf16                   1048576 fl
    //   22568960  qbf                                       4194304 fl
    //   26763264  vbf                                       4194304 fl
    //   30957568  wqbf                                      131072 fl
    //   31088640  wvbf                                      131072 fl
    // total 31219712 < 34054144.
    float* ws = (float*)d_ws;
    unsigned short* w_knb  = (unsigned short*)(ws + 0);
    unsigned short* w_vmTb = (unsigned short*)(ws + 32768);
    unsigned short* w_vnb  = (unsigned short*)(ws + 65536);
    float*          w_vn   = ws + 98304;
    unsigned short* w_w2tbf= (unsigned short*)(ws + 155648);
    unsigned short* w_vmbf = (unsigned short*)(ws + 516096);
    unsigned short* w_wlbf = (unsigned short*)(ws + 548864);
    float*          w_big1 = ws + 1597440;
    unsigned short* w_xbf  = (unsigned short*)(ws + 9986048);
    unsigned short* w_kaddc= (unsigned short*)(ws + 14180352);
    unsigned short* w_vsb  = (unsigned short*)(ws + 21520384);
    unsigned short* w_qbf  = (unsigned short*)(ws + 22568960);
    unsigned short* w_vbf  = (unsigned short*)(ws + 26763264);
    unsigned short* w_wqbf = (unsigned short*)(ws + 30957568);
    unsigned short* w_wvbf = (unsigned short*)(ws + 31088640);

    // 1) all input conversions in one launch (+ vmbf pad zeros)
    conv_all<<<19008, 256, 0, stream>>>(query, value, Wq, Wv, Wl, vmem,
                                        w_qbf, w_vbf, w_wqbf, w_wvbf,
                                        w_wlbf, w_vmbf);
    // 2) input-only precomputes (prep_key_norm block 0 zeroes out_rc;
    //    prep_value_norm blocks >=112 zero vmTb/vnb pads)
    prep_key_norm<<<1024, 64, 0, stream>>>(keym, w_knb, out_rc);
    prep_value_norm<<<176, 256, 0, stream>>>(vmem, w_vn, w_vnb, w_vmTb);
    contrastive_kernel<<<112, 128, 0, stream>>>(w_vn, out_rc + 32);
    gemm_bf16<<<dim3(1, 4, 8), 256, 0, stream>>>(             // W2T bf16 direct
        (const short*)w_wlbf, HEADS * DIMC, (const short*)w_vmbf, DIMC,
        nullptr, w_w2tbf, HEADS * SLOTS, DIMC, nullptr, SLOTS,
        DIMC, 0, SLOTS);

    // 3) key addressing path
    gemm_bf16<<<dim3(4, 128), 256, 0, stream>>>(              // eqbf = q@Wq^T+bq
        (const short*)w_qbf, DIMC, (const short*)w_wqbf, DIMC,
        nullptr, w_xbf, DIMC, DIMC, bq, DIMC, 0, 0, 0);
    gemm_softmax<<<dim3(1, 128, 8), 256, 0, stream>>>(        // kaddc = softmax(sims)
        (const short*)w_xbf, DIMC, HD, (const short*)w_knb, HD, 128 * HD,
        HD, w_kaddc, HEADS * SLOTS, SLOTS, SLOTS);
    gemm_bf16<<<dim3(4, 128), 256, 0, stream>>>(              // vir_pre = kaddc@W2T^T+bl
        (const short*)w_kaddc, HEADS * SLOTS, (const short*)w_w2tbf, HEADS * SLOTS,
        w_big1, nullptr, DIMC, HEADS * SLOTS, bl, DIMC, 0, 0, 0);
    vir_te_w<<<NROWS / 8, 256, 0, stream>>>(w_big1, query, g1, b1, g2, b2, out_te);

    // 4) value addressing path
    gemm_bf16<<<dim3(4, 128), 256, 0, stream>>>(              // evbf = v@Wv^T+bv
        (const short*)w_vbf, DIMC, (const short*)w_wvbf, DIMC,
        nullptr, w_xbf, DIMC, DIMC, bv, DIMC, 0, 0, 0);
    gemm_softmax<<<dim3(1, 128, 1), 256, 0, stream>>>(        // vsb = softmax(ev@vn^T)
        (const short*)w_xbf, DIMC, 0, (const short*)w_vnb, DIMC, 0,
        DIMC, w_vsb, 128, 0, 128);
    gemm_bf16<<<dim3(4, 128), 256, 0, stream>>>(              // aud = vsb@vmTb^T (fp32)
        (const short*)w_vsb, 128, (const short*)w_vmTb, 128,
        w_big1, nullptr, DIMC, 128, nullptr, DIMC, 0, 0, 0);
    aud_epilogue_w<<<NROWS / 8, 256, 0, stream>>>(
        w_big1, value, query, g1, b1, g3, b3, out_tr, out_rc);
}

// Round 7
// 336.782 us; speedup vs baseline: 1.4847x; 1.0685x over previous
//
#include <hip/hip_runtime.h>
#include <math.h>

// Problem constants
#define DIMC   512
#define HEADS  8
#define SLOTS  112
#define HD     64          // DIMC/HEADS
#define NROWS  16384       // B*S = 32*512
#define RADIUSF 16.0f

typedef short short8 __attribute__((ext_vector_type(8)));
typedef unsigned short ushort8 __attribute__((ext_vector_type(8)));
typedef float f32x4  __attribute__((ext_vector_type(4)));

__device__ __forceinline__ unsigned short f2bf(float f)
{
    unsigned u = __float_as_uint(f);
    unsigned r = (u + 0x7FFFu + ((u >> 16) & 1u)) >> 16;   // RNE
    return (unsigned short)r;
}
__device__ __forceinline__ float bf2f(unsigned short h)
{
    return __uint_as_float((unsigned)h << 16);
}

// Async global->LDS 16B/lane. LDS dest is wave-uniform base + lane*16.
__device__ __forceinline__ void gl16(const void* g, void* lds_wave_base)
{
    __builtin_amdgcn_global_load_lds(
        (const __attribute__((address_space(1))) unsigned int*)g,
        (__attribute__((address_space(3))) unsigned int*)lds_wave_base,
        16, 0, 0);
}

// ---------------------------------------------------------------------------
// DPP-based wave reductions (validated rounds 2-6). VALU-only, no LDS pipe.
// ---------------------------------------------------------------------------
#define DPP_ADD(x, ctrl, rmask)                                               \
    (x) += __int_as_float(__builtin_amdgcn_update_dpp(                        \
               0, __float_as_int(x), (ctrl), (rmask), 0xf, true))

__device__ __forceinline__ float wsum64(float x)
{
    DPP_ADD(x, 0x111, 0xf);
    DPP_ADD(x, 0x112, 0xf);
    DPP_ADD(x, 0x114, 0xf);
    DPP_ADD(x, 0x118, 0xf);
    DPP_ADD(x, 0x142, 0xa);
    DPP_ADD(x, 0x143, 0xc);
    return __int_as_float(__builtin_amdgcn_readlane(__float_as_int(x), 63));
}

__device__ __forceinline__ void wsum64_4(float& a, float& b, float& c, float& d)
{
    DPP_ADD(a, 0x111, 0xf); DPP_ADD(b, 0x111, 0xf); DPP_ADD(c, 0x111, 0xf); DPP_ADD(d, 0x111, 0xf);
    DPP_ADD(a, 0x112, 0xf); DPP_ADD(b, 0x112, 0xf); DPP_ADD(c, 0x112, 0xf); DPP_ADD(d, 0x112, 0xf);
    DPP_ADD(a, 0x114, 0xf); DPP_ADD(b, 0x114, 0xf); DPP_ADD(c, 0x114, 0xf); DPP_ADD(d, 0x114, 0xf);
    DPP_ADD(a, 0x118, 0xf); DPP_ADD(b, 0x118, 0xf); DPP_ADD(c, 0x118, 0xf); DPP_ADD(d, 0x118, 0xf);
    DPP_ADD(a, 0x142, 0xa); DPP_ADD(b, 0x142, 0xa); DPP_ADD(c, 0x142, 0xa); DPP_ADD(d, 0x142, 0xa);
    DPP_ADD(a, 0x143, 0xc); DPP_ADD(b, 0x143, 0xc); DPP_ADD(c, 0x143, 0xc); DPP_ADD(d, 0x143, 0xc);
    a = __int_as_float(__builtin_amdgcn_readlane(__float_as_int(a), 63));
    b = __int_as_float(__builtin_amdgcn_readlane(__float_as_int(b), 63));
    c = __int_as_float(__builtin_amdgcn_readlane(__float_as_int(c), 63));
    d = __int_as_float(__builtin_amdgcn_readlane(__float_as_int(d), 63));
}

// ---------------------------------------------------------------------------
// bf16 MFMA GEMM: C(MxN fp32) / Cb(MxN bf16) = A(MxK bf16) @ B(NxK bf16)^T
// (+ bias[col]). 128x128 tile, BK=32, gl16 staging (validated round 5/6).
// ---------------------------------------------------------------------------
__global__ __launch_bounds__(256)
void gemm_bf16(const short* __restrict__ A, int lda,
               const short* __restrict__ B, int ldb,
               float* __restrict__ C, unsigned short* __restrict__ Cb,
               int ldc, int K, const float* __restrict__ bias, int Nvalid,
               int aZ, int bZ, int cZ)
{
    __shared__ short As[128 * 32];
    __shared__ short Bs[128 * 32];
    A += (size_t)blockIdx.z * aZ;
    B += (size_t)blockIdx.z * bZ;
    const size_t czoff = (size_t)blockIdx.z * cZ;
    const int tid  = threadIdx.x;
    const int wave = tid >> 6;
    const int lane = tid & 63;
    const int m0 = blockIdx.y * 128;
    const int n0 = blockIdx.x * 128;
    const int wm = (wave >> 1) * 64;
    const int wn = (wave & 1) * 64;

    const int srow = tid >> 2;
    const int schk = (tid & 3) * 8;

    const int fr = lane & 15;
    const int fq = (lane >> 4) * 8;

    f32x4 acc[4][4] = {};

    const short* Ag = A + (size_t)(m0 + srow) * lda + schk;
    const short* Bg = B + (size_t)(n0 + srow) * ldb + schk;

    short* asL = As + wave * 512;
    short* asU = As + 2048 + wave * 512;
    short* bsL = Bs + wave * 512;
    short* bsU = Bs + 2048 + wave * 512;

    for (int k0 = 0; k0 < K; k0 += 32) {
        gl16(Ag, asL);
        gl16(Ag + (size_t)64 * lda, asU);
        gl16(Bg, bsL);
        gl16(Bg + (size_t)64 * ldb, bsU);
        Ag += 32; Bg += 32;
        __syncthreads();
        short8 af[4], bf[4];
        #pragma unroll
        for (int i = 0; i < 4; ++i)
            af[i] = *(const short8*)&As[(wm + i * 16 + fr) * 32 + fq];
        #pragma unroll
        for (int j = 0; j < 4; ++j)
            bf[j] = *(const short8*)&Bs[(wn + j * 16 + fr) * 32 + fq];
        #pragma unroll
        for (int i = 0; i < 4; ++i)
            #pragma unroll
            for (int j = 0; j < 4; ++j)
                acc[i][j] = __builtin_amdgcn_mfma_f32_16x16x32_bf16(
                    af[i], bf[j], acc[i][j], 0, 0, 0);
        __syncthreads();
    }

    const int cr = (lane >> 4) * 4;
    const int cc = lane & 15;
    #pragma unroll
    for (int i = 0; i < 4; ++i) {
        const int grow = m0 + wm + i * 16 + cr;
        #pragma unroll
        for (int j = 0; j < 4; ++j) {
            const int gcol = n0 + wn + j * 16 + cc;
            if (gcol < Nvalid) {
                const float bb = bias ? bias[gcol] : 0.f;
                const size_t base = czoff + (size_t)grow * ldc + gcol;
                #pragma unroll
                for (int r = 0; r < 4; ++r) {
                    const float val = acc[i][j][r] + bb;
                    if (C)  C[base + (size_t)r * ldc]  = val;
                    if (Cb) Cb[base + (size_t)r * ldc] = f2bf(val);
                }
            }
        }
    }
}

// ---------------------------------------------------------------------------
// Fused GEMM + in-kernel row-l2norm + row-softmax (validated round 6).
// ---------------------------------------------------------------------------
__global__ __launch_bounds__(256)
void gemm_softmax(const short* __restrict__ A, int lda, int aZ,
                  const short* __restrict__ B, int ldb, int bZ,
                  int K,
                  unsigned short* __restrict__ Ob, int ldo, int oPerZ, int padN)
{
    __shared__ short As[128 * 32];
    __shared__ short Bs[128 * 32];
    __shared__ float P[128][113];
    __shared__ float hinvS[128];
    A += (size_t)blockIdx.z * aZ;
    B += (size_t)blockIdx.z * bZ;
    const int tid  = threadIdx.x;
    const int wave = tid >> 6;
    const int lane = tid & 63;
    const int m0 = blockIdx.y * 128;
    const int wm = (wave >> 1) * 64;
    const int wn = (wave & 1) * 64;
    const int srow = tid >> 2;
    const int schk = (tid & 3) * 8;
    const int fr = lane & 15;
    const int fq = (lane >> 4) * 8;

    f32x4 acc[4][4] = {};
    float ss[4] = {0.f, 0.f, 0.f, 0.f};

    const short* Ag = A + (size_t)(m0 + srow) * lda + schk;
    const short* Bg = B + (size_t)srow * ldb + schk;

    short* asL = As + wave * 512;
    short* asU = As + 2048 + wave * 512;
    short* bsL = Bs + wave * 512;
    short* bsU = Bs + 2048 + wave * 512;

    for (int k0 = 0; k0 < K; k0 += 32) {
        gl16(Ag, asL);
        gl16(Ag + (size_t)64 * lda, asU);
        gl16(Bg, bsL);
        gl16(Bg + (size_t)64 * ldb, bsU);
        Ag += 32; Bg += 32;
        __syncthreads();
        short8 af[4], bf[4];
        #pragma unroll
        for (int i = 0; i < 4; ++i)
            af[i] = *(const short8*)&As[(wm + i * 16 + fr) * 32 + fq];
        #pragma unroll
        for (int j = 0; j < 4; ++j)
            bf[j] = *(const short8*)&Bs[(wn + j * 16 + fr) * 32 + fq];
        #pragma unroll
        for (int i = 0; i < 4; ++i)
            #pragma unroll
            for (int e = 0; e < 8; ++e) {
                const float f = bf2f((unsigned short)af[i][e]);
                ss[i] += f * f;
            }
        #pragma unroll
        for (int i = 0; i < 4; ++i)
            #pragma unroll
            for (int j = 0; j < 4; ++j)
                acc[i][j] = __builtin_amdgcn_mfma_f32_16x16x32_bf16(
                    af[i], bf[j], acc[i][j], 0, 0, 0);
        __syncthreads();
    }

    #pragma unroll
    for (int i = 0; i < 4; ++i) {
        ss[i] += __shfl_xor(ss[i], 16, 64);
        ss[i] += __shfl_xor(ss[i], 32, 64);
    }
    if (lane < 16) {
        #pragma unroll
        for (int i = 0; i < 4; ++i)
            hinvS[wm + i * 16 + lane] = 1.f / fmaxf(sqrtf(ss[i]), 1e-12f);
    }

    const int cr = (lane >> 4) * 4;
    const int cc = lane & 15;
    #pragma unroll
    for (int i = 0; i < 4; ++i) {
        const int prow = wm + i * 16 + cr;
        #pragma unroll
        for (int j = 0; j < 4; ++j) {
            const int pcol = wn + j * 16 + cc;
            if (pcol < SLOTS) {
                #pragma unroll
                for (int r = 0; r < 4; ++r)
                    P[prow + r][pcol] = acc[i][j][r];
            }
        }
    }
    __syncthreads();

    const int rowt = tid >> 1;
    const int half = tid & 1;
    const int k0 = half * 56;
    const int rr = m0 + rowt;
    const float s = RADIUSF * hinvS[rowt];
    float mx = -1e30f;
    for (int k = k0; k < k0 + 56; ++k) mx = fmaxf(mx, P[rowt][k]);
    mx = fmaxf(mx, __shfl_xor(mx, 1, 64));
    float sum = 0.f;
    for (int k = k0; k < k0 + 56; ++k) {
        const float e = __expf(s * (P[rowt][k] - mx));
        P[rowt][k] = e;
        sum += e;
    }
    sum += __shfl_xor(sum, 1, 64);
    const float inv = 1.f / sum;
    unsigned short* orow = Ob + (size_t)rr * ldo + (size_t)blockIdx.z * oPerZ;
    for (int k = k0; k < k0 + 56; ++k) orow[k] = f2bf(P[rowt][k] * inv);
    if (half == 1)
        for (int k = SLOTS; k < padN; ++k) orow[k] = 0;
}

// ---------------------------------------------------------------------------
// Round-10: fused GEMM (32x512 tile) + full LN epilogue. Each block owns 32
// COMPLETE rows -> the LN chains fuse in-block, deleting the 33 MB fp32
// vir_pre/aud HBM round-trips and 2 dispatches. acc scattered once to LDS
// P[32][516] (stride 516: 16B-aligned; row+4 -> +16 banks -> 2-way write
// conflict = free; epilogue reads contiguous per row). Staging aliased in P.
// ---------------------------------------------------------------------------

// GEMM core shared by both fused kernels: computes acc[2][8] for a 32x512
// tile at row m0, staging A (32xBK) and B (512xBK) via gl16.
#define FUSED_GEMM_CORE(A, lda, B, ldb, K)                                    \
    f32x4 acc[2][8] = {};                                                     \
    {                                                                         \
        const int lrow = lane >> 2;                                           \
        const int lchk = (lane & 3) * 8;                                      \
        const short* Ag = (A) + (size_t)(m0 + wave * 16 + lrow) * (lda) + lchk;\
        const short* Bg = (B) + (size_t)(wave * 16 + lrow) * (ldb) + lchk;    \
        short* asB = As + wave * 512;                                         \
        short* bsB = Bs + wave * 512;                                         \
        for (int k0 = 0; k0 < (K); k0 += 32) {                                \
            if (wave < 2) gl16(Ag, asB);                                      \
            _Pragma("unroll")                                                 \
            for (int s = 0; s < 8; ++s)                                       \
                gl16(Bg + (size_t)(s * 64) * (ldb), bsB + s * 2048);          \
            Ag += 32; Bg += 32;                                               \
            __syncthreads();                                                  \
            short8 af[2], bf[8];                                              \
            af[0] = *(const short8*)&As[fr * 32 + fq];                        \
            af[1] = *(const short8*)&As[(16 + fr) * 32 + fq];                 \
            _Pragma("unroll")                                                 \
            for (int c = 0; c < 8; ++c)                                       \
                bf[c] = *(const short8*)&Bs[(wave * 128 + c * 16 + fr) * 32 + fq];\
            _Pragma("unroll")                                                 \
            for (int i = 0; i < 2; ++i)                                       \
                _Pragma("unroll")                                             \
                for (int c = 0; c < 8; ++c)                                   \
                    acc[i][c] = __builtin_amdgcn_mfma_f32_16x16x32_bf16(      \
                        af[i], bf[c], acc[i][c], 0, 0, 0);                    \
            __syncthreads();                                                  \
        }                                                                     \
    }                                                                         \
    {                                                                         \
        const int cr = (lane >> 4) * 4;                                       \
        const int cc = lane & 15;                                             \
        _Pragma("unroll")                                                     \
        for (int i = 0; i < 2; ++i)                                           \
            _Pragma("unroll")                                                 \
            for (int c = 0; c < 8; ++c) {                                     \
                const int col = wave * 128 + c * 16 + cc;                     \
                _Pragma("unroll")                                             \
                for (int r = 0; r < 4; ++r)                                   \
                    P[(i * 16 + cr + r) * 516 + col] = acc[i][c][r];          \
            }                                                                 \
    }                                                                         \
    __syncthreads();

// vir path: x = A@B^T + bl -> LN(g2,b2) -> +query -> LN(g1,b1) -> out_te
__global__ __launch_bounds__(256)
void gemm_vir_te(const short* __restrict__ A, int lda,
                 const short* __restrict__ B, int ldb, int K,
                 const float* __restrict__ bias, const float* __restrict__ query,
                 const float* __restrict__ g1, const float* __restrict__ b1,
                 const float* __restrict__ g2, const float* __restrict__ b2,
                 float* __restrict__ out_te)
{
    __shared__ float P[32 * 516];          // 66 KB; staging aliased below
    short* As = (short*)P;                 // 32x32 shorts (2 KB)
    short* Bs = As + 1024;                 // 512x32 shorts (32 KB)
    const int tid = threadIdx.x;
    const int wave = tid >> 6;
    const int lane = tid & 63;
    const int m0 = blockIdx.x * 32;
    const int fr = lane & 15;
    const int fq = (lane >> 4) * 8;

    FUSED_GEMM_CORE(A, lda, B, ldb, K)

    const int c0 = lane * 8;
    float blv[8], gg2[8], bb2[8], gg1[8], bb1[8];
    *(f32x4*)&blv[0] = *(const f32x4*)(bias + c0);
    *(f32x4*)&blv[4] = *(const f32x4*)(bias + c0 + 4);
    *(f32x4*)&gg2[0] = *(const f32x4*)(g2 + c0);
    *(f32x4*)&gg2[4] = *(const f32x4*)(g2 + c0 + 4);
    *(f32x4*)&bb2[0] = *(const f32x4*)(b2 + c0);
    *(f32x4*)&bb2[4] = *(const f32x4*)(b2 + c0 + 4);
    *(f32x4*)&gg1[0] = *(const f32x4*)(g1 + c0);
    *(f32x4*)&gg1[4] = *(const f32x4*)(g1 + c0 + 4);
    *(f32x4*)&bb1[0] = *(const f32x4*)(b1 + c0);
    *(f32x4*)&bb1[4] = *(const f32x4*)(b1 + c0 + 4);

    for (int rp = 0; rp < 4; ++rp) {
        const int lr0 = rp * 8 + wave * 2;
        float x[2][8], q[2][8];
        #pragma unroll
        for (int p = 0; p < 2; ++p) {
            *(f32x4*)&x[p][0] = *(const f32x4*)&P[(lr0 + p) * 516 + c0];
            *(f32x4*)&x[p][4] = *(const f32x4*)&P[(lr0 + p) * 516 + c0 + 4];
            const size_t gbase = (size_t)(m0 + lr0 + p) * DIMC + c0;
            *(f32x4*)&q[p][0] = *(const f32x4*)(query + gbase);
            *(f32x4*)&q[p][4] = *(const f32x4*)(query + gbase + 4);
            #pragma unroll
            for (int j = 0; j < 8; ++j) x[p][j] += blv[j];
        }
        float s1[2] = {0.f, 0.f}, s2[2] = {0.f, 0.f};
        #pragma unroll
        for (int p = 0; p < 2; ++p)
            #pragma unroll
            for (int j = 0; j < 8; ++j) {
                s1[p] += x[p][j];
                s2[p] += x[p][j] * x[p][j];
            }
        wsum64_4(s1[0], s2[0], s1[1], s2[1]);

        float y[2][8];
        float t1[2] = {0.f, 0.f}, t2[2] = {0.f, 0.f};
        #pragma unroll
        for (int p = 0; p < 2; ++p) {
            const float mu = s1[p] * (1.f / DIMC);
            const float var = s2[p] * (1.f / DIMC) - mu * mu;
            const float rstd = rsqrtf(var + 1e-5f);
            #pragma unroll
            for (int j = 0; j < 8; ++j) {
                const float v = (x[p][j] - mu) * rstd * gg2[j] + bb2[j];
                y[p][j] = q[p][j] + v;
                t1[p] += y[p][j];
                t2[p] += y[p][j] * y[p][j];
            }
        }
        wsum64_4(t1[0], t2[0], t1[1], t2[1]);

        #pragma unroll
        for (int p = 0; p < 2; ++p) {
            const float mu = t1[p] * (1.f / DIMC);
            const float var = t2[p] * (1.f / DIMC) - mu * mu;
            const float rstd = rsqrtf(var + 1e-5f);
            float o[8];
            #pragma unroll
            for (int j = 0; j < 8; ++j)
                o[j] = (y[p][j] - mu) * rstd * gg1[j] + bb1[j];
            const size_t gbase = (size_t)(m0 + lr0 + p) * DIMC + c0;
            *(float4*)(out_te + gbase)     = make_float4(o[0], o[1], o[2], o[3]);
            *(float4*)(out_te + gbase + 4) = make_float4(o[4], o[5], o[6], o[7]);
        }
    }
}

// aud path: a = A@B^T -> cos/recon vs value -> LN(g3,b3) -> +query ->
// LN(g1,b1) -> out_tr (+ one recon atomic per block; 32 | 512 so all rows
// of a block share the batch index).
__global__ __launch_bounds__(256)
void gemm_aud_tr(const short* __restrict__ A, int lda,
                 const short* __restrict__ B, int ldb, int K,
                 const float* __restrict__ value, const float* __restrict__ query,
                 const float* __restrict__ g1, const float* __restrict__ b1,
                 const float* __restrict__ g3, const float* __restrict__ b3,
                 float* __restrict__ out_tr, float* __restrict__ recon)
{
    __shared__ float P[32 * 516];
    __shared__ float red[4];
    short* As = (short*)P;
    short* Bs = As + 1024;
    const int tid = threadIdx.x;
    const int wave = tid >> 6;
    const int lane = tid & 63;
    const int m0 = blockIdx.x * 32;
    const int fr = lane & 15;
    const int fq = (lane >> 4) * 8;

    FUSED_GEMM_CORE(A, lda, B, ldb, K)

    const int c0 = lane * 8;
    float gg3[8], bb3[8], gg1[8], bb1[8];
    *(f32x4*)&gg3[0] = *(const f32x4*)(g3 + c0);
    *(f32x4*)&gg3[4] = *(const f32x4*)(g3 + c0 + 4);
    *(f32x4*)&bb3[0] = *(const f32x4*)(b3 + c0);
    *(f32x4*)&bb3[4] = *(const f32x4*)(b3 + c0 + 4);
    *(f32x4*)&gg1[0] = *(const f32x4*)(g1 + c0);
    *(f32x4*)&gg1[4] = *(const f32x4*)(g1 + c0 + 4);
    *(f32x4*)&bb1[0] = *(const f32x4*)(b1 + c0);
    *(f32x4*)&bb1[4] = *(const f32x4*)(b1 + c0 + 4);

    float rloc = 0.f;
    for (int rp = 0; rp < 4; ++rp) {
        const int lr0 = rp * 8 + wave * 2;
        float a[2][8], v[2][8], q[2][8];
        #pragma unroll
        for (int p = 0; p < 2; ++p) {
            *(f32x4*)&a[p][0] = *(const f32x4*)&P[(lr0 + p) * 516 + c0];
            *(f32x4*)&a[p][4] = *(const f32x4*)&P[(lr0 + p) * 516 + c0 + 4];
            const size_t gbase = (size_t)(m0 + lr0 + p) * DIMC + c0;
            *(f32x4*)&v[p][0] = *(const f32x4*)(value + gbase);
            *(f32x4*)&v[p][4] = *(const f32x4*)(value + gbase + 4);
            *(f32x4*)&q[p][0] = *(const f32x4*)(query + gbase);
            *(f32x4*)&q[p][4] = *(const f32x4*)(query + gbase + 4);
        }
        float dot[2] = {0.f, 0.f}, na[2] = {0.f, 0.f};
        float nv[2] = {0.f, 0.f}, s1[2] = {0.f, 0.f};
        #pragma unroll
        for (int p = 0; p < 2; ++p)
            #pragma unroll
            for (int j = 0; j < 8; ++j) {
                dot[p] += a[p][j] * v[p][j];
                na[p]  += a[p][j] * a[p][j];
                nv[p]  += v[p][j] * v[p][j];
                s1[p]  += a[p][j];
            }
        wsum64_4(dot[0], na[0], nv[0], s1[0]);
        wsum64_4(dot[1], na[1], nv[1], s1[1]);

        #pragma unroll
        for (int p = 0; p < 2; ++p) {
            const float cosv = dot[p] / fmaxf(sqrtf(na[p]) * sqrtf(nv[p]), 1e-8f);
            rloc += fabsf(1.f - cosv);
        }

        float y[2][8];
        float t1[2] = {0.f, 0.f}, t2[2] = {0.f, 0.f};
        #pragma unroll
        for (int p = 0; p < 2; ++p) {
            const float mu = s1[p] * (1.f / DIMC);
            const float var = na[p] * (1.f / DIMC) - mu * mu;   // na == sum(a^2)
            const float rstd = rsqrtf(var + 1e-5f);
            #pragma unroll
            for (int j = 0; j < 8; ++j) {
                const float w = (a[p][j] - mu) * rstd * gg3[j] + bb3[j];
                y[p][j] = q[p][j] + w;
                t1[p] += y[p][j];
                t2[p] += y[p][j] * y[p][j];
            }
        }
        wsum64_4(t1[0], t2[0], t1[1], t2[1]);

        #pragma unroll
        for (int p = 0; p < 2; ++p) {
            const float mu = t1[p] * (1.f / DIMC);
            const float var = t2[p] * (1.f / DIMC) - mu * mu;
            const float rstd = rsqrtf(var + 1e-5f);
            float o[8];
            #pragma unroll
            for (int j = 0; j < 8; ++j)
                o[j] = (y[p][j] - mu) * rstd * gg1[j] + bb1[j];
            const size_t gbase = (size_t)(m0 + lr0 + p) * DIMC + c0;
            *(float4*)(out_tr + gbase)     = make_float4(o[0], o[1], o[2], o[3]);
            *(float4*)(out_tr + gbase + 4) = make_float4(o[4], o[5], o[6], o[7]);
        }
    }

    if (lane == 0) red[wave] = rloc;
    __syncthreads();
    if (tid == 0)
        atomicAdd(&recon[m0 >> 9], red[0] + red[1] + red[2] + red[3]);
}

// ---------------------------------------------------------------------------
// Small helpers (all validated round 6)
// ---------------------------------------------------------------------------
__device__ __forceinline__ float block_sum_256(float v, float* red)
{
    #pragma unroll
    for (int off = 32; off; off >>= 1) v += __shfl_down(v, off, 64);
    const int lane = threadIdx.x & 63, wid = threadIdx.x >> 6;
    __syncthreads();
    if (lane == 0) red[wid] = v;
    __syncthreads();
    return red[0] + red[1] + red[2] + red[3];
}

__global__ void conv_all(const float* __restrict__ q, const float* __restrict__ v,
                         const float* __restrict__ Wq, const float* __restrict__ Wv,
                         const float* __restrict__ Wl, const float* __restrict__ vm,
                         unsigned short* __restrict__ qbf, unsigned short* __restrict__ vbf,
                         unsigned short* __restrict__ wqbf, unsigned short* __restrict__ wvbf,
                         unsigned short* __restrict__ wlbf, unsigned short* __restrict__ vmbf)
{
    const int i = blockIdx.x * blockDim.x + threadIdx.x;   // float4-unit index
    const float* src;
    unsigned short* dst;
    int off;
    if (i < 2097152)      { src = q;  dst = qbf;  off = i; }
    else if (i < 4194304) { src = v;  dst = vbf;  off = i - 2097152; }
    else if (i < 4259840) { src = Wq; dst = wqbf; off = i - 4194304; }
    else if (i < 4325376) { src = Wv; dst = wvbf; off = i - 4259840; }
    else if (i < 4849664) { src = Wl; dst = wlbf; off = i - 4325376; }
    else if (i < 4864000) { src = vm; dst = vmbf; off = i - 4849664; }
    else {                 // zero vmbf pad rows 112..127 (8192 bf16)
        const int j = i - 4864000;   // 0..2047
        *(ushort4*)(vmbf + 57344 + (size_t)j * 4) = make_ushort4(0, 0, 0, 0);
        return;
    }
    const float4 x = *(const float4*)(src + (size_t)off * 4);
    ushort4 o;
    o.x = f2bf(x.x); o.y = f2bf(x.y); o.z = f2bf(x.z); o.w = f2bf(x.w);
    *(ushort4*)(dst + (size_t)off * 4) = o;
}

__global__ void prep_key_norm(const float* __restrict__ km,
                              unsigned short* __restrict__ knb,
                              float* __restrict__ outrc)
{
    const int row = blockIdx.x;         // h*128+s
    const int h = row >> 7, s = row & 127;
    const int lane = threadIdx.x;       // 64 threads
    if (row == 0 && lane < 33) outrc[lane] = 0.f;
    const float v = (s < SLOTS) ? km[(size_t)(h * SLOTS + s) * HD + lane] : 0.f;
    const float ssum = wsum64(v * v);
    const float inv = 1.f / fmaxf(sqrtf(ssum), 1e-12f);
    knb[(size_t)row * HD + lane] = f2bf(v * inv);
}

__global__ void prep_value_norm(const float* __restrict__ vm,
                                float* __restrict__ vn,
                                unsigned short* __restrict__ vnb,
                                unsigned short* __restrict__ vmTb)
{
    const int row = blockIdx.x;        // 0..175
    const int tid = threadIdx.x;       // 256
    if (row >= 112) {
        const int idx = (row - 112) * 256 + tid;   // 0..16383
        if (idx < 8192) {
            vmTb[(size_t)(idx >> 4) * 128 + 112 + (idx & 15)] = 0;
        } else {
            const int j = idx - 8192;
            vnb[(size_t)(112 + (j >> 9)) * 512 + (j & 511)] = 0;
        }
        return;
    }
    __shared__ float red[4];
    const float v0 = vm[(size_t)row * DIMC + tid];
    const float v1 = vm[(size_t)row * DIMC + 256 + tid];
    const float tot = block_sum_256(v0 * v0 + v1 * v1, red);
    const float inv = 1.f / fmaxf(sqrtf(tot), 1e-12f);
    vn[(size_t)row * DIMC + tid]        = v0 * inv;
    vn[(size_t)row * DIMC + 256 + tid]  = v1 * inv;
    vnb[(size_t)row * DIMC + tid]       = f2bf(v0 * inv);
    vnb[(size_t)row * DIMC + 256 + tid] = f2bf(v1 * inv);
    vmTb[(size_t)tid * 128 + row]         = f2bf(v0);
    vmTb[(size_t)(256 + tid) * 128 + row] = f2bf(v1);
}

__global__ void contrastive_kernel(const float* __restrict__ vn, float* __restrict__ outc)
{
    __shared__ float vni[DIMC];
    __shared__ float red[2];
    const int i = blockIdx.x, tid = threadIdx.x;   // 128 threads
    for (int d = tid; d < DIMC; d += 128) vni[d] = vn[(size_t)i * DIMC + d];
    __syncthreads();
    float t = 0.f;
    if (tid < SLOTS) {
        const float* r = vn + (size_t)tid * DIMC;
        float dot = 0.f;
        for (int d = 0; d < DIMC; ++d) dot += vni[d] * r[d];
        const float delta = (tid == i) ? 1.f : 0.f;
        t = fabsf(delta - dot);
    }
    #pragma unroll
    for (int off = 32; off; off >>= 1) t += __shfl_down(t, off, 64);
    if ((tid & 63) == 0) red[tid >> 6] = t;
    __syncthreads();
    if (tid == 0) atomicAdd(outc, 0.5f * (red[0] + red[1]));
}

// ---------------------------------------------------------------------------
// Launch
// ---------------------------------------------------------------------------
extern "C" void kernel_launch(void* const* d_in, const int* in_sizes, int n_in,
                              void* d_out, int out_size, void* d_ws, size_t ws_size,
                              hipStream_t stream)
{
    const float* query = (const float*)d_in[0];
    const float* value = (const float*)d_in[1];
    const float* keym  = (const float*)d_in[2];
    const float* vmem  = (const float*)d_in[3];
    const float* Wq    = (const float*)d_in[4];
    const float* bq    = (const float*)d_in[5];
    const float* Wv    = (const float*)d_in[6];
    const float* bv    = (const float*)d_in[7];
    const float* Wl    = (const float*)d_in[8];
    const float* bl    = (const float*)d_in[9];
    const float* g1    = (const float*)d_in[10];
    const float* b1    = (const float*)d_in[11];
    const float* g2    = (const float*)d_in[12];
    const float* b2    = (const float*)d_in[13];
    const float* g3    = (const float*)d_in[14];
    const float* b3    = (const float*)d_in[15];

    float* out    = (float*)d_out;
    float* out_te = out;
    float* out_tr = out + 8388608;
    float* out_rc = out + 16777216;    // 32 recon + 1 contrastive

    // Workspace layout (float offsets), round-10 (big1 deleted).
    //   0         knb    [8][128][64] bf16    32768 fl
    //   32768     vmTb   [512][128]  bf16     32768 fl
    //   65536     vnb    [128][512]  bf16     32768 fl
    //   98304     vn     [112][512]  fp32     57344 fl
    //   155648    w2tbf  [512][896]  bf16     229376 fl
    //   385024    vmbf   [128][512]  bf16     32768 fl
    //   417792    wlbf   [512][4096] bf16     1048576 fl
    //   1466368   xbf:  eqbf (key) -> evbf (value)     4194304 fl
    //   5660672   kaddc [16384][896] bf16 compact      7340032 fl
    //   13000704  vsb   [16384][128] bf16              1048576 fl
    //   14049280  qbf                                  4194304 fl
    //   18243584  vbf                                  4194304 fl
    //   22437888  wqbf                                 131072 fl
    //   22568960  wvbf                                 131072 fl
    // total 22700032 < 34054144.
    float* ws = (float*)d_ws;
    unsigned short* w_knb  = (unsigned short*)(ws + 0);
    unsigned short* w_vmTb = (unsigned short*)(ws + 32768);
    unsigned short* w_vnb  = (unsigned short*)(ws + 65536);
    float*          w_vn   = ws + 98304;
    unsigned short* w_w2tbf= (unsigned short*)(ws + 155648);
    unsigned short* w_vmbf = (unsigned short*)(ws + 385024);
    unsigned short* w_wlbf = (unsigned short*)(ws + 417792);
    unsigned short* w_xbf  = (unsigned short*)(ws + 1466368);
    unsigned short* w_kaddc= (unsigned short*)(ws + 5660672);
    unsigned short* w_vsb  = (unsigned short*)(ws + 13000704);
    unsigned short* w_qbf  = (unsigned short*)(ws + 14049280);
    unsigned short* w_vbf  = (unsigned short*)(ws + 18243584);
    unsigned short* w_wqbf = (unsigned short*)(ws + 22437888);
    unsigned short* w_wvbf = (unsigned short*)(ws + 22568960);

    // 1) all input conversions in one launch (+ vmbf pad zeros)
    conv_all<<<19008, 256, 0, stream>>>(query, value, Wq, Wv, Wl, vmem,
                                        w_qbf, w_vbf, w_wqbf, w_wvbf,
                                        w_wlbf, w_vmbf);
    // 2) input-only precomputes
    prep_key_norm<<<1024, 64, 0, stream>>>(keym, w_knb, out_rc);
    prep_value_norm<<<176, 256, 0, stream>>>(vmem, w_vn, w_vnb, w_vmTb);
    contrastive_kernel<<<112, 128, 0, stream>>>(w_vn, out_rc + 32);
    gemm_bf16<<<dim3(1, 4, 8), 256, 0, stream>>>(             // W2T bf16 direct
        (const short*)w_wlbf, HEADS * DIMC, (const short*)w_vmbf, DIMC,
        nullptr, w_w2tbf, HEADS * SLOTS, DIMC, nullptr, SLOTS,
        DIMC, 0, SLOTS);

    // 3) key addressing path
    gemm_bf16<<<dim3(4, 128), 256, 0, stream>>>(              // eqbf = q@Wq^T+bq
        (const short*)w_qbf, DIMC, (const short*)w_wqbf, DIMC,
        nullptr, w_xbf, DIMC, DIMC, bq, DIMC, 0, 0, 0);
    gemm_softmax<<<dim3(1, 128, 8), 256, 0, stream>>>(        // kaddc = softmax(sims)
        (const short*)w_xbf, DIMC, HD, (const short*)w_knb, HD, 128 * HD,
        HD, w_kaddc, HEADS * SLOTS, SLOTS, SLOTS);
    gemm_vir_te<<<NROWS / 32, 256, 0, stream>>>(              // fused vir+LN+LN
        (const short*)w_kaddc, HEADS * SLOTS, (const short*)w_w2tbf, HEADS * SLOTS,
        HEADS * SLOTS, bl, query, g1, b1, g2, b2, out_te);

    // 4) value addressing path
    gemm_bf16<<<dim3(4, 128), 256, 0, stream>>>(              // evbf = v@Wv^T+bv
        (const short*)w_vbf, DIMC, (const short*)w_wvbf, DIMC,
        nullptr, w_xbf, DIMC, DIMC, bv, DIMC, 0, 0, 0);
    gemm_softmax<<<dim3(1, 128, 1), 256, 0, stream>>>(        // vsb = softmax(ev@vn^T)
        (const short*)w_xbf, DIMC, 0, (const short*)w_vnb, DIMC, 0,
        DIMC, w_vsb, 128, 0, 128);
    gemm_aud_tr<<<NROWS / 32, 256, 0, stream>>>(              // fused aud+cos+LN+LN
        (const short*)w_vsb, 128, (const short*)w_vmTb, 128, 128,
        value, query, g1, b1, g3, b3, out_tr, out_rc);
}

// Round 8
// 328.901 us; speedup vs baseline: 1.5203x; 1.0240x over previous
//
#include <hip/hip_runtime.h>
#include <math.h>

// Problem constants
#define DIMC   512
#define HEADS  8
#define SLOTS  112
#define HD     64          // DIMC/HEADS
#define NROWS  16384       // B*S = 32*512
#define RADIUSF 16.0f

typedef short short8 __attribute__((ext_vector_type(8)));
typedef unsigned short ushort8 __attribute__((ext_vector_type(8)));
typedef float f32x4  __attribute__((ext_vector_type(4)));

__device__ __forceinline__ unsigned short f2bf(float f)
{
    unsigned u = __float_as_uint(f);
    unsigned r = (u + 0x7FFFu + ((u >> 16) & 1u)) >> 16;   // RNE
    return (unsigned short)r;
}
__device__ __forceinline__ float bf2f(unsigned short h)
{
    return __uint_as_float((unsigned)h << 16);
}

// Async global->LDS 16B/lane. LDS dest is wave-uniform base + lane*16.
__device__ __forceinline__ void gl16(const void* g, void* lds_wave_base)
{
    __builtin_amdgcn_global_load_lds(
        (const __attribute__((address_space(1))) unsigned int*)g,
        (__attribute__((address_space(3))) unsigned int*)lds_wave_base,
        16, 0, 0);
}

// ---------------------------------------------------------------------------
// DPP-based wave reductions (validated rounds 2-7). VALU-only, no LDS pipe.
// ---------------------------------------------------------------------------
#define DPP_ADD(x, ctrl, rmask)                                               \
    (x) += __int_as_float(__builtin_amdgcn_update_dpp(                        \
               0, __float_as_int(x), (ctrl), (rmask), 0xf, true))

__device__ __forceinline__ float wsum64(float x)
{
    DPP_ADD(x, 0x111, 0xf);
    DPP_ADD(x, 0x112, 0xf);
    DPP_ADD(x, 0x114, 0xf);
    DPP_ADD(x, 0x118, 0xf);
    DPP_ADD(x, 0x142, 0xa);
    DPP_ADD(x, 0x143, 0xc);
    return __int_as_float(__builtin_amdgcn_readlane(__float_as_int(x), 63));
}

__device__ __forceinline__ void wsum64_4(float& a, float& b, float& c, float& d)
{
    DPP_ADD(a, 0x111, 0xf); DPP_ADD(b, 0x111, 0xf); DPP_ADD(c, 0x111, 0xf); DPP_ADD(d, 0x111, 0xf);
    DPP_ADD(a, 0x112, 0xf); DPP_ADD(b, 0x112, 0xf); DPP_ADD(c, 0x112, 0xf); DPP_ADD(d, 0x112, 0xf);
    DPP_ADD(a, 0x114, 0xf); DPP_ADD(b, 0x114, 0xf); DPP_ADD(c, 0x114, 0xf); DPP_ADD(d, 0x114, 0xf);
    DPP_ADD(a, 0x118, 0xf); DPP_ADD(b, 0x118, 0xf); DPP_ADD(c, 0x118, 0xf); DPP_ADD(d, 0x118, 0xf);
    DPP_ADD(a, 0x142, 0xa); DPP_ADD(b, 0x142, 0xa); DPP_ADD(c, 0x142, 0xa); DPP_ADD(d, 0x142, 0xa);
    DPP_ADD(a, 0x143, 0xc); DPP_ADD(b, 0x143, 0xc); DPP_ADD(c, 0x143, 0xc); DPP_ADD(d, 0x143, 0xc);
    a = __int_as_float(__builtin_amdgcn_readlane(__float_as_int(a), 63));
    b = __int_as_float(__builtin_amdgcn_readlane(__float_as_int(b), 63));
    c = __int_as_float(__builtin_amdgcn_readlane(__float_as_int(c), 63));
    d = __int_as_float(__builtin_amdgcn_readlane(__float_as_int(d), 63));
}

// ---------------------------------------------------------------------------
// bf16 MFMA GEMM: C(MxN fp32) / Cb(MxN bf16) = A(MxK bf16) @ B(NxK bf16)^T
// (+ bias[col]). 128x128 tile, BK=32, gl16 staging (validated round 5/6).
// ---------------------------------------------------------------------------
__global__ __launch_bounds__(256)
void gemm_bf16(const short* __restrict__ A, int lda,
               const short* __restrict__ B, int ldb,
               float* __restrict__ C, unsigned short* __restrict__ Cb,
               int ldc, int K, const float* __restrict__ bias, int Nvalid,
               int aZ, int bZ, int cZ)
{
    __shared__ short As[128 * 32];
    __shared__ short Bs[128 * 32];
    A += (size_t)blockIdx.z * aZ;
    B += (size_t)blockIdx.z * bZ;
    const size_t czoff = (size_t)blockIdx.z * cZ;
    const int tid  = threadIdx.x;
    const int wave = tid >> 6;
    const int lane = tid & 63;
    const int m0 = blockIdx.y * 128;
    const int n0 = blockIdx.x * 128;
    const int wm = (wave >> 1) * 64;
    const int wn = (wave & 1) * 64;

    const int srow = tid >> 2;
    const int schk = (tid & 3) * 8;

    const int fr = lane & 15;
    const int fq = (lane >> 4) * 8;

    f32x4 acc[4][4] = {};

    const short* Ag = A + (size_t)(m0 + srow) * lda + schk;
    const short* Bg = B + (size_t)(n0 + srow) * ldb + schk;

    short* asL = As + wave * 512;
    short* asU = As + 2048 + wave * 512;
    short* bsL = Bs + wave * 512;
    short* bsU = Bs + 2048 + wave * 512;

    for (int k0 = 0; k0 < K; k0 += 32) {
        gl16(Ag, asL);
        gl16(Ag + (size_t)64 * lda, asU);
        gl16(Bg, bsL);
        gl16(Bg + (size_t)64 * ldb, bsU);
        Ag += 32; Bg += 32;
        __syncthreads();
        short8 af[4], bf[4];
        #pragma unroll
        for (int i = 0; i < 4; ++i)
            af[i] = *(const short8*)&As[(wm + i * 16 + fr) * 32 + fq];
        #pragma unroll
        for (int j = 0; j < 4; ++j)
            bf[j] = *(const short8*)&Bs[(wn + j * 16 + fr) * 32 + fq];
        #pragma unroll
        for (int i = 0; i < 4; ++i)
            #pragma unroll
            for (int j = 0; j < 4; ++j)
                acc[i][j] = __builtin_amdgcn_mfma_f32_16x16x32_bf16(
                    af[i], bf[j], acc[i][j], 0, 0, 0);
        __syncthreads();
    }

    const int cr = (lane >> 4) * 4;
    const int cc = lane & 15;
    #pragma unroll
    for (int i = 0; i < 4; ++i) {
        const int grow = m0 + wm + i * 16 + cr;
        #pragma unroll
        for (int j = 0; j < 4; ++j) {
            const int gcol = n0 + wn + j * 16 + cc;
            if (gcol < Nvalid) {
                const float bb = bias ? bias[gcol] : 0.f;
                const size_t base = czoff + (size_t)grow * ldc + gcol;
                #pragma unroll
                for (int r = 0; r < 4; ++r) {
                    const float val = acc[i][j][r] + bb;
                    if (C)  C[base + (size_t)r * ldc]  = val;
                    if (Cb) Cb[base + (size_t)r * ldc] = f2bf(val);
                }
            }
        }
    }
}

// ---------------------------------------------------------------------------
// Fused GEMM + in-kernel row-l2norm + row-softmax (validated round 6).
// ---------------------------------------------------------------------------
__global__ __launch_bounds__(256)
void gemm_softmax(const short* __restrict__ A, int lda, int aZ,
                  const short* __restrict__ B, int ldb, int bZ,
                  int K,
                  unsigned short* __restrict__ Ob, int ldo, int oPerZ, int padN)
{
    __shared__ short As[128 * 32];
    __shared__ short Bs[128 * 32];
    __shared__ float P[128][113];
    __shared__ float hinvS[128];
    A += (size_t)blockIdx.z * aZ;
    B += (size_t)blockIdx.z * bZ;
    const int tid  = threadIdx.x;
    const int wave = tid >> 6;
    const int lane = tid & 63;
    const int m0 = blockIdx.y * 128;
    const int wm = (wave >> 1) * 64;
    const int wn = (wave & 1) * 64;
    const int srow = tid >> 2;
    const int schk = (tid & 3) * 8;
    const int fr = lane & 15;
    const int fq = (lane >> 4) * 8;

    f32x4 acc[4][4] = {};
    float ss[4] = {0.f, 0.f, 0.f, 0.f};

    const short* Ag = A + (size_t)(m0 + srow) * lda + schk;
    const short* Bg = B + (size_t)srow * ldb + schk;

    short* asL = As + wave * 512;
    short* asU = As + 2048 + wave * 512;
    short* bsL = Bs + wave * 512;
    short* bsU = Bs + 2048 + wave * 512;

    for (int k0 = 0; k0 < K; k0 += 32) {
        gl16(Ag, asL);
        gl16(Ag + (size_t)64 * lda, asU);
        gl16(Bg, bsL);
        gl16(Bg + (size_t)64 * ldb, bsU);
        Ag += 32; Bg += 32;
        __syncthreads();
        short8 af[4], bf[4];
        #pragma unroll
        for (int i = 0; i < 4; ++i)
            af[i] = *(const short8*)&As[(wm + i * 16 + fr) * 32 + fq];
        #pragma unroll
        for (int j = 0; j < 4; ++j)
            bf[j] = *(const short8*)&Bs[(wn + j * 16 + fr) * 32 + fq];
        #pragma unroll
        for (int i = 0; i < 4; ++i)
            #pragma unroll
            for (int e = 0; e < 8; ++e) {
                const float f = bf2f((unsigned short)af[i][e]);
                ss[i] += f * f;
            }
        #pragma unroll
        for (int i = 0; i < 4; ++i)
            #pragma unroll
            for (int j = 0; j < 4; ++j)
                acc[i][j] = __builtin_amdgcn_mfma_f32_16x16x32_bf16(
                    af[i], bf[j], acc[i][j], 0, 0, 0);
        __syncthreads();
    }

    #pragma unroll
    for (int i = 0; i < 4; ++i) {
        ss[i] += __shfl_xor(ss[i], 16, 64);
        ss[i] += __shfl_xor(ss[i], 32, 64);
    }
    if (lane < 16) {
        #pragma unroll
        for (int i = 0; i < 4; ++i)
            hinvS[wm + i * 16 + lane] = 1.f / fmaxf(sqrtf(ss[i]), 1e-12f);
    }

    const int cr = (lane >> 4) * 4;
    const int cc = lane & 15;
    #pragma unroll
    for (int i = 0; i < 4; ++i) {
        const int prow = wm + i * 16 + cr;
        #pragma unroll
        for (int j = 0; j < 4; ++j) {
            const int pcol = wn + j * 16 + cc;
            if (pcol < SLOTS) {
                #pragma unroll
                for (int r = 0; r < 4; ++r)
                    P[prow + r][pcol] = acc[i][j][r];
            }
        }
    }
    __syncthreads();

    const int rowt = tid >> 1;
    const int half = tid & 1;
    const int k0 = half * 56;
    const int rr = m0 + rowt;
    const float s = RADIUSF * hinvS[rowt];
    float mx = -1e30f;
    for (int k = k0; k < k0 + 56; ++k) mx = fmaxf(mx, P[rowt][k]);
    mx = fmaxf(mx, __shfl_xor(mx, 1, 64));
    float sum = 0.f;
    for (int k = k0; k < k0 + 56; ++k) {
        const float e = __expf(s * (P[rowt][k] - mx));
        P[rowt][k] = e;
        sum += e;
    }
    sum += __shfl_xor(sum, 1, 64);
    const float inv = 1.f / sum;
    unsigned short* orow = Ob + (size_t)rr * ldo + (size_t)blockIdx.z * oPerZ;
    for (int k = k0; k < k0 + 56; ++k) orow[k] = f2bf(P[rowt][k] * inv);
    if (half == 1)
        for (int k = SLOTS; k < padN; ++k) orow[k] = 0;
}

// ---------------------------------------------------------------------------
// Round-11 fused GEMM (32x512 tile) + LN epilogue, restructured:
// round-7 counters (gemm_vir_te 50 µs, Occupancy 18%, MfmaUtil 11%) showed
// a barrier-drain-bound loop at 2 waves/SIMD. Now: 512 threads = 8 waves
// (wave owns a 32x64 col slice, acc 2x4), TWO k-chunks per barrier pair
// (14 iters for K=896, 2 for K=128), two side-by-side 32-wide LDS tiles
// (row stride stays 64 B — avoids the 16-way conflict of native BK=64).
// LDS 68 KB (staging ∪ P[32][516]) -> 2 blocks/CU = 4 waves/SIMD.
// ---------------------------------------------------------------------------
#define FUSED_LDS_DECL                                                        \
    __shared__ float U[17408];  /* 69632 B: staging (68 KB) ∪ P (64.5 KB) */  \
    float* P = U;                                                             \
    short* As0 = (short*)U;          /* [32][32] chunk 0 */                   \
    short* As1 = As0 + 1024;         /* [32][32] chunk 1 */                   \
    short* Bs0 = As1 + 1024;         /* [512][32] chunk 0 */                  \
    short* Bs1 = Bs0 + 16384;        /* [512][32] chunk 1 */

#define FUSED_GEMM_CORE(Aptr, lda, Bptr, ldb, K)                              \
    f32x4 acc[2][4] = {};                                                     \
    {                                                                         \
        const int lrow = lane >> 2;                                           \
        const int lchk = (lane & 3) * 8;                                      \
        for (int k0 = 0; k0 < (K); k0 += 64) {                                \
            if (wave < 2)                                                     \
                gl16((Aptr) + (size_t)(m0 + wave * 16 + lrow) * (lda) + k0 + lchk, \
                     As0 + wave * 512);                                       \
            else if (wave < 4)                                                \
                gl16((Aptr) + (size_t)(m0 + (wave - 2) * 16 + lrow) * (lda) + k0 + 32 + lchk, \
                     As1 + (wave - 2) * 512);                                 \
            _Pragma("unroll")                                                 \
            for (int s = 0; s < 4; ++s) {                                     \
                const size_t brow = (size_t)(wave * 64 + s * 16 + lrow);      \
                gl16((Bptr) + brow * (ldb) + k0 + lchk,                       \
                     Bs0 + (wave * 64 + s * 16) * 32);                        \
                gl16((Bptr) + brow * (ldb) + k0 + 32 + lchk,                  \
                     Bs1 + (wave * 64 + s * 16) * 32);                        \
            }                                                                 \
            __syncthreads();                                                  \
            short8 af0[2], af1[2], bf0[4], bf1[4];                            \
            _Pragma("unroll")                                                 \
            for (int i = 0; i < 2; ++i) {                                     \
                af0[i] = *(const short8*)&As0[(i * 16 + fr) * 32 + fq];       \
                af1[i] = *(const short8*)&As1[(i * 16 + fr) * 32 + fq];       \
            }                                                                 \
            _Pragma("unroll")                                                 \
            for (int c = 0; c < 4; ++c) {                                     \
                bf0[c] = *(const short8*)&Bs0[(wave * 64 + c * 16 + fr) * 32 + fq]; \
                bf1[c] = *(const short8*)&Bs1[(wave * 64 + c * 16 + fr) * 32 + fq]; \
            }                                                                 \
            _Pragma("unroll")                                                 \
            for (int i = 0; i < 2; ++i)                                       \
                _Pragma("unroll")                                             \
                for (int c = 0; c < 4; ++c) {                                 \
                    acc[i][c] = __builtin_amdgcn_mfma_f32_16x16x32_bf16(      \
                        af0[i], bf0[c], acc[i][c], 0, 0, 0);                  \
                    acc[i][c] = __builtin_amdgcn_mfma_f32_16x16x32_bf16(      \
                        af1[i], bf1[c], acc[i][c], 0, 0, 0);                  \
                }                                                             \
            __syncthreads();                                                  \
        }                                                                     \
    }                                                                         \
    {                                                                         \
        const int cr = (lane >> 4) * 4;                                       \
        const int cc = lane & 15;                                             \
        _Pragma("unroll")                                                     \
        for (int i = 0; i < 2; ++i)                                           \
            _Pragma("unroll")                                                 \
            for (int c = 0; c < 4; ++c) {                                     \
                const int col = wave * 64 + c * 16 + cc;                      \
                _Pragma("unroll")                                             \
                for (int r = 0; r < 4; ++r)                                   \
                    P[(i * 16 + cr + r) * 516 + col] = acc[i][c][r];          \
            }                                                                 \
    }                                                                         \
    __syncthreads();

// vir path: x = A@B^T + bl -> LN(g2,b2) -> +query -> LN(g1,b1) -> out_te
__global__ __launch_bounds__(512, 4)
void gemm_vir_te(const short* __restrict__ A, int lda,
                 const short* __restrict__ B, int ldb, int K,
                 const float* __restrict__ bias, const float* __restrict__ query,
                 const float* __restrict__ g1, const float* __restrict__ b1,
                 const float* __restrict__ g2, const float* __restrict__ b2,
                 float* __restrict__ out_te)
{
    FUSED_LDS_DECL
    const int tid = threadIdx.x;
    const int wave = tid >> 6;
    const int lane = tid & 63;
    const int m0 = blockIdx.x * 32;
    const int fr = lane & 15;
    const int fq = (lane >> 4) * 8;

    FUSED_GEMM_CORE(A, lda, B, ldb, K)

    const int c0 = lane * 8;
    float blv[8], gg2[8], bb2[8], gg1[8], bb1[8];
    *(f32x4*)&blv[0] = *(const f32x4*)(bias + c0);
    *(f32x4*)&blv[4] = *(const f32x4*)(bias + c0 + 4);
    *(f32x4*)&gg2[0] = *(const f32x4*)(g2 + c0);
    *(f32x4*)&gg2[4] = *(const f32x4*)(g2 + c0 + 4);
    *(f32x4*)&bb2[0] = *(const f32x4*)(b2 + c0);
    *(f32x4*)&bb2[4] = *(const f32x4*)(b2 + c0 + 4);
    *(f32x4*)&gg1[0] = *(const f32x4*)(g1 + c0);
    *(f32x4*)&gg1[4] = *(const f32x4*)(g1 + c0 + 4);
    *(f32x4*)&bb1[0] = *(const f32x4*)(b1 + c0);
    *(f32x4*)&bb1[4] = *(const f32x4*)(b1 + c0 + 4);

    // 8 waves x 4 rows each; two 2-row passes per wave.
    for (int rp = 0; rp < 2; ++rp) {
        const int lr0 = wave * 4 + rp * 2;
        float x[2][8], q[2][8];
        #pragma unroll
        for (int p = 0; p < 2; ++p) {
            *(f32x4*)&x[p][0] = *(const f32x4*)&P[(lr0 + p) * 516 + c0];
            *(f32x4*)&x[p][4] = *(const f32x4*)&P[(lr0 + p) * 516 + c0 + 4];
            const size_t gbase = (size_t)(m0 + lr0 + p) * DIMC + c0;
            *(f32x4*)&q[p][0] = *(const f32x4*)(query + gbase);
            *(f32x4*)&q[p][4] = *(const f32x4*)(query + gbase + 4);
            #pragma unroll
            for (int j = 0; j < 8; ++j) x[p][j] += blv[j];
        }
        float s1[2] = {0.f, 0.f}, s2[2] = {0.f, 0.f};
        #pragma unroll
        for (int p = 0; p < 2; ++p)
            #pragma unroll
            for (int j = 0; j < 8; ++j) {
                s1[p] += x[p][j];
                s2[p] += x[p][j] * x[p][j];
            }
        wsum64_4(s1[0], s2[0], s1[1], s2[1]);

        float y[2][8];
        float t1[2] = {0.f, 0.f}, t2[2] = {0.f, 0.f};
        #pragma unroll
        for (int p = 0; p < 2; ++p) {
            const float mu = s1[p] * (1.f / DIMC);
            const float var = s2[p] * (1.f / DIMC) - mu * mu;
            const float rstd = rsqrtf(var + 1e-5f);
            #pragma unroll
            for (int j = 0; j < 8; ++j) {
                const float v = (x[p][j] - mu) * rstd * gg2[j] + bb2[j];
                y[p][j] = q[p][j] + v;
                t1[p] += y[p][j];
                t2[p] += y[p][j] * y[p][j];
            }
        }
        wsum64_4(t1[0], t2[0], t1[1], t2[1]);

        #pragma unroll
        for (int p = 0; p < 2; ++p) {
            const float mu = t1[p] * (1.f / DIMC);
            const float var = t2[p] * (1.f / DIMC) - mu * mu;
            const float rstd = rsqrtf(var + 1e-5f);
            float o[8];
            #pragma unroll
            for (int j = 0; j < 8; ++j)
                o[j] = (y[p][j] - mu) * rstd * gg1[j] + bb1[j];
            const size_t gbase = (size_t)(m0 + lr0 + p) * DIMC + c0;
            *(float4*)(out_te + gbase)     = make_float4(o[0], o[1], o[2], o[3]);
            *(float4*)(out_te + gbase + 4) = make_float4(o[4], o[5], o[6], o[7]);
        }
    }
}

// aud path: a = A@B^T -> cos/recon vs value -> LN(g3,b3) -> +query ->
// LN(g1,b1) -> out_tr (+ one recon atomic per block; 32 | 512).
__global__ __launch_bounds__(512, 4)
void gemm_aud_tr(const short* __restrict__ A, int lda,
                 const short* __restrict__ B, int ldb, int K,
                 const float* __restrict__ value, const float* __restrict__ query,
                 const float* __restrict__ g1, const float* __restrict__ b1,
                 const float* __restrict__ g3, const float* __restrict__ b3,
                 float* __restrict__ out_tr, float* __restrict__ recon)
{
    FUSED_LDS_DECL
    __shared__ float red[8];
    const int tid = threadIdx.x;
    const int wave = tid >> 6;
    const int lane = tid & 63;
    const int m0 = blockIdx.x * 32;
    const int fr = lane & 15;
    const int fq = (lane >> 4) * 8;

    FUSED_GEMM_CORE(A, lda, B, ldb, K)

    const int c0 = lane * 8;
    float gg3[8], bb3[8], gg1[8], bb1[8];
    *(f32x4*)&gg3[0] = *(const f32x4*)(g3 + c0);
    *(f32x4*)&gg3[4] = *(const f32x4*)(g3 + c0 + 4);
    *(f32x4*)&bb3[0] = *(const f32x4*)(b3 + c0);
    *(f32x4*)&bb3[4] = *(const f32x4*)(b3 + c0 + 4);
    *(f32x4*)&gg1[0] = *(const f32x4*)(g1 + c0);
    *(f32x4*)&gg1[4] = *(const f32x4*)(g1 + c0 + 4);
    *(f32x4*)&bb1[0] = *(const f32x4*)(b1 + c0);
    *(f32x4*)&bb1[4] = *(const f32x4*)(b1 + c0 + 4);

    float rloc = 0.f;
    for (int rp = 0; rp < 2; ++rp) {
        const int lr0 = wave * 4 + rp * 2;
        float a[2][8], v[2][8], q[2][8];
        #pragma unroll
        for (int p = 0; p < 2; ++p) {
            *(f32x4*)&a[p][0] = *(const f32x4*)&P[(lr0 + p) * 516 + c0];
            *(f32x4*)&a[p][4] = *(const f32x4*)&P[(lr0 + p) * 516 + c0 + 4];
            const size_t gbase = (size_t)(m0 + lr0 + p) * DIMC + c0;
            *(f32x4*)&v[p][0] = *(const f32x4*)(value + gbase);
            *(f32x4*)&v[p][4] = *(const f32x4*)(value + gbase + 4);
            *(f32x4*)&q[p][0] = *(const f32x4*)(query + gbase);
            *(f32x4*)&q[p][4] = *(const f32x4*)(query + gbase + 4);
        }
        float dot[2] = {0.f, 0.f}, na[2] = {0.f, 0.f};
        float nv[2] = {0.f, 0.f}, s1[2] = {0.f, 0.f};
        #pragma unroll
        for (int p = 0; p < 2; ++p)
            #pragma unroll
            for (int j = 0; j < 8; ++j) {
                dot[p] += a[p][j] * v[p][j];
                na[p]  += a[p][j] * a[p][j];
                nv[p]  += v[p][j] * v[p][j];
                s1[p]  += a[p][j];
            }
        wsum64_4(dot[0], na[0], nv[0], s1[0]);
        wsum64_4(dot[1], na[1], nv[1], s1[1]);

        #pragma unroll
        for (int p = 0; p < 2; ++p) {
            const float cosv = dot[p] / fmaxf(sqrtf(na[p]) * sqrtf(nv[p]), 1e-8f);
            rloc += fabsf(1.f - cosv);
        }

        float y[2][8];
        float t1[2] = {0.f, 0.f}, t2[2] = {0.f, 0.f};
        #pragma unroll
        for (int p = 0; p < 2; ++p) {
            const float mu = s1[p] * (1.f / DIMC);
            const float var = na[p] * (1.f / DIMC) - mu * mu;   // na == sum(a^2)
            const float rstd = rsqrtf(var + 1e-5f);
            #pragma unroll
            for (int j = 0; j < 8; ++j) {
                const float w = (a[p][j] - mu) * rstd * gg3[j] + bb3[j];
                y[p][j] = q[p][j] + w;
                t1[p] += y[p][j];
                t2[p] += y[p][j] * y[p][j];
            }
        }
        wsum64_4(t1[0], t2[0], t1[1], t2[1]);

        #pragma unroll
        for (int p = 0; p < 2; ++p) {
            const float mu = t1[p] * (1.f / DIMC);
            const float var = t2[p] * (1.f / DIMC) - mu * mu;
            const float rstd = rsqrtf(var + 1e-5f);
            float o[8];
            #pragma unroll
            for (int j = 0; j < 8; ++j)
                o[j] = (y[p][j] - mu) * rstd * gg1[j] + bb1[j];
            const size_t gbase = (size_t)(m0 + lr0 + p) * DIMC + c0;
            *(float4*)(out_tr + gbase)     = make_float4(o[0], o[1], o[2], o[3]);
            *(float4*)(out_tr + gbase + 4) = make_float4(o[4], o[5], o[6], o[7]);
        }
    }

    if (lane == 0) red[wave] = rloc;
    __syncthreads();
    if (tid == 0)
        atomicAdd(&recon[m0 >> 9], red[0] + red[1] + red[2] + red[3]
                                 + red[4] + red[5] + red[6] + red[7]);
}

// ---------------------------------------------------------------------------
// Small helpers (all validated round 6)
// ---------------------------------------------------------------------------
__device__ __forceinline__ float block_sum_256(float v, float* red)
{
    #pragma unroll
    for (int off = 32; off; off >>= 1) v += __shfl_down(v, off, 64);
    const int lane = threadIdx.x & 63, wid = threadIdx.x >> 6;
    __syncthreads();
    if (lane == 0) red[wid] = v;
    __syncthreads();
    return red[0] + red[1] + red[2] + red[3];
}

__global__ void conv_all(const float* __restrict__ q, const float* __restrict__ v,
                         const float* __restrict__ Wq, const float* __restrict__ Wv,
                         const float* __restrict__ Wl, const float* __restrict__ vm,
                         unsigned short* __restrict__ qbf, unsigned short* __restrict__ vbf,
                         unsigned short* __restrict__ wqbf, unsigned short* __restrict__ wvbf,
                         unsigned short* __restrict__ wlbf, unsigned short* __restrict__ vmbf)
{
    const int i = blockIdx.x * blockDim.x + threadIdx.x;   // float4-unit index
    const float* src;
    unsigned short* dst;
    int off;
    if (i < 2097152)      { src = q;  dst = qbf;  off = i; }
    else if (i < 4194304) { src = v;  dst = vbf;  off = i - 2097152; }
    else if (i < 4259840) { src = Wq; dst = wqbf; off = i - 4194304; }
    else if (i < 4325376) { src = Wv; dst = wvbf; off = i - 4259840; }
    else if (i < 4849664) { src = Wl; dst = wlbf; off = i - 4325376; }
    else if (i < 4864000) { src = vm; dst = vmbf; off = i - 4849664; }
    else {                 // zero vmbf pad rows 112..127 (8192 bf16)
        const int j = i - 4864000;   // 0..2047
        *(ushort4*)(vmbf + 57344 + (size_t)j * 4) = make_ushort4(0, 0, 0, 0);
        return;
    }
    const float4 x = *(const float4*)(src + (size_t)off * 4);
    ushort4 o;
    o.x = f2bf(x.x); o.y = f2bf(x.y); o.z = f2bf(x.z); o.w = f2bf(x.w);
    *(ushort4*)(dst + (size_t)off * 4) = o;
}

__global__ void prep_key_norm(const float* __restrict__ km,
                              unsigned short* __restrict__ knb,
                              float* __restrict__ outrc)
{
    const int row = blockIdx.x;         // h*128+s
    const int h = row >> 7, s = row & 127;
    const int lane = threadIdx.x;       // 64 threads
    if (row == 0 && lane < 33) outrc[lane] = 0.f;
    const float v = (s < SLOTS) ? km[(size_t)(h * SLOTS + s) * HD + lane] : 0.f;
    const float ssum = wsum64(v * v);
    const float inv = 1.f / fmaxf(sqrtf(ssum), 1e-12f);
    knb[(size_t)row * HD + lane] = f2bf(v * inv);
}

__global__ void prep_value_norm(const float* __restrict__ vm,
                                float* __restrict__ vn,
                                unsigned short* __restrict__ vnb,
                                unsigned short* __restrict__ vmTb)
{
    const int row = blockIdx.x;        // 0..175
    const int tid = threadIdx.x;       // 256
    if (row >= 112) {
        const int idx = (row - 112) * 256 + tid;   // 0..16383
        if (idx < 8192) {
            vmTb[(size_t)(idx >> 4) * 128 + 112 + (idx & 15)] = 0;
        } else {
            const int j = idx - 8192;
            vnb[(size_t)(112 + (j >> 9)) * 512 + (j & 511)] = 0;
        }
        return;
    }
    __shared__ float red[4];
    const float v0 = vm[(size_t)row * DIMC + tid];
    const float v1 = vm[(size_t)row * DIMC + 256 + tid];
    const float tot = block_sum_256(v0 * v0 + v1 * v1, red);
    const float inv = 1.f / fmaxf(sqrtf(tot), 1e-12f);
    vn[(size_t)row * DIMC + tid]        = v0 * inv;
    vn[(size_t)row * DIMC + 256 + tid]  = v1 * inv;
    vnb[(size_t)row * DIMC + tid]       = f2bf(v0 * inv);
    vnb[(size_t)row * DIMC + 256 + tid] = f2bf(v1 * inv);
    vmTb[(size_t)tid * 128 + row]         = f2bf(v0);
    vmTb[(size_t)(256 + tid) * 128 + row] = f2bf(v1);
}

__global__ void contrastive_kernel(const float* __restrict__ vn, float* __restrict__ outc)
{
    __shared__ float vni[DIMC];
    __shared__ float red[2];
    const int i = blockIdx.x, tid = threadIdx.x;   // 128 threads
    for (int d = tid; d < DIMC; d += 128) vni[d] = vn[(size_t)i * DIMC + d];
    __syncthreads();
    float t = 0.f;
    if (tid < SLOTS) {
        const float* r = vn + (size_t)tid * DIMC;
        float dot = 0.f;
        for (int d = 0; d < DIMC; ++d) dot += vni[d] * r[d];
        const float delta = (tid == i) ? 1.f : 0.f;
        t = fabsf(delta - dot);
    }
    #pragma unroll
    for (int off = 32; off; off >>= 1) t += __shfl_down(t, off, 64);
    if ((tid & 63) == 0) red[tid >> 6] = t;
    __syncthreads();
    if (tid == 0) atomicAdd(outc, 0.5f * (red[0] + red[1]));
}

// ---------------------------------------------------------------------------
// Launch
// ---------------------------------------------------------------------------
extern "C" void kernel_launch(void* const* d_in, const int* in_sizes, int n_in,
                              void* d_out, int out_size, void* d_ws, size_t ws_size,
                              hipStream_t stream)
{
    const float* query = (const float*)d_in[0];
    const float* value = (const float*)d_in[1];
    const float* keym  = (const float*)d_in[2];
    const float* vmem  = (const float*)d_in[3];
    const float* Wq    = (const float*)d_in[4];
    const float* bq    = (const float*)d_in[5];
    const float* Wv    = (const float*)d_in[6];
    const float* bv    = (const float*)d_in[7];
    const float* Wl    = (const float*)d_in[8];
    const float* bl    = (const float*)d_in[9];
    const float* g1    = (const float*)d_in[10];
    const float* b1    = (const float*)d_in[11];
    const float* g2    = (const float*)d_in[12];
    const float* b2    = (const float*)d_in[13];
    const float* g3    = (const float*)d_in[14];
    const float* b3    = (const float*)d_in[15];

    float* out    = (float*)d_out;
    float* out_te = out;
    float* out_tr = out + 8388608;
    float* out_rc = out + 16777216;    // 32 recon + 1 contrastive

    // Workspace layout (float offsets), round-11 (same as round-10).
    float* ws = (float*)d_ws;
    unsigned short* w_knb  = (unsigned short*)(ws + 0);
    unsigned short* w_vmTb = (unsigned short*)(ws + 32768);
    unsigned short* w_vnb  = (unsigned short*)(ws + 65536);
    float*          w_vn   = ws + 98304;
    unsigned short* w_w2tbf= (unsigned short*)(ws + 155648);
    unsigned short* w_vmbf = (unsigned short*)(ws + 385024);
    unsigned short* w_wlbf = (unsigned short*)(ws + 417792);
    unsigned short* w_xbf  = (unsigned short*)(ws + 1466368);
    unsigned short* w_kaddc= (unsigned short*)(ws + 5660672);
    unsigned short* w_vsb  = (unsigned short*)(ws + 13000704);
    unsigned short* w_qbf  = (unsigned short*)(ws + 14049280);
    unsigned short* w_vbf  = (unsigned short*)(ws + 18243584);
    unsigned short* w_wqbf = (unsigned short*)(ws + 22437888);
    unsigned short* w_wvbf = (unsigned short*)(ws + 22568960);

    // 1) all input conversions in one launch (+ vmbf pad zeros)
    conv_all<<<19008, 256, 0, stream>>>(query, value, Wq, Wv, Wl, vmem,
                                        w_qbf, w_vbf, w_wqbf, w_wvbf,
                                        w_wlbf, w_vmbf);
    // 2) input-only precomputes
    prep_key_norm<<<1024, 64, 0, stream>>>(keym, w_knb, out_rc);
    prep_value_norm<<<176, 256, 0, stream>>>(vmem, w_vn, w_vnb, w_vmTb);
    contrastive_kernel<<<112, 128, 0, stream>>>(w_vn, out_rc + 32);
    gemm_bf16<<<dim3(1, 4, 8), 256, 0, stream>>>(             // W2T bf16 direct
        (const short*)w_wlbf, HEADS * DIMC, (const short*)w_vmbf, DIMC,
        nullptr, w_w2tbf, HEADS * SLOTS, DIMC, nullptr, SLOTS,
        DIMC, 0, SLOTS);

    // 3) key addressing path
    gemm_bf16<<<dim3(4, 128), 256, 0, stream>>>(              // eqbf = q@Wq^T+bq
        (const short*)w_qbf, DIMC, (const short*)w_wqbf, DIMC,
        nullptr, w_xbf, DIMC, DIMC, bq, DIMC, 0, 0, 0);
    gemm_softmax<<<dim3(1, 128, 8), 256, 0, stream>>>(        // kaddc = softmax(sims)
        (const short*)w_xbf, DIMC, HD, (const short*)w_knb, HD, 128 * HD,
        HD, w_kaddc, HEADS * SLOTS, SLOTS, SLOTS);
    gemm_vir_te<<<NROWS / 32, 512, 0, stream>>>(              // fused vir+LN+LN
        (const short*)w_kaddc, HEADS * SLOTS, (const short*)w_w2tbf, HEADS * SLOTS,
        HEADS * SLOTS, bl, query, g1, b1, g2, b2, out_te);

    // 4) value addressing path
    gemm_bf16<<<dim3(4, 128), 256, 0, stream>>>(              // evbf = v@Wv^T+bv
        (const short*)w_vbf, DIMC, (const short*)w_wvbf, DIMC,
        nullptr, w_xbf, DIMC, DIMC, bv, DIMC, 0, 0, 0);
    gemm_softmax<<<dim3(1, 128, 1), 256, 0, stream>>>(        // vsb = softmax(ev@vn^T)
        (const short*)w_xbf, DIMC, 0, (const short*)w_vnb, DIMC, 0,
        DIMC, w_vsb, 128, 0, 128);
    gemm_aud_tr<<<NROWS / 32, 512, 0, stream>>>(              // fused aud+cos+LN+LN
        (const short*)w_vsb, 128, (const short*)w_vmTb, 128, 128,
        value, query, g1, b1, g3, b3, out_tr, out_rc);
}